// Round 5
// baseline (1439.875 us; speedup 1.0000x reference)
//
#include <hip/hip_runtime.h>
#include <math.h>

// ---------------- constants ----------------
#define NBT   256    // B*T
#define NP    256    // points per frame
#define NC    10     // point channels
#define KNN   16
#define NPB   8      // points per block in edgeconv

__device__ __forceinline__ float gelu_f(float x) {
  return 0.5f * x * (1.0f + erff(x * 0.7071067811865476f));
}

// ---------------- K1: knn (wave-per-point, branchless top-16) ----------------
__global__ __launch_bounds__(256) void knn_kernel(const float* __restrict__ x_pt,
                                                  int* __restrict__ idx) {
  __shared__ float sx[NP], sy[NP], sz[NP], ssq[NP];
  int bt = blockIdx.x >> 6;
  int p0 = (blockIdx.x & 63) * 4;
  int tid = threadIdx.x;
  const float* xb = x_pt + (size_t)bt * NP * NC;
  {
    int q = tid;
    float x0 = xb[q*NC+0], x1 = xb[q*NC+1], x2 = xb[q*NC+2];
    sx[q] = x0; sy[q] = x1; sz[q] = x2;
    ssq[q] = x0*x0 + x1*x1 + x2*x2;
  }
  __syncthreads();

  int wv = tid >> 6, lane = tid & 63;
  int p = p0 + wv;
  float px = sx[p], py = sy[p], pz = sz[p], psq = ssq[p];

  unsigned k0, k1, k2, k3;
  {
    unsigned kk[4];
#pragma unroll
    for (int c = 0; c < 4; ++c) {
      int q = lane + c*64;
      float d = psq + ssq[q] - 2.0f*(px*sx[q] + py*sy[q] + pz*sz[q]);
      d = fmaxf(d, 0.0f);
      kk[c] = (__float_as_uint(d) & 0xFFFFFF00u) | (unsigned)q;
    }
    unsigned a0 = min(kk[0], kk[1]), a1 = max(kk[0], kk[1]);
    unsigned a2 = min(kk[2], kk[3]), a3 = max(kk[2], kk[3]);
    unsigned b0 = min(a0, a2), b2 = max(a0, a2);
    unsigned b1 = min(a1, a3), b3 = max(a1, a3);
    k0 = b0; k1 = min(b1, b2); k2 = max(b1, b2); k3 = b3;
  }

  unsigned cur = k0, mykeep = 0u;
#pragma unroll
  for (int r = 0; r < 16; ++r) {
    unsigned w = cur;
    w = min(w, (unsigned)__shfl_xor((int)w, 1));
    w = min(w, (unsigned)__shfl_xor((int)w, 2));
    w = min(w, (unsigned)__shfl_xor((int)w, 4));
    w = min(w, (unsigned)__shfl_xor((int)w, 8));
    w = min(w, (unsigned)__shfl_xor((int)w, 16));
    w = min(w, (unsigned)__shfl_xor((int)w, 32));
    bool win = (cur == w);
    cur = win ? k1 : cur;
    k1  = win ? k2 : k1;
    k2  = win ? k3 : k2;
    k3  = win ? 0xFFFFFFFFu : k3;
    if (lane == r) mykeep = w;
  }
  if (lane < 16)
    idx[((size_t)bt*NP + p)*KNN + lane] = (int)(mykeep & 0xFFu);
}

// ---------------- K2: factored layer-1 features ----------------
__global__ __launch_bounds__(256) void featAB_kernel(const float* __restrict__ x_pt,
                                                     const float* __restrict__ ew1,
                                                     float* __restrict__ Af,
                                                     float* __restrict__ Bf) {
  int t = blockIdx.x*256 + threadIdx.x;
  int o = t & 63, p = t >> 6;
  const float* xr = x_pt + (size_t)p*NC;
  float a = 0.f, b = 0.f;
#pragma unroll
  for (int e = 0; e < NC; ++e) {
    float w1 = ew1[o*20 + e], w2 = ew1[o*20 + 10 + e];
    float xv = xr[e];
    a = fmaf(xv, w1 - w2, a);
    b = fmaf(xv, w2, b);
  }
  Af[(size_t)p*64 + o] = a;
  Bf[(size_t)p*64 + o] = b;
}

// ---------------- K3: edgeconv layer2 + max over k ----------------
__global__ __launch_bounds__(256) void edgeconv_kernel(
    const float* __restrict__ Af, const float* __restrict__ Bf,
    const int* __restrict__ idx, const float* __restrict__ ew2,
    const float* __restrict__ eg1, const float* __restrict__ eb1,
    const float* __restrict__ em1, const float* __restrict__ ev1,
    const float* __restrict__ eg2, const float* __restrict__ eb2,
    const float* __restrict__ em2, const float* __restrict__ ev2,
    float* __restrict__ localf) {
  __shared__ __align__(16) float w2s[64*128];
  __shared__ __align__(16) float h1s[NPB*64*20];
  __shared__ float sc1[64], sh1[64], sc2[128], sh2[128];
  __shared__ int idxs[NPB*16];

  int tid = threadIdx.x;
  int p0  = blockIdx.x * NPB;
  int bt  = p0 >> 8;

  for (int i = tid; i < 8192; i += 256) {
    int q = i >> 6, o = i & 63;
    w2s[o*128 + q] = ew2[i];
  }
  if (tid < 128) {
    idxs[tid] = idx[(size_t)p0*16 + tid];
  }
  if (tid < 64) {
    float s = eg1[tid] * (1.0f / sqrtf(ev1[tid] + 1e-5f));
    sc1[tid] = s; sh1[tid] = eb1[tid] - em1[tid]*s;
  }
  if (tid >= 64 && tid < 192) {
    int q = tid - 64;
    float s = eg2[q] * (1.0f / sqrtf(ev2[q] + 1e-5f));
    sc2[q] = s; sh2[q] = eb2[q] - em2[q]*s;
  }
  __syncthreads();

  {
    int o = tid & 63, g = tid >> 6;
    float s1 = sc1[o], h1 = sh1[o];
    const float* Bbase = Bf + (size_t)bt*NP*64 + o;
#pragma unroll
    for (int pi = 0; pi < 2; ++pi) {
      int pt = g*2 + pi;
      float af = Af[((size_t)(p0+pt))*64 + o];
      float* hrow = h1s + pt*1280 + o*20;
      for (int k = 0; k < KNN; ++k) {
        int j = idxs[pt*16 + k];
        float hv = af + Bbase[(size_t)j*64];
        hrow[k] = gelu_f(fmaf(hv, s1, h1));
      }
    }
  }
  __syncthreads();

  int pt = tid >> 5, s = tid & 31;
  int kb = s & 1, qb = s >> 1;
  int k0 = kb*8, q0 = qb*8;
  float acc[8][8];
#pragma unroll
  for (int a = 0; a < 8; ++a)
#pragma unroll
    for (int b = 0; b < 8; ++b) acc[a][b] = 0.f;

  const float* hbase = h1s + pt*1280;
#pragma unroll 2
  for (int o = 0; o < 64; ++o) {
    float4 a0 = *(const float4*)(hbase + o*20 + k0);
    float4 a1 = *(const float4*)(hbase + o*20 + k0 + 4);
    float4 b0 = *(const float4*)(w2s + o*128 + q0);
    float4 b1 = *(const float4*)(w2s + o*128 + q0 + 4);
    float av[8] = {a0.x,a0.y,a0.z,a0.w,a1.x,a1.y,a1.z,a1.w};
    float bv[8] = {b0.x,b0.y,b0.z,b0.w,b1.x,b1.y,b1.z,b1.w};
#pragma unroll
    for (int ki = 0; ki < 8; ++ki)
#pragma unroll
      for (int qi = 0; qi < 8; ++qi)
        acc[ki][qi] = fmaf(av[ki], bv[qi], acc[ki][qi]);
  }

  float mn8[8], mx8[8];
#pragma unroll
  for (int qi = 0; qi < 8; ++qi) {
    float sc = sc2[q0+qi], sh = sh2[q0+qi];
    float mn = INFINITY, mx = -INFINITY;
#pragma unroll
    for (int ki = 0; ki < 8; ++ki) {
      float v = fmaf(acc[ki][qi], sc, sh);
      mn = fminf(mn, v); mx = fmaxf(mx, v);
    }
    mn = fminf(mn, __shfl_xor(mn, 1));
    mx = fmaxf(mx, __shfl_xor(mx, 1));
    mn8[qi] = mn; mx8[qi] = mx;
  }
  float g4[4];
#pragma unroll
  for (int j = 0; j < 4; ++j) {
    int qi = kb*4 + j;
    g4[j] = fmaxf(gelu_f(mn8[qi]), gelu_f(mx8[qi]));
  }
  float o4[4];
#pragma unroll
  for (int j = 0; j < 4; ++j) o4[j] = __shfl_xor(g4[j], 1);
  if (kb == 0) {
    float* op = localf + ((size_t)(p0+pt))*128 + q0;
    *(float4*)op     = make_float4(g4[0],g4[1],g4[2],g4[3]);
    *(float4*)(op+4) = make_float4(o4[0],o4[1],o4[2],o4[3]);
  }
}

// ---------------- K4: p1p2 partial (16 points per block, 4096 blocks) ----------------
// feat rows padded to 144, h1c rows padded to 136 (16B-aligned rows -> ds_read_b128)
__global__ __launch_bounds__(256, 4) void p1p2_kernel(
    const float* __restrict__ localf, const float* __restrict__ x_pt,
    const float* __restrict__ p1w, const float* __restrict__ p1b,
    const float* __restrict__ ln1g, const float* __restrict__ ln1b,
    const float* __restrict__ p2w, const float* __restrict__ p2b,
    const float* __restrict__ ln2g, const float* __restrict__ ln2b,
    float* __restrict__ pmaxb, float* __restrict__ psumb) {
  __shared__ __align__(16) float feat[16*144];
  __shared__ __align__(16) float h1c[16*136];
  __shared__ float pool[16*256];
  int blk = blockIdx.x;
  int bt = blk >> 4, ch = blk & 15;
  int tid = threadIdx.x;
  int pt = tid >> 4, sg = tid & 15;
  size_t gbase = (size_t)bt*NP + ch*16;

  // stage: localf via float4, x_pt scalar
  for (int i = tid; i < 16*32; i += 256) {
    int pp = i >> 5, v = i & 31;
    *(float4*)(feat + pp*144 + v*4) =
        *(const float4*)(localf + (gbase+pp)*128 + v*4);
  }
  if (tid < 160) {
    int pp = tid / 10, e = tid - pp*10;
    feat[pp*144 + 128 + e] = x_pt[(gbase+pp)*NC + e];
  }
  __syncthreads();

  // GEMM1: 8 outputs o = sg*8 + j
  float a[8];
#pragma unroll
  for (int j = 0; j < 8; ++j) a[j] = p1b[sg*8 + j];
  const float* fr = feat + pt*144;
  const float* wb1 = p1w + sg*8;
  for (int e4 = 0; e4 < 34; ++e4) {
    float4 f4 = *(const float4*)(fr + e4*4);
    float fs[4] = {f4.x, f4.y, f4.z, f4.w};
#pragma unroll
    for (int c = 0; c < 4; ++c) {
      int e = e4*4 + c;
      float4 w0 = *(const float4*)(wb1 + e*128);
      float4 w1 = *(const float4*)(wb1 + e*128 + 4);
      float fv = fs[c];
      a[0]=fmaf(fv,w0.x,a[0]); a[1]=fmaf(fv,w0.y,a[1]);
      a[2]=fmaf(fv,w0.z,a[2]); a[3]=fmaf(fv,w0.w,a[3]);
      a[4]=fmaf(fv,w1.x,a[4]); a[5]=fmaf(fv,w1.y,a[5]);
      a[6]=fmaf(fv,w1.z,a[6]); a[7]=fmaf(fv,w1.w,a[7]);
    }
  }
#pragma unroll
  for (int e = 136; e < 138; ++e) {
    float fv = fr[e];
    float4 w0 = *(const float4*)(wb1 + e*128);
    float4 w1 = *(const float4*)(wb1 + e*128 + 4);
    a[0]=fmaf(fv,w0.x,a[0]); a[1]=fmaf(fv,w0.y,a[1]);
    a[2]=fmaf(fv,w0.z,a[2]); a[3]=fmaf(fv,w0.w,a[3]);
    a[4]=fmaf(fv,w1.x,a[4]); a[5]=fmaf(fv,w1.y,a[5]);
    a[6]=fmaf(fv,w1.z,a[6]); a[7]=fmaf(fv,w1.w,a[7]);
  }
  // LN over 128 (16 lanes x 8)
  float s = 0.f;
#pragma unroll
  for (int j = 0; j < 8; ++j) s += a[j];
  s += __shfl_xor(s,1); s += __shfl_xor(s,2); s += __shfl_xor(s,4); s += __shfl_xor(s,8);
  float mu = s * (1.0f/128.0f);
  float s2 = 0.f;
#pragma unroll
  for (int j = 0; j < 8; ++j) { float d = a[j]-mu; s2 += d*d; }
  s2 += __shfl_xor(s2,1); s2 += __shfl_xor(s2,2); s2 += __shfl_xor(s2,4); s2 += __shfl_xor(s2,8);
  float rs = 1.0f / sqrtf(s2*(1.0f/128.0f) + 1e-5f);
#pragma unroll
  for (int j = 0; j < 8; ++j) {
    float y = (a[j]-mu)*rs*ln1g[sg*8+j] + ln1b[sg*8+j];
    h1c[pt*136 + sg*8 + j] = gelu_f(y);
  }
  __syncthreads();

  // GEMM2: 16 outputs q = sg*16 + j
  float c2[16];
#pragma unroll
  for (int j = 0; j < 16; ++j) c2[j] = p2b[sg*16 + j];
  const float* hr = h1c + pt*136;
  const float* wb2 = p2w + sg*16;
  for (int e4 = 0; e4 < 32; ++e4) {
    float4 h4 = *(const float4*)(hr + e4*4);
    float hs[4] = {h4.x, h4.y, h4.z, h4.w};
#pragma unroll
    for (int c = 0; c < 4; ++c) {
      int e = e4*4 + c;
      float hv = hs[c];
      float4 w0 = *(const float4*)(wb2 + e*256);
      float4 w1 = *(const float4*)(wb2 + e*256 + 4);
      float4 w2v = *(const float4*)(wb2 + e*256 + 8);
      float4 w3 = *(const float4*)(wb2 + e*256 + 12);
      c2[0]=fmaf(hv,w0.x,c2[0]);  c2[1]=fmaf(hv,w0.y,c2[1]);
      c2[2]=fmaf(hv,w0.z,c2[2]);  c2[3]=fmaf(hv,w0.w,c2[3]);
      c2[4]=fmaf(hv,w1.x,c2[4]);  c2[5]=fmaf(hv,w1.y,c2[5]);
      c2[6]=fmaf(hv,w1.z,c2[6]);  c2[7]=fmaf(hv,w1.w,c2[7]);
      c2[8]=fmaf(hv,w2v.x,c2[8]); c2[9]=fmaf(hv,w2v.y,c2[9]);
      c2[10]=fmaf(hv,w2v.z,c2[10]); c2[11]=fmaf(hv,w2v.w,c2[11]);
      c2[12]=fmaf(hv,w3.x,c2[12]); c2[13]=fmaf(hv,w3.y,c2[13]);
      c2[14]=fmaf(hv,w3.z,c2[14]); c2[15]=fmaf(hv,w3.w,c2[15]);
    }
  }
  // LN over 256 (16 lanes x 16)
  float t1 = 0.f;
#pragma unroll
  for (int j = 0; j < 16; ++j) t1 += c2[j];
  t1 += __shfl_xor(t1,1); t1 += __shfl_xor(t1,2); t1 += __shfl_xor(t1,4); t1 += __shfl_xor(t1,8);
  float mu2 = t1 * (1.0f/256.0f);
  float t2 = 0.f;
#pragma unroll
  for (int j = 0; j < 16; ++j) { float d = c2[j]-mu2; t2 += d*d; }
  t2 += __shfl_xor(t2,1); t2 += __shfl_xor(t2,2); t2 += __shfl_xor(t2,4); t2 += __shfl_xor(t2,8);
  float rs2 = 1.0f / sqrtf(t2*(1.0f/256.0f) + 1e-5f);
#pragma unroll
  for (int j = 0; j < 16; ++j) {
    float y = (c2[j]-mu2)*rs2*ln2g[sg*16+j] + ln2b[sg*16+j];
    pool[pt*256 + sg*16 + j] = gelu_f(y);
  }
  __syncthreads();

  // block-level partial max/sum over 16 points
  {
    int q = tid;
    float mx = -INFINITY, sm = 0.f;
#pragma unroll
    for (int sl = 0; sl < 16; ++sl) {
      float vv = pool[sl*256 + q];
      mx = fmaxf(mx, vv); sm += vv;
    }
    pmaxb[(size_t)blk*256 + q] = mx;
    psumb[(size_t)blk*256 + q] = sm;
  }
}

// ---------------- K4b: combine partials + frame MLP ----------------
__global__ __launch_bounds__(256) void p1p2_reduce_kernel(
    const float* __restrict__ pmaxb, const float* __restrict__ psumb,
    const float* __restrict__ xfr, const float* __restrict__ f1w,
    const float* __restrict__ f1b, const float* __restrict__ f2w,
    const float* __restrict__ f2b, float* __restrict__ perbuf) {
  int bt = blockIdx.x, q = threadIdx.x;
  const float* mb = pmaxb + (size_t)bt*16*256 + q;
  const float* sb = psumb + (size_t)bt*16*256 + q;
  float mx = -INFINITY, sm = 0.f;
#pragma unroll
  for (int i = 0; i < 16; ++i) {
    mx = fmaxf(mx, mb[i*256]);
    sm += sb[i*256];
  }
  perbuf[(size_t)bt*576 + q] = mx;
  perbuf[(size_t)bt*576 + 256 + q] = sm * (1.0f/256.0f);

  if (q < 64) {
    float x0 = xfr[bt*4], x1 = xfr[bt*4+1], x2 = xfr[bt*4+2], x3 = xfr[bt*4+3];
    float acc = f2b[q];
#pragma unroll
    for (int e = 0; e < 32; ++e) {
      float hv = f1b[e];
      hv = fmaf(x0, f1w[e], hv);
      hv = fmaf(x1, f1w[32+e], hv);
      hv = fmaf(x2, f1w[64+e], hv);
      hv = fmaf(x3, f1w[96+e], hv);
      acc = fmaf(gelu_f(hv), f2w[e*64 + q], acc);
    }
    perbuf[(size_t)bt*576 + 512 + q] = acc;
  }
}

// ---------------- K6: 1x1 projection conv ----------------
__global__ __launch_bounds__(256) void proj_kernel(
    const float* __restrict__ per, const float* __restrict__ projw,
    const float* __restrict__ projb, float* __restrict__ hout) {
  __shared__ __align__(16) float sp[576];
  int bt = blockIdx.x, c = threadIdx.x;
  for (int i = c; i < 576; i += 256) sp[i] = per[(size_t)bt*576 + i];
  __syncthreads();
  float acc = projb[c];
  const float* wr = projw + (size_t)c*576;
  for (int i = 0; i < 144; ++i) {
    float4 wv = *(const float4*)(wr + i*4);
    float4 pv = *(const float4*)(sp + i*4);
    acc = fmaf(wv.x, pv.x, acc); acc = fmaf(wv.y, pv.y, acc);
    acc = fmaf(wv.z, pv.z, acc); acc = fmaf(wv.w, pv.w, acc);
  }
  hout[(size_t)bt*256 + c] = acc;
}

// ---------------- K7: conv3 + bn + gelu (+residual) ----------------
__global__ __launch_bounds__(256) void conv_bn_kernel(
    const float* __restrict__ hin, float* __restrict__ hout,
    const float* __restrict__ w, const float* __restrict__ bias,
    const float* __restrict__ g, const float* __restrict__ be,
    const float* __restrict__ m, const float* __restrict__ v,
    int residual) {
  __shared__ __align__(16) float win[768];
  int bt = blockIdx.x, b = bt >> 5, t = bt & 31;
  int c = threadIdx.x;
  for (int i = c; i < 768; i += 256) {
    int cin = i / 3, dt = i - cin*3;
    int tt = t + dt - 1;
    win[i] = (tt >= 0 && tt < 32) ? hin[((size_t)b*32 + tt)*256 + cin] : 0.0f;
  }
  __syncthreads();
  float acc = bias[c];
  const float* wr = w + (size_t)c*768;
  for (int i = 0; i < 192; ++i) {
    float4 wv = *(const float4*)(wr + i*4);
    float4 pv = *(const float4*)(win + i*4);
    acc = fmaf(wv.x, pv.x, acc); acc = fmaf(wv.y, pv.y, acc);
    acc = fmaf(wv.z, pv.z, acc); acc = fmaf(wv.w, pv.w, acc);
  }
  float rsv = 1.0f / sqrtf(v[c] + 1e-5f);
  float y = (acc - m[c]) * rsv * g[c] + be[c];
  y = gelu_f(y);
  if (residual) y += win[c*3 + 1];
  hout[(size_t)bt*256 + c] = y;
}

// ---------------- K8: max-pool over T + head ----------------
__global__ __launch_bounds__(256) void poolhead_kernel(
    const float* __restrict__ hs, const float* __restrict__ h1w,
    const float* __restrict__ h1b, const float* __restrict__ h2w,
    const float* __restrict__ h2b, float* __restrict__ out) {
  __shared__ float pooled[256];
  __shared__ float hh[128];
  int b = blockIdx.x, tid = threadIdx.x;
  float mx = -INFINITY;
  for (int t = 0; t < 32; ++t)
    mx = fmaxf(mx, hs[((size_t)b*32 + t)*256 + tid]);
  pooled[tid] = mx;
  __syncthreads();
  if (tid < 128) {
    float acc = h1b[tid];
    for (int e = 0; e < 256; ++e) acc = fmaf(pooled[e], h1w[e*128 + tid], acc);
    hh[tid] = gelu_f(acc);
  }
  __syncthreads();
  if (tid < 25) {
    float acc = h2b[tid];
    for (int e = 0; e < 128; ++e) acc = fmaf(hh[e], h2w[e*25 + tid], acc);
    out[b*25 + tid] = acc;
  }
}

// ---------------- launch ----------------
extern "C" void kernel_launch(void* const* d_in, const int* in_sizes, int n_in,
                              void* d_out, int out_size, void* d_ws, size_t ws_size,
                              hipStream_t stream) {
  const float* x_pt = (const float*)d_in[0];
  const float* x_fr = (const float*)d_in[1];
  const float* ew1  = (const float*)d_in[2];
  const float* eg1  = (const float*)d_in[3];
  const float* eb1  = (const float*)d_in[4];
  const float* em1  = (const float*)d_in[5];
  const float* ev1  = (const float*)d_in[6];
  const float* ew2  = (const float*)d_in[7];
  const float* eg2  = (const float*)d_in[8];
  const float* eb2  = (const float*)d_in[9];
  const float* em2  = (const float*)d_in[10];
  const float* ev2  = (const float*)d_in[11];
  const float* p1w  = (const float*)d_in[12];
  const float* p1b  = (const float*)d_in[13];
  const float* ln1g = (const float*)d_in[14];
  const float* ln1b = (const float*)d_in[15];
  const float* p2w  = (const float*)d_in[16];
  const float* p2b  = (const float*)d_in[17];
  const float* ln2g = (const float*)d_in[18];
  const float* ln2b = (const float*)d_in[19];
  const float* f1w  = (const float*)d_in[20];
  const float* f1b  = (const float*)d_in[21];
  const float* f2w  = (const float*)d_in[22];
  const float* f2b  = (const float*)d_in[23];
  const float* projw= (const float*)d_in[24];
  const float* projb= (const float*)d_in[25];
  const float* cw[4] = {(const float*)d_in[26],(const float*)d_in[32],(const float*)d_in[38],(const float*)d_in[44]};
  const float* cb[4] = {(const float*)d_in[27],(const float*)d_in[33],(const float*)d_in[39],(const float*)d_in[45]};
  const float* cg[4] = {(const float*)d_in[28],(const float*)d_in[34],(const float*)d_in[40],(const float*)d_in[46]};
  const float* cbe[4]= {(const float*)d_in[29],(const float*)d_in[35],(const float*)d_in[41],(const float*)d_in[47]};
  const float* cm[4] = {(const float*)d_in[30],(const float*)d_in[36],(const float*)d_in[42],(const float*)d_in[48]};
  const float* cv[4] = {(const float*)d_in[31],(const float*)d_in[37],(const float*)d_in[43],(const float*)d_in[49]};
  const float* h1w  = (const float*)d_in[50];
  const float* h1b  = (const float*)d_in[51];
  const float* h2w  = (const float*)d_in[52];
  const float* h2b  = (const float*)d_in[53];
  float* out = (float*)d_out;

  char* ws = (char*)d_ws;
  int*   idxw   = (int*)ws;                          // 4 MB (dead after edgeconv)
  float* perbuf = (float*)ws;                        // reused after edgeconv
  float* hs0    = (float*)(ws + 0x90000);
  float* hs1    = (float*)(ws + 0x90000 + 0x40000);
  float* hs2    = (float*)(ws + 0x90000 + 2*0x40000);
  float* hs3    = (float*)(ws + 0x90000 + 3*0x40000);
  float* hs4    = (float*)(ws + 0x90000 + 4*0x40000);
  float* Af     = (float*)(ws + ((size_t)4  << 20)); // dead after edgeconv
  float* Bfw    = (float*)(ws + ((size_t)20 << 20)); // dead after edgeconv
  float* localf = (float*)(ws + ((size_t)36 << 20));
  float* pmaxb  = (float*)(ws + ((size_t)4  << 20)); // reuse Af region: 4 MB
  float* psumb  = (float*)(ws + ((size_t)8  << 20)); // 4 MB

  knn_kernel<<<NBT*64, 256, 0, stream>>>(x_pt, idxw);
  featAB_kernel<<<(NBT*NP*64)/256, 256, 0, stream>>>(x_pt, ew1, Af, Bfw);
  edgeconv_kernel<<<(NBT*NP)/NPB, 256, 0, stream>>>(Af, Bfw, idxw, ew2,
      eg1, eb1, em1, ev1, eg2, eb2, em2, ev2, localf);
  p1p2_kernel<<<NBT*16, 256, 0, stream>>>(localf, x_pt, p1w, p1b, ln1g, ln1b,
      p2w, p2b, ln2g, ln2b, pmaxb, psumb);
  p1p2_reduce_kernel<<<NBT, 256, 0, stream>>>(pmaxb, psumb, x_fr,
      f1w, f1b, f2w, f2b, perbuf);
  proj_kernel<<<NBT, 256, 0, stream>>>(perbuf, projw, projb, hs0);
  conv_bn_kernel<<<NBT, 256, 0, stream>>>(hs0, hs1, cw[0], cb[0], cg[0], cbe[0], cm[0], cv[0], 0);
  conv_bn_kernel<<<NBT, 256, 0, stream>>>(hs1, hs2, cw[1], cb[1], cg[1], cbe[1], cm[1], cv[1], 1);
  conv_bn_kernel<<<NBT, 256, 0, stream>>>(hs2, hs3, cw[2], cb[2], cg[2], cbe[2], cm[2], cv[2], 1);
  conv_bn_kernel<<<NBT, 256, 0, stream>>>(hs3, hs4, cw[3], cb[3], cg[3], cbe[3], cm[3], cv[3], 1);
  poolhead_kernel<<<8, 256, 0, stream>>>(hs4, h1w, h1b, h2w, h2b, out);
}

// Round 6
// 856.901 us; speedup vs baseline: 1.6803x; 1.6803x over previous
//
#include <hip/hip_runtime.h>
#include <math.h>

// ---------------- constants ----------------
#define NBT   256    // B*T
#define NP    256    // points per frame
#define NC    10     // point channels
#define KNN   16
#define NPB   8      // points per block in edgeconv

__device__ __forceinline__ float gelu_f(float x) {
  return 0.5f * x * (1.0f + erff(x * 0.7071067811865476f));
}

// ---------------- K1: knn (wave-per-point, branchless top-16) ----------------
__global__ __launch_bounds__(256) void knn_kernel(const float* __restrict__ x_pt,
                                                  int* __restrict__ idx) {
  __shared__ float sx[NP], sy[NP], sz[NP], ssq[NP];
  int bt = blockIdx.x >> 6;
  int p0 = (blockIdx.x & 63) * 4;
  int tid = threadIdx.x;
  const float* xb = x_pt + (size_t)bt * NP * NC;
  {
    int q = tid;
    float x0 = xb[q*NC+0], x1 = xb[q*NC+1], x2 = xb[q*NC+2];
    sx[q] = x0; sy[q] = x1; sz[q] = x2;
    ssq[q] = x0*x0 + x1*x1 + x2*x2;
  }
  __syncthreads();

  int wv = tid >> 6, lane = tid & 63;
  int p = p0 + wv;
  float px = sx[p], py = sy[p], pz = sz[p], psq = ssq[p];

  unsigned k0, k1, k2, k3;
  {
    unsigned kk[4];
#pragma unroll
    for (int c = 0; c < 4; ++c) {
      int q = lane + c*64;
      float d = psq + ssq[q] - 2.0f*(px*sx[q] + py*sy[q] + pz*sz[q]);
      d = fmaxf(d, 0.0f);
      kk[c] = (__float_as_uint(d) & 0xFFFFFF00u) | (unsigned)q;
    }
    unsigned a0 = min(kk[0], kk[1]), a1 = max(kk[0], kk[1]);
    unsigned a2 = min(kk[2], kk[3]), a3 = max(kk[2], kk[3]);
    unsigned b0 = min(a0, a2), b2 = max(a0, a2);
    unsigned b1 = min(a1, a3), b3 = max(a1, a3);
    k0 = b0; k1 = min(b1, b2); k2 = max(b1, b2); k3 = b3;
  }

  unsigned cur = k0, mykeep = 0u;
#pragma unroll
  for (int r = 0; r < 16; ++r) {
    unsigned w = cur;
    w = min(w, (unsigned)__shfl_xor((int)w, 1));
    w = min(w, (unsigned)__shfl_xor((int)w, 2));
    w = min(w, (unsigned)__shfl_xor((int)w, 4));
    w = min(w, (unsigned)__shfl_xor((int)w, 8));
    w = min(w, (unsigned)__shfl_xor((int)w, 16));
    w = min(w, (unsigned)__shfl_xor((int)w, 32));
    bool win = (cur == w);
    cur = win ? k1 : cur;
    k1  = win ? k2 : k1;
    k2  = win ? k3 : k2;
    k3  = win ? 0xFFFFFFFFu : k3;
    if (lane == r) mykeep = w;
  }
  if (lane < 16)
    idx[((size_t)bt*NP + p)*KNN + lane] = (int)(mykeep & 0xFFu);
}

// ---------------- K2: factored layer-1 features ----------------
__global__ __launch_bounds__(256) void featAB_kernel(const float* __restrict__ x_pt,
                                                     const float* __restrict__ ew1,
                                                     float* __restrict__ Af,
                                                     float* __restrict__ Bf) {
  int t = blockIdx.x*256 + threadIdx.x;
  int o = t & 63, p = t >> 6;
  const float* xr = x_pt + (size_t)p*NC;
  float a = 0.f, b = 0.f;
#pragma unroll
  for (int e = 0; e < NC; ++e) {
    float w1 = ew1[o*20 + e], w2 = ew1[o*20 + 10 + e];
    float xv = xr[e];
    a = fmaf(xv, w1 - w2, a);
    b = fmaf(xv, w2, b);
  }
  Af[(size_t)p*64 + o] = a;
  Bf[(size_t)p*64 + o] = b;
}

// ---------------- K3: edgeconv layer2 + max over k ----------------
// w2s rows padded 128 -> 132 floats: staging write bank = (4o+q)%32 (8-way)
// instead of q%32 (64-way).
__global__ __launch_bounds__(256) void edgeconv_kernel(
    const float* __restrict__ Af, const float* __restrict__ Bf,
    const int* __restrict__ idx, const float* __restrict__ ew2,
    const float* __restrict__ eg1, const float* __restrict__ eb1,
    const float* __restrict__ em1, const float* __restrict__ ev1,
    const float* __restrict__ eg2, const float* __restrict__ eb2,
    const float* __restrict__ em2, const float* __restrict__ ev2,
    float* __restrict__ localf) {
  __shared__ __align__(16) float w2s[64*132];
  __shared__ __align__(16) float h1s[NPB*64*20];
  __shared__ float sc1[64], sh1[64], sc2[128], sh2[128];
  __shared__ int idxs[NPB*16];

  int tid = threadIdx.x;
  int p0  = blockIdx.x * NPB;
  int bt  = p0 >> 8;

  for (int i = tid; i < 8192; i += 256) {
    int q = i >> 6, o = i & 63;
    w2s[o*132 + q] = ew2[i];
  }
  if (tid < 128) {
    idxs[tid] = idx[(size_t)p0*16 + tid];
  }
  if (tid < 64) {
    float s = eg1[tid] * (1.0f / sqrtf(ev1[tid] + 1e-5f));
    sc1[tid] = s; sh1[tid] = eb1[tid] - em1[tid]*s;
  }
  if (tid >= 64 && tid < 192) {
    int q = tid - 64;
    float s = eg2[q] * (1.0f / sqrtf(ev2[q] + 1e-5f));
    sc2[q] = s; sh2[q] = eb2[q] - em2[q]*s;
  }
  __syncthreads();

  {
    int o = tid & 63, g = tid >> 6;
    float s1 = sc1[o], h1 = sh1[o];
    const float* Bbase = Bf + (size_t)bt*NP*64 + o;
#pragma unroll
    for (int pi = 0; pi < 2; ++pi) {
      int pt = g*2 + pi;
      float af = Af[((size_t)(p0+pt))*64 + o];
      float* hrow = h1s + pt*1280 + o*20;
      for (int k = 0; k < KNN; ++k) {
        int j = idxs[pt*16 + k];
        float hv = af + Bbase[(size_t)j*64];
        hrow[k] = gelu_f(fmaf(hv, s1, h1));
      }
    }
  }
  __syncthreads();

  int pt = tid >> 5, s = tid & 31;
  int kb = s & 1, qb = s >> 1;
  int k0 = kb*8, q0 = qb*8;
  float acc[8][8];
#pragma unroll
  for (int a = 0; a < 8; ++a)
#pragma unroll
    for (int b = 0; b < 8; ++b) acc[a][b] = 0.f;

  const float* hbase = h1s + pt*1280;
#pragma unroll 2
  for (int o = 0; o < 64; ++o) {
    float4 a0 = *(const float4*)(hbase + o*20 + k0);
    float4 a1 = *(const float4*)(hbase + o*20 + k0 + 4);
    float4 b0 = *(const float4*)(w2s + o*132 + q0);
    float4 b1 = *(const float4*)(w2s + o*132 + q0 + 4);
    float av[8] = {a0.x,a0.y,a0.z,a0.w,a1.x,a1.y,a1.z,a1.w};
    float bv[8] = {b0.x,b0.y,b0.z,b0.w,b1.x,b1.y,b1.z,b1.w};
#pragma unroll
    for (int ki = 0; ki < 8; ++ki)
#pragma unroll
      for (int qi = 0; qi < 8; ++qi)
        acc[ki][qi] = fmaf(av[ki], bv[qi], acc[ki][qi]);
  }

  float mn8[8], mx8[8];
#pragma unroll
  for (int qi = 0; qi < 8; ++qi) {
    float sc = sc2[q0+qi], sh = sh2[q0+qi];
    float mn = INFINITY, mx = -INFINITY;
#pragma unroll
    for (int ki = 0; ki < 8; ++ki) {
      float v = fmaf(acc[ki][qi], sc, sh);
      mn = fminf(mn, v); mx = fmaxf(mx, v);
    }
    mn = fminf(mn, __shfl_xor(mn, 1));
    mx = fmaxf(mx, __shfl_xor(mx, 1));
    mn8[qi] = mn; mx8[qi] = mx;
  }
  float g4[4];
#pragma unroll
  for (int j = 0; j < 4; ++j) {
    int qi = kb*4 + j;
    g4[j] = fmaxf(gelu_f(mn8[qi]), gelu_f(mx8[qi]));
  }
  float o4[4];
#pragma unroll
  for (int j = 0; j < 4; ++j) o4[j] = __shfl_xor(g4[j], 1);
  if (kb == 0) {
    float* op = localf + ((size_t)(p0+pt))*128 + q0;
    *(float4*)op     = make_float4(g4[0],g4[1],g4[2],g4[3]);
    *(float4*)(op+4) = make_float4(o4[0],o4[1],o4[2],o4[3]);
  }
}

// ---------------- K4: p1p2, register-tiled GEMMs with LDS weight tiles ----------------
// Grid: NBT*4 blocks, 256 threads, 64 points/block.
// Thread (pgrp=tid>>4, g=tid&15): 4 points x 8 outputs register tile.
// Weight traffic amortized: LDS tiles (w1: 46x128 x3, w2: 16x256 x8).
// sA: feat[64][148] (GEMM1 input) then h1c[64][140] (GEMM2 input) - row pads
//     chosen so 4-way point-strided access is 2-way bank aliasing (free).
// sW: weight tile / pooling partials (overlaid; sync-protected).
__global__ __launch_bounds__(256, 2) void p1p2_kernel(
    const float* __restrict__ localf, const float* __restrict__ x_pt,
    const float* __restrict__ p1w, const float* __restrict__ p1b,
    const float* __restrict__ ln1g, const float* __restrict__ ln1b,
    const float* __restrict__ p2w, const float* __restrict__ p2b,
    const float* __restrict__ ln2g, const float* __restrict__ ln2b,
    float* __restrict__ pmaxb, float* __restrict__ psumb) {
  __shared__ __align__(16) float sA[64*148];   // 37,888 B
  __shared__ __align__(16) float sW[46*128];   // 23,552 B
  int blk = blockIdx.x;
  int bt = blk >> 2, ch = blk & 3;
  int tid = threadIdx.x;
  int pgrp = tid >> 4, g = tid & 15;     // g: output group (16 lanes/LN group)
  size_t gbase = (size_t)bt*NP + ch*64;

  // ---- stage feat: localf (float4) + x_pt (scalar), rows padded to 148
  for (int i = tid; i < 64*32; i += 256) {
    int pp = i >> 5, v = i & 31;
    *(float4*)(sA + pp*148 + v*4) =
        *(const float4*)(localf + (gbase+pp)*128 + v*4);
  }
  for (int i = tid; i < 640; i += 256) {
    int pp = i / 10, e = i - pp*10;
    sA[pp*148 + 128 + e] = x_pt[(gbase+pp)*NC + e];
  }

  // ---- GEMM1: out[p][o] for o = g*8..+7, p = pgrp*4..+3
  float a0[8], a1[8], a2[8], a3[8];
#pragma unroll
  for (int j = 0; j < 8; ++j) { float b = p1b[g*8+j]; a0[j]=b; a1[j]=b; a2[j]=b; a3[j]=b; }
  const float4* sWf4 = (const float4*)sW;
  for (int t = 0; t < 3; ++t) {
    __syncthreads();                    // protect sW before restage (and feat after stage, t=0)
    for (int i = tid; i < 1472; i += 256)
      ((float4*)sW)[i] = ((const float4*)(p1w + t*46*128))[i];
    __syncthreads();
    const float* fA = sA + (pgrp*4)*148 + t*46;
#pragma unroll 2
    for (int el = 0; el < 46; ++el) {
      float4 w0 = sWf4[el*32 + g*2];
      float4 w1 = sWf4[el*32 + g*2 + 1];
      float wv[8] = {w0.x,w0.y,w0.z,w0.w,w1.x,w1.y,w1.z,w1.w};
      float f0 = fA[el], f1 = fA[148+el], f2 = fA[296+el], f3 = fA[444+el];
#pragma unroll
      for (int j = 0; j < 8; ++j) {
        a0[j] = fmaf(f0, wv[j], a0[j]);
        a1[j] = fmaf(f1, wv[j], a1[j]);
        a2[j] = fmaf(f2, wv[j], a2[j]);
        a3[j] = fmaf(f3, wv[j], a3[j]);
      }
    }
  }
  __syncthreads();   // all feat reads done; sA may be rewritten as h1c

  // ---- LN1 + gelu -> h1c[64][140]
  {
    float* ap[4] = {a0, a1, a2, a3};
    float g1v[8], b1v[8];
#pragma unroll
    for (int j = 0; j < 8; ++j) { g1v[j] = ln1g[g*8+j]; b1v[j] = ln1b[g*8+j]; }
#pragma unroll
    for (int i = 0; i < 4; ++i) {
      float* a = ap[i];
      float s = 0.f;
#pragma unroll
      for (int j = 0; j < 8; ++j) s += a[j];
      s += __shfl_xor(s,1); s += __shfl_xor(s,2); s += __shfl_xor(s,4); s += __shfl_xor(s,8);
      float mu = s * (1.0f/128.0f);
      float s2 = 0.f;
#pragma unroll
      for (int j = 0; j < 8; ++j) { float d = a[j]-mu; s2 += d*d; }
      s2 += __shfl_xor(s2,1); s2 += __shfl_xor(s2,2); s2 += __shfl_xor(s2,4); s2 += __shfl_xor(s2,8);
      float rs = 1.0f / sqrtf(s2*(1.0f/128.0f) + 1e-5f);
      float h[8];
#pragma unroll
      for (int j = 0; j < 8; ++j)
        h[j] = gelu_f((a[j]-mu)*rs*g1v[j] + b1v[j]);
      float* hp = sA + (pgrp*4+i)*140 + g*8;
      *(float4*)hp     = make_float4(h[0],h[1],h[2],h[3]);
      *(float4*)(hp+4) = make_float4(h[4],h[5],h[6],h[7]);
    }
  }

  // ---- GEMM2: out[p][q], q = h*128 + g*8..+7, K=128 in 8 tiles of 16
  float c00[8], c01[8], c02[8], c03[8];   // half 0, points 0..3
  float c10[8], c11[8], c12[8], c13[8];   // half 1
#pragma unroll
  for (int j = 0; j < 8; ++j) {
    float bA = p2b[g*8+j], bB = p2b[128 + g*8+j];
    c00[j]=bA; c01[j]=bA; c02[j]=bA; c03[j]=bA;
    c10[j]=bB; c11[j]=bB; c12[j]=bB; c13[j]=bB;
  }
  for (int t = 0; t < 8; ++t) {
    __syncthreads();
    for (int i = tid; i < 1024; i += 256)
      ((float4*)sW)[i] = ((const float4*)(p2w + t*16*256))[i];
    __syncthreads();
    const float* hA = sA + (pgrp*4)*140 + t*16;
#pragma unroll 2
    for (int el = 0; el < 16; ++el) {
      float f0 = hA[el], f1 = hA[140+el], f2 = hA[280+el], f3 = hA[420+el];
      float4 wa = sWf4[el*64 + g*2];
      float4 wb = sWf4[el*64 + g*2 + 1];
      float wv[8] = {wa.x,wa.y,wa.z,wa.w,wb.x,wb.y,wb.z,wb.w};
#pragma unroll
      for (int j = 0; j < 8; ++j) {
        c00[j] = fmaf(f0, wv[j], c00[j]);
        c01[j] = fmaf(f1, wv[j], c01[j]);
        c02[j] = fmaf(f2, wv[j], c02[j]);
        c03[j] = fmaf(f3, wv[j], c03[j]);
      }
      float4 wc = sWf4[el*64 + 32 + g*2];
      float4 wd = sWf4[el*64 + 32 + g*2 + 1];
      float wu[8] = {wc.x,wc.y,wc.z,wc.w,wd.x,wd.y,wd.z,wd.w};
#pragma unroll
      for (int j = 0; j < 8; ++j) {
        c10[j] = fmaf(f0, wu[j], c10[j]);
        c11[j] = fmaf(f1, wu[j], c11[j]);
        c12[j] = fmaf(f2, wu[j], c12[j]);
        c13[j] = fmaf(f3, wu[j], c13[j]);
      }
    }
  }
  __syncthreads();   // sW free for pooling

  // ---- LN2 + gelu + per-thread 4-point pool partials
  float pm0[8], ps0[8], pm1[8], ps1[8];
#pragma unroll
  for (int j = 0; j < 8; ++j) { pm0[j] = pm1[j] = -INFINITY; ps0[j] = ps1[j] = 0.f; }
  {
    float* cA[4] = {c00, c01, c02, c03};
    float* cB[4] = {c10, c11, c12, c13};
    float g2a[8], b2a[8], g2b[8], b2b[8];
#pragma unroll
    for (int j = 0; j < 8; ++j) {
      g2a[j] = ln2g[g*8+j];      b2a[j] = ln2b[g*8+j];
      g2b[j] = ln2g[128+g*8+j];  b2b[j] = ln2b[128+g*8+j];
    }
#pragma unroll
    for (int i = 0; i < 4; ++i) {
      float* ca = cA[i]; float* cb = cB[i];
      float s = 0.f;
#pragma unroll
      for (int j = 0; j < 8; ++j) s += ca[j] + cb[j];
      s += __shfl_xor(s,1); s += __shfl_xor(s,2); s += __shfl_xor(s,4); s += __shfl_xor(s,8);
      float mu = s * (1.0f/256.0f);
      float s2 = 0.f;
#pragma unroll
      for (int j = 0; j < 8; ++j) {
        float d1 = ca[j]-mu, d2 = cb[j]-mu; s2 += d1*d1 + d2*d2;
      }
      s2 += __shfl_xor(s2,1); s2 += __shfl_xor(s2,2); s2 += __shfl_xor(s2,4); s2 += __shfl_xor(s2,8);
      float rs = 1.0f / sqrtf(s2*(1.0f/256.0f) + 1e-5f);
#pragma unroll
      for (int j = 0; j < 8; ++j) {
        float v1 = gelu_f((ca[j]-mu)*rs*g2a[j] + b2a[j]);
        float v2 = gelu_f((cb[j]-mu)*rs*g2b[j] + b2b[j]);
        pm0[j] = fmaxf(pm0[j], v1); ps0[j] += v1;
        pm1[j] = fmaxf(pm1[j], v2); ps1[j] += v2;
      }
    }
  }

  // ---- block pool reduce via sW (16 pgrps x 256), two passes
  {
    float* pool = sW;
    *(float4*)(pool + pgrp*256 + g*8)       = make_float4(pm0[0],pm0[1],pm0[2],pm0[3]);
    *(float4*)(pool + pgrp*256 + g*8 + 4)   = make_float4(pm0[4],pm0[5],pm0[6],pm0[7]);
    *(float4*)(pool + pgrp*256 + 128 + g*8)     = make_float4(pm1[0],pm1[1],pm1[2],pm1[3]);
    *(float4*)(pool + pgrp*256 + 128 + g*8 + 4) = make_float4(pm1[4],pm1[5],pm1[6],pm1[7]);
    __syncthreads();
    float mx = -INFINITY;
#pragma unroll
    for (int r = 0; r < 16; ++r) mx = fmaxf(mx, pool[r*256 + tid]);
    pmaxb[(size_t)blk*256 + tid] = mx;
    __syncthreads();
    *(float4*)(pool + pgrp*256 + g*8)       = make_float4(ps0[0],ps0[1],ps0[2],ps0[3]);
    *(float4*)(pool + pgrp*256 + g*8 + 4)   = make_float4(ps0[4],ps0[5],ps0[6],ps0[7]);
    *(float4*)(pool + pgrp*256 + 128 + g*8)     = make_float4(ps1[0],ps1[1],ps1[2],ps1[3]);
    *(float4*)(pool + pgrp*256 + 128 + g*8 + 4) = make_float4(ps1[4],ps1[5],ps1[6],ps1[7]);
    __syncthreads();
    float sm = 0.f;
#pragma unroll
    for (int r = 0; r < 16; ++r) sm += pool[r*256 + tid];
    psumb[(size_t)blk*256 + tid] = sm;
  }
}

// ---------------- K4b: combine partials + frame MLP ----------------
__global__ __launch_bounds__(256) void p1p2_reduce_kernel(
    const float* __restrict__ pmaxb, const float* __restrict__ psumb,
    const float* __restrict__ xfr, const float* __restrict__ f1w,
    const float* __restrict__ f1b, const float* __restrict__ f2w,
    const float* __restrict__ f2b, float* __restrict__ perbuf) {
  int bt = blockIdx.x, q = threadIdx.x;
  const float* mb = pmaxb + (size_t)bt*4*256 + q;
  const float* sb = psumb + (size_t)bt*4*256 + q;
  float mx = -INFINITY, sm = 0.f;
#pragma unroll
  for (int i = 0; i < 4; ++i) {
    mx = fmaxf(mx, mb[i*256]);
    sm += sb[i*256];
  }
  perbuf[(size_t)bt*576 + q] = mx;
  perbuf[(size_t)bt*576 + 256 + q] = sm * (1.0f/256.0f);

  if (q < 64) {
    float x0 = xfr[bt*4], x1 = xfr[bt*4+1], x2 = xfr[bt*4+2], x3 = xfr[bt*4+3];
    float acc = f2b[q];
#pragma unroll
    for (int e = 0; e < 32; ++e) {
      float hv = f1b[e];
      hv = fmaf(x0, f1w[e], hv);
      hv = fmaf(x1, f1w[32+e], hv);
      hv = fmaf(x2, f1w[64+e], hv);
      hv = fmaf(x3, f1w[96+e], hv);
      acc = fmaf(gelu_f(hv), f2w[e*64 + q], acc);
    }
    perbuf[(size_t)bt*576 + 512 + q] = acc;
  }
}

// ---------------- K6: 1x1 projection conv ----------------
__global__ __launch_bounds__(256) void proj_kernel(
    const float* __restrict__ per, const float* __restrict__ projw,
    const float* __restrict__ projb, float* __restrict__ hout) {
  __shared__ __align__(16) float sp[576];
  int bt = blockIdx.x, c = threadIdx.x;
  for (int i = c; i < 576; i += 256) sp[i] = per[(size_t)bt*576 + i];
  __syncthreads();
  float acc = projb[c];
  const float* wr = projw + (size_t)c*576;
  for (int i = 0; i < 144; ++i) {
    float4 wv = *(const float4*)(wr + i*4);
    float4 pv = *(const float4*)(sp + i*4);
    acc = fmaf(wv.x, pv.x, acc); acc = fmaf(wv.y, pv.y, acc);
    acc = fmaf(wv.z, pv.z, acc); acc = fmaf(wv.w, pv.w, acc);
  }
  hout[(size_t)bt*256 + c] = acc;
}

// ---------------- K7: conv3 + bn + gelu (+residual) ----------------
__global__ __launch_bounds__(256) void conv_bn_kernel(
    const float* __restrict__ hin, float* __restrict__ hout,
    const float* __restrict__ w, const float* __restrict__ bias,
    const float* __restrict__ g, const float* __restrict__ be,
    const float* __restrict__ m, const float* __restrict__ v,
    int residual) {
  __shared__ __align__(16) float win[768];
  int bt = blockIdx.x, b = bt >> 5, t = bt & 31;
  int c = threadIdx.x;
  for (int i = c; i < 768; i += 256) {
    int cin = i / 3, dt = i - cin*3;
    int tt = t + dt - 1;
    win[i] = (tt >= 0 && tt < 32) ? hin[((size_t)b*32 + tt)*256 + cin] : 0.0f;
  }
  __syncthreads();
  float acc = bias[c];
  const float* wr = w + (size_t)c*768;
  for (int i = 0; i < 192; ++i) {
    float4 wv = *(const float4*)(wr + i*4);
    float4 pv = *(const float4*)(win + i*4);
    acc = fmaf(wv.x, pv.x, acc); acc = fmaf(wv.y, pv.y, acc);
    acc = fmaf(wv.z, pv.z, acc); acc = fmaf(wv.w, pv.w, acc);
  }
  float rsv = 1.0f / sqrtf(v[c] + 1e-5f);
  float y = (acc - m[c]) * rsv * g[c] + be[c];
  y = gelu_f(y);
  if (residual) y += win[c*3 + 1];
  hout[(size_t)bt*256 + c] = y;
}

// ---------------- K8: max-pool over T + head ----------------
__global__ __launch_bounds__(256) void poolhead_kernel(
    const float* __restrict__ hs, const float* __restrict__ h1w,
    const float* __restrict__ h1b, const float* __restrict__ h2w,
    const float* __restrict__ h2b, float* __restrict__ out) {
  __shared__ float pooled[256];
  __shared__ float hh[128];
  int b = blockIdx.x, tid = threadIdx.x;
  float mx = -INFINITY;
  for (int t = 0; t < 32; ++t)
    mx = fmaxf(mx, hs[((size_t)b*32 + t)*256 + tid]);
  pooled[tid] = mx;
  __syncthreads();
  if (tid < 128) {
    float acc = h1b[tid];
    for (int e = 0; e < 256; ++e) acc = fmaf(pooled[e], h1w[e*128 + tid], acc);
    hh[tid] = gelu_f(acc);
  }
  __syncthreads();
  if (tid < 25) {
    float acc = h2b[tid];
    for (int e = 0; e < 128; ++e) acc = fmaf(hh[e], h2w[e*25 + tid], acc);
    out[b*25 + tid] = acc;
  }
}

// ---------------- launch ----------------
extern "C" void kernel_launch(void* const* d_in, const int* in_sizes, int n_in,
                              void* d_out, int out_size, void* d_ws, size_t ws_size,
                              hipStream_t stream) {
  const float* x_pt = (const float*)d_in[0];
  const float* x_fr = (const float*)d_in[1];
  const float* ew1  = (const float*)d_in[2];
  const float* eg1  = (const float*)d_in[3];
  const float* eb1  = (const float*)d_in[4];
  const float* em1  = (const float*)d_in[5];
  const float* ev1  = (const float*)d_in[6];
  const float* ew2  = (const float*)d_in[7];
  const float* eg2  = (const float*)d_in[8];
  const float* eb2  = (const float*)d_in[9];
  const float* em2  = (const float*)d_in[10];
  const float* ev2  = (const float*)d_in[11];
  const float* p1w  = (const float*)d_in[12];
  const float* p1b  = (const float*)d_in[13];
  const float* ln1g = (const float*)d_in[14];
  const float* ln1b = (const float*)d_in[15];
  const float* p2w  = (const float*)d_in[16];
  const float* p2b  = (const float*)d_in[17];
  const float* ln2g = (const float*)d_in[18];
  const float* ln2b = (const float*)d_in[19];
  const float* f1w  = (const float*)d_in[20];
  const float* f1b  = (const float*)d_in[21];
  const float* f2w  = (const float*)d_in[22];
  const float* f2b  = (const float*)d_in[23];
  const float* projw= (const float*)d_in[24];
  const float* projb= (const float*)d_in[25];
  const float* cw[4] = {(const float*)d_in[26],(const float*)d_in[32],(const float*)d_in[38],(const float*)d_in[44]};
  const float* cb[4] = {(const float*)d_in[27],(const float*)d_in[33],(const float*)d_in[39],(const float*)d_in[45]};
  const float* cg[4] = {(const float*)d_in[28],(const float*)d_in[34],(const float*)d_in[40],(const float*)d_in[46]};
  const float* cbe[4]= {(const float*)d_in[29],(const float*)d_in[35],(const float*)d_in[41],(const float*)d_in[47]};
  const float* cm[4] = {(const float*)d_in[30],(const float*)d_in[36],(const float*)d_in[42],(const float*)d_in[48]};
  const float* cv[4] = {(const float*)d_in[31],(const float*)d_in[37],(const float*)d_in[43],(const float*)d_in[49]};
  const float* h1w  = (const float*)d_in[50];
  const float* h1b  = (const float*)d_in[51];
  const float* h2w  = (const float*)d_in[52];
  const float* h2b  = (const float*)d_in[53];
  float* out = (float*)d_out;

  char* ws = (char*)d_ws;
  int*   idxw   = (int*)ws;                          // 4 MB (dead after edgeconv)
  float* perbuf = (float*)ws;                        // reused after edgeconv
  float* hs0    = (float*)(ws + 0x90000);
  float* hs1    = (float*)(ws + 0x90000 + 0x40000);
  float* hs2    = (float*)(ws + 0x90000 + 2*0x40000);
  float* hs3    = (float*)(ws + 0x90000 + 3*0x40000);
  float* hs4    = (float*)(ws + 0x90000 + 4*0x40000);
  float* Af     = (float*)(ws + ((size_t)4  << 20)); // dead after edgeconv
  float* Bfw    = (float*)(ws + ((size_t)20 << 20)); // dead after edgeconv
  float* localf = (float*)(ws + ((size_t)36 << 20));
  float* pmaxb  = (float*)(ws + ((size_t)4  << 20)); // reuse Af region: 1 MB
  float* psumb  = (float*)(ws + ((size_t)8  << 20)); // 1 MB

  knn_kernel<<<NBT*64, 256, 0, stream>>>(x_pt, idxw);
  featAB_kernel<<<(NBT*NP*64)/256, 256, 0, stream>>>(x_pt, ew1, Af, Bfw);
  edgeconv_kernel<<<(NBT*NP)/NPB, 256, 0, stream>>>(Af, Bfw, idxw, ew2,
      eg1, eb1, em1, ev1, eg2, eb2, em2, ev2, localf);
  p1p2_kernel<<<NBT*4, 256, 0, stream>>>(localf, x_pt, p1w, p1b, ln1g, ln1b,
      p2w, p2b, ln2g, ln2b, pmaxb, psumb);
  p1p2_reduce_kernel<<<NBT, 256, 0, stream>>>(pmaxb, psumb, x_fr,
      f1w, f1b, f2w, f2b, perbuf);
  proj_kernel<<<NBT, 256, 0, stream>>>(perbuf, projw, projb, hs0);
  conv_bn_kernel<<<NBT, 256, 0, stream>>>(hs0, hs1, cw[0], cb[0], cg[0], cbe[0], cm[0], cv[0], 0);
  conv_bn_kernel<<<NBT, 256, 0, stream>>>(hs1, hs2, cw[1], cb[1], cg[1], cbe[1], cm[1], cv[1], 1);
  conv_bn_kernel<<<NBT, 256, 0, stream>>>(hs2, hs3, cw[2], cb[2], cg[2], cbe[2], cm[2], cv[2], 1);
  conv_bn_kernel<<<NBT, 256, 0, stream>>>(hs3, hs4, cw[3], cb[3], cg[3], cbe[3], cm[3], cv[3], 1);
  poolhead_kernel<<<8, 256, 0, stream>>>(hs4, h1w, h1b, h2w, h2b, out);
}

// Round 7
// 746.506 us; speedup vs baseline: 1.9288x; 1.1479x over previous
//
#include <hip/hip_runtime.h>
#include <math.h>

// ---------------- constants ----------------
#define NBT   256    // B*T
#define NP    256    // points per frame
#define NC    10     // point channels
#define KNN   16
#define NPB   8      // points per block in edgeconv

typedef unsigned short ushort_t;
typedef __attribute__((ext_vector_type(8))) short short8;
typedef __attribute__((ext_vector_type(4))) float f32x4;

__device__ __forceinline__ float gelu_f(float x) {
  return 0.5f * x * (1.0f + erff(x * 0.7071067811865476f));
}
__device__ __forceinline__ ushort_t f2bf(float f) {   // RNE fp32 -> bf16
  unsigned u = __float_as_uint(f);
  return (ushort_t)((u + 0x7FFFu + ((u >> 16) & 1u)) >> 16);
}

// ---------------- K1: knn (wave-per-point, branchless top-16) ----------------
__global__ __launch_bounds__(256) void knn_kernel(const float* __restrict__ x_pt,
                                                  int* __restrict__ idx) {
  __shared__ float sx[NP], sy[NP], sz[NP], ssq[NP];
  int bt = blockIdx.x >> 6;
  int p0 = (blockIdx.x & 63) * 4;
  int tid = threadIdx.x;
  const float* xb = x_pt + (size_t)bt * NP * NC;
  {
    int q = tid;
    float x0 = xb[q*NC+0], x1 = xb[q*NC+1], x2 = xb[q*NC+2];
    sx[q] = x0; sy[q] = x1; sz[q] = x2;
    ssq[q] = x0*x0 + x1*x1 + x2*x2;
  }
  __syncthreads();

  int wv = tid >> 6, lane = tid & 63;
  int p = p0 + wv;
  float px = sx[p], py = sy[p], pz = sz[p], psq = ssq[p];

  unsigned k0, k1, k2, k3;
  {
    unsigned kk[4];
#pragma unroll
    for (int c = 0; c < 4; ++c) {
      int q = lane + c*64;
      float d = psq + ssq[q] - 2.0f*(px*sx[q] + py*sy[q] + pz*sz[q]);
      d = fmaxf(d, 0.0f);
      kk[c] = (__float_as_uint(d) & 0xFFFFFF00u) | (unsigned)q;
    }
    unsigned a0 = min(kk[0], kk[1]), a1 = max(kk[0], kk[1]);
    unsigned a2 = min(kk[2], kk[3]), a3 = max(kk[2], kk[3]);
    unsigned b0 = min(a0, a2), b2 = max(a0, a2);
    unsigned b1 = min(a1, a3), b3 = max(a1, a3);
    k0 = b0; k1 = min(b1, b2); k2 = max(b1, b2); k3 = b3;
  }

  unsigned cur = k0, mykeep = 0u;
#pragma unroll
  for (int r = 0; r < 16; ++r) {
    unsigned w = cur;
    w = min(w, (unsigned)__shfl_xor((int)w, 1));
    w = min(w, (unsigned)__shfl_xor((int)w, 2));
    w = min(w, (unsigned)__shfl_xor((int)w, 4));
    w = min(w, (unsigned)__shfl_xor((int)w, 8));
    w = min(w, (unsigned)__shfl_xor((int)w, 16));
    w = min(w, (unsigned)__shfl_xor((int)w, 32));
    bool win = (cur == w);
    cur = win ? k1 : cur;
    k1  = win ? k2 : k1;
    k2  = win ? k3 : k2;
    k3  = win ? 0xFFFFFFFFu : k3;
    if (lane == r) mykeep = w;
  }
  if (lane < 16)
    idx[((size_t)bt*NP + p)*KNN + lane] = (int)(mykeep & 0xFFu);
}

// ---------------- K2: factored layer-1 features ----------------
__global__ __launch_bounds__(256) void featAB_kernel(const float* __restrict__ x_pt,
                                                     const float* __restrict__ ew1,
                                                     float* __restrict__ Af,
                                                     float* __restrict__ Bf) {
  int t = blockIdx.x*256 + threadIdx.x;
  int o = t & 63, p = t >> 6;
  const float* xr = x_pt + (size_t)p*NC;
  float a = 0.f, b = 0.f;
#pragma unroll
  for (int e = 0; e < NC; ++e) {
    float w1 = ew1[o*20 + e], w2 = ew1[o*20 + 10 + e];
    float xv = xr[e];
    a = fmaf(xv, w1 - w2, a);
    b = fmaf(xv, w2, b);
  }
  Af[(size_t)p*64 + o] = a;
  Bf[(size_t)p*64 + o] = b;
}

// ---------------- K3: edgeconv layer2 via bf16 MFMA + max over k ----------------
// Per block: 8 points -> GEMM [128 rows = 8pt x 16k][128 q], K=64.
// h1 (bf16) in LDS [128][72] rows (144B stride: 2-way bank alias = free, 16B aligned).
// w2T[q][o] = ew2 layout directly, bf16 [128][72].
// MFMA 16x16x32_bf16: A lane l: row=l&15, k=(l>>4)*8+j; D: col=l&15, row=(l>>4)*4+reg.
__global__ __launch_bounds__(256, 2) void edgeconv_kernel(
    const float* __restrict__ Af, const float* __restrict__ Bf,
    const int* __restrict__ idx, const float* __restrict__ ew2,
    const float* __restrict__ eg1, const float* __restrict__ eb1,
    const float* __restrict__ em1, const float* __restrict__ ev1,
    const float* __restrict__ eg2, const float* __restrict__ eb2,
    const float* __restrict__ em2, const float* __restrict__ ev2,
    float* __restrict__ localf) {
  __shared__ __align__(16) ushort_t h1s[128*72];
  __shared__ __align__(16) ushort_t w2T[128*72];
  __shared__ float sc1[64], sh1[64], sc2[128], sh2[128];
  __shared__ int idxs[128];

  int tid = threadIdx.x;
  int p0  = blockIdx.x * NPB;
  int bt  = p0 >> 8;

  // stage w2T (ew2 is [q][o] row-major already)
  for (int i = tid; i < 8192; i += 256)
    w2T[(i >> 6)*72 + (i & 63)] = f2bf(ew2[i]);
  if (tid < 128) idxs[tid] = idx[(size_t)p0*16 + tid];
  if (tid < 64) {
    float s = eg1[tid] * (1.0f / sqrtf(ev1[tid] + 1e-5f));
    sc1[tid] = s; sh1[tid] = eb1[tid] - em1[tid]*s;
  }
  if (tid >= 64 && tid < 192) {
    int q = tid - 64;
    float s = eg2[q] * (1.0f / sqrtf(ev2[q] + 1e-5f));
    sc2[q] = s; sh2[q] = eb2[q] - em2[q]*s;
  }
  __syncthreads();

  // build h1 = bf16(gelu(bn1(A[p] + B[idx]))) into h1s[pt*16+k][o]
  {
    int o = tid & 63, g = tid >> 6;
    float s1 = sc1[o], h1v = sh1[o];
    const float* Bbase = Bf + (size_t)bt*NP*64 + o;
#pragma unroll
    for (int pi = 0; pi < 2; ++pi) {
      int pt = g*2 + pi;
      float af = Af[((size_t)(p0+pt))*64 + o];
      ushort_t* hrow = h1s + (pt*16)*72 + o;
      for (int k = 0; k < KNN; ++k) {
        int j = idxs[pt*16 + k];
        float hv = af + Bbase[(size_t)j*64];
        hrow[k*72] = f2bf(gelu_f(fmaf(hv, s1, h1v)));
      }
    }
  }
  __syncthreads();

  // MFMA: wave w handles points {2w, 2w+1} x all 8 col-tiles
  int w = tid >> 6, l = tid & 63;
  int m_lo = l & 15, kq = l >> 4;

  short8 afr[2][2];
#pragma unroll
  for (int pt = 0; pt < 2; ++pt)
#pragma unroll
    for (int ks = 0; ks < 2; ++ks)
      afr[pt][ks] = *(const short8*)&h1s[((2*w+pt)*16 + m_lo)*72 + ks*32 + kq*8];

  f32x4 acc[2][8];
#pragma unroll
  for (int pt = 0; pt < 2; ++pt)
#pragma unroll
    for (int ct = 0; ct < 8; ++ct) acc[pt][ct] = (f32x4){0.f,0.f,0.f,0.f};

#pragma unroll
  for (int ct = 0; ct < 8; ++ct) {
#pragma unroll
    for (int ks = 0; ks < 2; ++ks) {
      short8 bfr = *(const short8*)&w2T[(ct*16 + m_lo)*72 + ks*32 + kq*8];
      acc[0][ct] = __builtin_amdgcn_mfma_f32_16x16x32_bf16(afr[0][ks], bfr, acc[0][ct], 0, 0, 0);
      acc[1][ct] = __builtin_amdgcn_mfma_f32_16x16x32_bf16(afr[1][ks], bfr, acc[1][ct], 0, 0, 0);
    }
  }

  // epilogue: bn2 affine -> min/max over k (4 regs + cross-quad shfl) -> 2 gelu
#pragma unroll
  for (int pt = 0; pt < 2; ++pt) {
    int gp = p0 + 2*w + pt;
#pragma unroll
    for (int ct = 0; ct < 8; ++ct) {
      int q = ct*16 + m_lo;
      float sc = sc2[q], sh = sh2[q];
      f32x4 a = acc[pt][ct];
      float mn = INFINITY, mx = -INFINITY;
#pragma unroll
      for (int r = 0; r < 4; ++r) {
        float y = fmaf(a[r], sc, sh);
        mn = fminf(mn, y); mx = fmaxf(mx, y);
      }
      mn = fminf(mn, __shfl_xor(mn, 16));
      mn = fminf(mn, __shfl_xor(mn, 32));
      mx = fmaxf(mx, __shfl_xor(mx, 16));
      mx = fmaxf(mx, __shfl_xor(mx, 32));
      if (l < 16) {
        float res = fmaxf(gelu_f(mn), gelu_f(mx));
        localf[(size_t)gp*128 + q] = res;
      }
    }
  }
}

// ---------------- K4: p1p2, register-tiled GEMMs with LDS weight tiles ----------------
__global__ __launch_bounds__(256, 2) void p1p2_kernel(
    const float* __restrict__ localf, const float* __restrict__ x_pt,
    const float* __restrict__ p1w, const float* __restrict__ p1b,
    const float* __restrict__ ln1g, const float* __restrict__ ln1b,
    const float* __restrict__ p2w, const float* __restrict__ p2b,
    const float* __restrict__ ln2g, const float* __restrict__ ln2b,
    float* __restrict__ pmaxb, float* __restrict__ psumb) {
  __shared__ __align__(16) float sA[64*148];
  __shared__ __align__(16) float sW[46*128];
  int blk = blockIdx.x;
  int bt = blk >> 2, ch = blk & 3;
  int tid = threadIdx.x;
  int pgrp = tid >> 4, g = tid & 15;
  size_t gbase = (size_t)bt*NP + ch*64;

  for (int i = tid; i < 64*32; i += 256) {
    int pp = i >> 5, v = i & 31;
    *(float4*)(sA + pp*148 + v*4) =
        *(const float4*)(localf + (gbase+pp)*128 + v*4);
  }
  for (int i = tid; i < 640; i += 256) {
    int pp = i / 10, e = i - pp*10;
    sA[pp*148 + 128 + e] = x_pt[(gbase+pp)*NC + e];
  }

  float a0[8], a1[8], a2[8], a3[8];
#pragma unroll
  for (int j = 0; j < 8; ++j) { float b = p1b[g*8+j]; a0[j]=b; a1[j]=b; a2[j]=b; a3[j]=b; }
  const float4* sWf4 = (const float4*)sW;
  for (int t = 0; t < 3; ++t) {
    __syncthreads();
    for (int i = tid; i < 1472; i += 256)
      ((float4*)sW)[i] = ((const float4*)(p1w + t*46*128))[i];
    __syncthreads();
    const float* fA = sA + (pgrp*4)*148 + t*46;
#pragma unroll 2
    for (int el = 0; el < 46; ++el) {
      float4 w0 = sWf4[el*32 + g*2];
      float4 w1 = sWf4[el*32 + g*2 + 1];
      float wv[8] = {w0.x,w0.y,w0.z,w0.w,w1.x,w1.y,w1.z,w1.w};
      float f0 = fA[el], f1 = fA[148+el], f2 = fA[296+el], f3 = fA[444+el];
#pragma unroll
      for (int j = 0; j < 8; ++j) {
        a0[j] = fmaf(f0, wv[j], a0[j]);
        a1[j] = fmaf(f1, wv[j], a1[j]);
        a2[j] = fmaf(f2, wv[j], a2[j]);
        a3[j] = fmaf(f3, wv[j], a3[j]);
      }
    }
  }
  __syncthreads();

  {
    float* ap[4] = {a0, a1, a2, a3};
    float g1v[8], b1v[8];
#pragma unroll
    for (int j = 0; j < 8; ++j) { g1v[j] = ln1g[g*8+j]; b1v[j] = ln1b[g*8+j]; }
#pragma unroll
    for (int i = 0; i < 4; ++i) {
      float* a = ap[i];
      float s = 0.f;
#pragma unroll
      for (int j = 0; j < 8; ++j) s += a[j];
      s += __shfl_xor(s,1); s += __shfl_xor(s,2); s += __shfl_xor(s,4); s += __shfl_xor(s,8);
      float mu = s * (1.0f/128.0f);
      float s2 = 0.f;
#pragma unroll
      for (int j = 0; j < 8; ++j) { float d = a[j]-mu; s2 += d*d; }
      s2 += __shfl_xor(s2,1); s2 += __shfl_xor(s2,2); s2 += __shfl_xor(s2,4); s2 += __shfl_xor(s2,8);
      float rs = 1.0f / sqrtf(s2*(1.0f/128.0f) + 1e-5f);
      float h[8];
#pragma unroll
      for (int j = 0; j < 8; ++j)
        h[j] = gelu_f((a[j]-mu)*rs*g1v[j] + b1v[j]);
      float* hp = sA + (pgrp*4+i)*140 + g*8;
      *(float4*)hp     = make_float4(h[0],h[1],h[2],h[3]);
      *(float4*)(hp+4) = make_float4(h[4],h[5],h[6],h[7]);
    }
  }

  float c00[8], c01[8], c02[8], c03[8];
  float c10[8], c11[8], c12[8], c13[8];
#pragma unroll
  for (int j = 0; j < 8; ++j) {
    float bA = p2b[g*8+j], bB = p2b[128 + g*8+j];
    c00[j]=bA; c01[j]=bA; c02[j]=bA; c03[j]=bA;
    c10[j]=bB; c11[j]=bB; c12[j]=bB; c13[j]=bB;
  }
  for (int t = 0; t < 8; ++t) {
    __syncthreads();
    for (int i = tid; i < 1024; i += 256)
      ((float4*)sW)[i] = ((const float4*)(p2w + t*16*256))[i];
    __syncthreads();
    const float* hA = sA + (pgrp*4)*140 + t*16;
#pragma unroll 2
    for (int el = 0; el < 16; ++el) {
      float f0 = hA[el], f1 = hA[140+el], f2 = hA[280+el], f3 = hA[420+el];
      float4 wa = sWf4[el*64 + g*2];
      float4 wb = sWf4[el*64 + g*2 + 1];
      float wv[8] = {wa.x,wa.y,wa.z,wa.w,wb.x,wb.y,wb.z,wb.w};
#pragma unroll
      for (int j = 0; j < 8; ++j) {
        c00[j] = fmaf(f0, wv[j], c00[j]);
        c01[j] = fmaf(f1, wv[j], c01[j]);
        c02[j] = fmaf(f2, wv[j], c02[j]);
        c03[j] = fmaf(f3, wv[j], c03[j]);
      }
      float4 wc = sWf4[el*64 + 32 + g*2];
      float4 wd = sWf4[el*64 + 32 + g*2 + 1];
      float wu[8] = {wc.x,wc.y,wc.z,wc.w,wd.x,wd.y,wd.z,wd.w};
#pragma unroll
      for (int j = 0; j < 8; ++j) {
        c10[j] = fmaf(f0, wu[j], c10[j]);
        c11[j] = fmaf(f1, wu[j], c11[j]);
        c12[j] = fmaf(f2, wu[j], c12[j]);
        c13[j] = fmaf(f3, wu[j], c13[j]);
      }
    }
  }
  __syncthreads();

  float pm0[8], ps0[8], pm1[8], ps1[8];
#pragma unroll
  for (int j = 0; j < 8; ++j) { pm0[j] = pm1[j] = -INFINITY; ps0[j] = ps1[j] = 0.f; }
  {
    float* cA[4] = {c00, c01, c02, c03};
    float* cB[4] = {c10, c11, c12, c13};
    float g2a[8], b2a[8], g2b[8], b2b[8];
#pragma unroll
    for (int j = 0; j < 8; ++j) {
      g2a[j] = ln2g[g*8+j];      b2a[j] = ln2b[g*8+j];
      g2b[j] = ln2g[128+g*8+j];  b2b[j] = ln2b[128+g*8+j];
    }
#pragma unroll
    for (int i = 0; i < 4; ++i) {
      float* ca = cA[i]; float* cb = cB[i];
      float s = 0.f;
#pragma unroll
      for (int j = 0; j < 8; ++j) s += ca[j] + cb[j];
      s += __shfl_xor(s,1); s += __shfl_xor(s,2); s += __shfl_xor(s,4); s += __shfl_xor(s,8);
      float mu = s * (1.0f/256.0f);
      float s2 = 0.f;
#pragma unroll
      for (int j = 0; j < 8; ++j) {
        float d1 = ca[j]-mu, d2 = cb[j]-mu; s2 += d1*d1 + d2*d2;
      }
      s2 += __shfl_xor(s2,1); s2 += __shfl_xor(s2,2); s2 += __shfl_xor(s2,4); s2 += __shfl_xor(s2,8);
      float rs = 1.0f / sqrtf(s2*(1.0f/256.0f) + 1e-5f);
#pragma unroll
      for (int j = 0; j < 8; ++j) {
        float v1 = gelu_f((ca[j]-mu)*rs*g2a[j] + b2a[j]);
        float v2 = gelu_f((cb[j]-mu)*rs*g2b[j] + b2b[j]);
        pm0[j] = fmaxf(pm0[j], v1); ps0[j] += v1;
        pm1[j] = fmaxf(pm1[j], v2); ps1[j] += v2;
      }
    }
  }

  {
    float* pool = sW;
    *(float4*)(pool + pgrp*256 + g*8)       = make_float4(pm0[0],pm0[1],pm0[2],pm0[3]);
    *(float4*)(pool + pgrp*256 + g*8 + 4)   = make_float4(pm0[4],pm0[5],pm0[6],pm0[7]);
    *(float4*)(pool + pgrp*256 + 128 + g*8)     = make_float4(pm1[0],pm1[1],pm1[2],pm1[3]);
    *(float4*)(pool + pgrp*256 + 128 + g*8 + 4) = make_float4(pm1[4],pm1[5],pm1[6],pm1[7]);
    __syncthreads();
    float mx = -INFINITY;
#pragma unroll
    for (int r = 0; r < 16; ++r) mx = fmaxf(mx, pool[r*256 + tid]);
    pmaxb[(size_t)blk*256 + tid] = mx;
    __syncthreads();
    *(float4*)(pool + pgrp*256 + g*8)       = make_float4(ps0[0],ps0[1],ps0[2],ps0[3]);
    *(float4*)(pool + pgrp*256 + g*8 + 4)   = make_float4(ps0[4],ps0[5],ps0[6],ps0[7]);
    *(float4*)(pool + pgrp*256 + 128 + g*8)     = make_float4(ps1[0],ps1[1],ps1[2],ps1[3]);
    *(float4*)(pool + pgrp*256 + 128 + g*8 + 4) = make_float4(ps1[4],ps1[5],ps1[6],ps1[7]);
    __syncthreads();
    float sm = 0.f;
#pragma unroll
    for (int r = 0; r < 16; ++r) sm += pool[r*256 + tid];
    psumb[(size_t)blk*256 + tid] = sm;
  }
}

// ---------------- K4b: combine partials + frame MLP ----------------
__global__ __launch_bounds__(256) void p1p2_reduce_kernel(
    const float* __restrict__ pmaxb, const float* __restrict__ psumb,
    const float* __restrict__ xfr, const float* __restrict__ f1w,
    const float* __restrict__ f1b, const float* __restrict__ f2w,
    const float* __restrict__ f2b, float* __restrict__ perbuf) {
  int bt = blockIdx.x, q = threadIdx.x;
  const float* mb = pmaxb + (size_t)bt*4*256 + q;
  const float* sb = psumb + (size_t)bt*4*256 + q;
  float mx = -INFINITY, sm = 0.f;
#pragma unroll
  for (int i = 0; i < 4; ++i) {
    mx = fmaxf(mx, mb[i*256]);
    sm += sb[i*256];
  }
  perbuf[(size_t)bt*576 + q] = mx;
  perbuf[(size_t)bt*576 + 256 + q] = sm * (1.0f/256.0f);

  if (q < 64) {
    float x0 = xfr[bt*4], x1 = xfr[bt*4+1], x2 = xfr[bt*4+2], x3 = xfr[bt*4+3];
    float acc = f2b[q];
#pragma unroll
    for (int e = 0; e < 32; ++e) {
      float hv = f1b[e];
      hv = fmaf(x0, f1w[e], hv);
      hv = fmaf(x1, f1w[32+e], hv);
      hv = fmaf(x2, f1w[64+e], hv);
      hv = fmaf(x3, f1w[96+e], hv);
      acc = fmaf(gelu_f(hv), f2w[e*64 + q], acc);
    }
    perbuf[(size_t)bt*576 + 512 + q] = acc;
  }
}

// ---------------- K6: 1x1 projection conv ----------------
__global__ __launch_bounds__(256) void proj_kernel(
    const float* __restrict__ per, const float* __restrict__ projw,
    const float* __restrict__ projb, float* __restrict__ hout) {
  __shared__ __align__(16) float sp[576];
  int bt = blockIdx.x, c = threadIdx.x;
  for (int i = c; i < 576; i += 256) sp[i] = per[(size_t)bt*576 + i];
  __syncthreads();
  float acc = projb[c];
  const float* wr = projw + (size_t)c*576;
  for (int i = 0; i < 144; ++i) {
    float4 wv = *(const float4*)(wr + i*4);
    float4 pv = *(const float4*)(sp + i*4);
    acc = fmaf(wv.x, pv.x, acc); acc = fmaf(wv.y, pv.y, acc);
    acc = fmaf(wv.z, pv.z, acc); acc = fmaf(wv.w, pv.w, acc);
  }
  hout[(size_t)bt*256 + c] = acc;
}

// ---------------- K7: conv3 + bn + gelu (+residual) ----------------
__global__ __launch_bounds__(256) void conv_bn_kernel(
    const float* __restrict__ hin, float* __restrict__ hout,
    const float* __restrict__ w, const float* __restrict__ bias,
    const float* __restrict__ g, const float* __restrict__ be,
    const float* __restrict__ m, const float* __restrict__ v,
    int residual) {
  __shared__ __align__(16) float win[768];
  int bt = blockIdx.x, b = bt >> 5, t = bt & 31;
  int c = threadIdx.x;
  for (int i = c; i < 768; i += 256) {
    int cin = i / 3, dt = i - cin*3;
    int tt = t + dt - 1;
    win[i] = (tt >= 0 && tt < 32) ? hin[((size_t)b*32 + tt)*256 + cin] : 0.0f;
  }
  __syncthreads();
  float acc = bias[c];
  const float* wr = w + (size_t)c*768;
  for (int i = 0; i < 192; ++i) {
    float4 wv = *(const float4*)(wr + i*4);
    float4 pv = *(const float4*)(win + i*4);
    acc = fmaf(wv.x, pv.x, acc); acc = fmaf(wv.y, pv.y, acc);
    acc = fmaf(wv.z, pv.z, acc); acc = fmaf(wv.w, pv.w, acc);
  }
  float rsv = 1.0f / sqrtf(v[c] + 1e-5f);
  float y = (acc - m[c]) * rsv * g[c] + be[c];
  y = gelu_f(y);
  if (residual) y += win[c*3 + 1];
  hout[(size_t)bt*256 + c] = y;
}

// ---------------- K8: max-pool over T + head ----------------
__global__ __launch_bounds__(256) void poolhead_kernel(
    const float* __restrict__ hs, const float* __restrict__ h1w,
    const float* __restrict__ h1b, const float* __restrict__ h2w,
    const float* __restrict__ h2b, float* __restrict__ out) {
  __shared__ float pooled[256];
  __shared__ float hh[128];
  int b = blockIdx.x, tid = threadIdx.x;
  float mx = -INFINITY;
  for (int t = 0; t < 32; ++t)
    mx = fmaxf(mx, hs[((size_t)b*32 + t)*256 + tid]);
  pooled[tid] = mx;
  __syncthreads();
  if (tid < 128) {
    float acc = h1b[tid];
    for (int e = 0; e < 256; ++e) acc = fmaf(pooled[e], h1w[e*128 + tid], acc);
    hh[tid] = gelu_f(acc);
  }
  __syncthreads();
  if (tid < 25) {
    float acc = h2b[tid];
    for (int e = 0; e < 128; ++e) acc = fmaf(hh[e], h2w[e*25 + tid], acc);
    out[b*25 + tid] = acc;
  }
}

// ---------------- launch ----------------
extern "C" void kernel_launch(void* const* d_in, const int* in_sizes, int n_in,
                              void* d_out, int out_size, void* d_ws, size_t ws_size,
                              hipStream_t stream) {
  const float* x_pt = (const float*)d_in[0];
  const float* x_fr = (const float*)d_in[1];
  const float* ew1  = (const float*)d_in[2];
  const float* eg1  = (const float*)d_in[3];
  const float* eb1  = (const float*)d_in[4];
  const float* em1  = (const float*)d_in[5];
  const float* ev1  = (const float*)d_in[6];
  const float* ew2  = (const float*)d_in[7];
  const float* eg2  = (const float*)d_in[8];
  const float* eb2  = (const float*)d_in[9];
  const float* em2  = (const float*)d_in[10];
  const float* ev2  = (const float*)d_in[11];
  const float* p1w  = (const float*)d_in[12];
  const float* p1b  = (const float*)d_in[13];
  const float* ln1g = (const float*)d_in[14];
  const float* ln1b = (const float*)d_in[15];
  const float* p2w  = (const float*)d_in[16];
  const float* p2b  = (const float*)d_in[17];
  const float* ln2g = (const float*)d_in[18];
  const float* ln2b = (const float*)d_in[19];
  const float* f1w  = (const float*)d_in[20];
  const float* f1b  = (const float*)d_in[21];
  const float* f2w  = (const float*)d_in[22];
  const float* f2b  = (const float*)d_in[23];
  const float* projw= (const float*)d_in[24];
  const float* projb= (const float*)d_in[25];
  const float* cw[4] = {(const float*)d_in[26],(const float*)d_in[32],(const float*)d_in[38],(const float*)d_in[44]};
  const float* cb[4] = {(const float*)d_in[27],(const float*)d_in[33],(const float*)d_in[39],(const float*)d_in[45]};
  const float* cg[4] = {(const float*)d_in[28],(const float*)d_in[34],(const float*)d_in[40],(const float*)d_in[46]};
  const float* cbe[4]= {(const float*)d_in[29],(const float*)d_in[35],(const float*)d_in[41],(const float*)d_in[47]};
  const float* cm[4] = {(const float*)d_in[30],(const float*)d_in[36],(const float*)d_in[42],(const float*)d_in[48]};
  const float* cv[4] = {(const float*)d_in[31],(const float*)d_in[37],(const float*)d_in[43],(const float*)d_in[49]};
  const float* h1w  = (const float*)d_in[50];
  const float* h1b  = (const float*)d_in[51];
  const float* h2w  = (const float*)d_in[52];
  const float* h2b  = (const float*)d_in[53];
  float* out = (float*)d_out;

  char* ws = (char*)d_ws;
  int*   idxw   = (int*)ws;                          // 4 MB (dead after edgeconv)
  float* perbuf = (float*)ws;                        // reused after edgeconv
  float* hs0    = (float*)(ws + 0x90000);
  float* hs1    = (float*)(ws + 0x90000 + 0x40000);
  float* hs2    = (float*)(ws + 0x90000 + 2*0x40000);
  float* hs3    = (float*)(ws + 0x90000 + 3*0x40000);
  float* hs4    = (float*)(ws + 0x90000 + 4*0x40000);
  float* Af     = (float*)(ws + ((size_t)4  << 20)); // dead after edgeconv
  float* Bfw    = (float*)(ws + ((size_t)20 << 20)); // dead after edgeconv
  float* localf = (float*)(ws + ((size_t)36 << 20));
  float* pmaxb  = (float*)(ws + ((size_t)4  << 20)); // reuse Af region: 1 MB
  float* psumb  = (float*)(ws + ((size_t)8  << 20)); // 1 MB

  knn_kernel<<<NBT*64, 256, 0, stream>>>(x_pt, idxw);
  featAB_kernel<<<(NBT*NP*64)/256, 256, 0, stream>>>(x_pt, ew1, Af, Bfw);
  edgeconv_kernel<<<(NBT*NP)/NPB, 256, 0, stream>>>(Af, Bfw, idxw, ew2,
      eg1, eb1, em1, ev1, eg2, eb2, em2, ev2, localf);
  p1p2_kernel<<<NBT*4, 256, 0, stream>>>(localf, x_pt, p1w, p1b, ln1g, ln1b,
      p2w, p2b, ln2g, ln2b, pmaxb, psumb);
  p1p2_reduce_kernel<<<NBT, 256, 0, stream>>>(pmaxb, psumb, x_fr,
      f1w, f1b, f2w, f2b, perbuf);
  proj_kernel<<<NBT, 256, 0, stream>>>(perbuf, projw, projb, hs0);
  conv_bn_kernel<<<NBT, 256, 0, stream>>>(hs0, hs1, cw[0], cb[0], cg[0], cbe[0], cm[0], cv[0], 0);
  conv_bn_kernel<<<NBT, 256, 0, stream>>>(hs1, hs2, cw[1], cb[1], cg[1], cbe[1], cm[1], cv[1], 1);
  conv_bn_kernel<<<NBT, 256, 0, stream>>>(hs2, hs3, cw[2], cb[2], cg[2], cbe[2], cm[2], cv[2], 1);
  conv_bn_kernel<<<NBT, 256, 0, stream>>>(hs3, hs4, cw[3], cb[3], cg[3], cbe[3], cm[3], cv[3], 1);
  poolhead_kernel<<<8, 256, 0, stream>>>(hs4, h1w, h1b, h2w, h2b, out);
}

// Round 8
// 604.517 us; speedup vs baseline: 2.3819x; 1.2349x over previous
//
#include <hip/hip_runtime.h>
#include <math.h>

// ---------------- constants ----------------
#define NBT   256    // B*T
#define NP    256    // points per frame
#define NC    10     // point channels
#define KNN   16
#define NPB   8      // points per block in edgeconv

typedef unsigned short ushort_t;
typedef __attribute__((ext_vector_type(8))) short short8;
typedef __attribute__((ext_vector_type(4))) float f32x4;

__device__ __forceinline__ float gelu_f(float x) {
  return 0.5f * x * (1.0f + erff(x * 0.7071067811865476f));
}
__device__ __forceinline__ ushort_t f2bf(float f) {   // RNE fp32 -> bf16
  unsigned u = __float_as_uint(f);
  return (ushort_t)((u + 0x7FFFu + ((u >> 16) & 1u)) >> 16);
}

// ---------------- K1: knn (wave-per-point, branchless top-16) ----------------
__global__ __launch_bounds__(256) void knn_kernel(const float* __restrict__ x_pt,
                                                  int* __restrict__ idx) {
  __shared__ float sx[NP], sy[NP], sz[NP], ssq[NP];
  int bt = blockIdx.x >> 6;
  int p0 = (blockIdx.x & 63) * 4;
  int tid = threadIdx.x;
  const float* xb = x_pt + (size_t)bt * NP * NC;
  {
    int q = tid;
    float x0 = xb[q*NC+0], x1 = xb[q*NC+1], x2 = xb[q*NC+2];
    sx[q] = x0; sy[q] = x1; sz[q] = x2;
    ssq[q] = x0*x0 + x1*x1 + x2*x2;
  }
  __syncthreads();

  int wv = tid >> 6, lane = tid & 63;
  int p = p0 + wv;
  float px = sx[p], py = sy[p], pz = sz[p], psq = ssq[p];

  unsigned k0, k1, k2, k3;
  {
    unsigned kk[4];
#pragma unroll
    for (int c = 0; c < 4; ++c) {
      int q = lane + c*64;
      float d = psq + ssq[q] - 2.0f*(px*sx[q] + py*sy[q] + pz*sz[q]);
      d = fmaxf(d, 0.0f);
      kk[c] = (__float_as_uint(d) & 0xFFFFFF00u) | (unsigned)q;
    }
    unsigned a0 = min(kk[0], kk[1]), a1 = max(kk[0], kk[1]);
    unsigned a2 = min(kk[2], kk[3]), a3 = max(kk[2], kk[3]);
    unsigned b0 = min(a0, a2), b2 = max(a0, a2);
    unsigned b1 = min(a1, a3), b3 = max(a1, a3);
    k0 = b0; k1 = min(b1, b2); k2 = max(b1, b2); k3 = b3;
  }

  unsigned cur = k0, mykeep = 0u;
#pragma unroll
  for (int r = 0; r < 16; ++r) {
    unsigned w = cur;
    w = min(w, (unsigned)__shfl_xor((int)w, 1));
    w = min(w, (unsigned)__shfl_xor((int)w, 2));
    w = min(w, (unsigned)__shfl_xor((int)w, 4));
    w = min(w, (unsigned)__shfl_xor((int)w, 8));
    w = min(w, (unsigned)__shfl_xor((int)w, 16));
    w = min(w, (unsigned)__shfl_xor((int)w, 32));
    bool win = (cur == w);
    cur = win ? k1 : cur;
    k1  = win ? k2 : k1;
    k2  = win ? k3 : k2;
    k3  = win ? 0xFFFFFFFFu : k3;
    if (lane == r) mykeep = w;
  }
  if (lane < 16)
    idx[((size_t)bt*NP + p)*KNN + lane] = (int)(mykeep & 0xFFu);
}

// ---------------- K2: factored layer-1 features ----------------
__global__ __launch_bounds__(256) void featAB_kernel(const float* __restrict__ x_pt,
                                                     const float* __restrict__ ew1,
                                                     float* __restrict__ Af,
                                                     float* __restrict__ Bf) {
  int t = blockIdx.x*256 + threadIdx.x;
  int o = t & 63, p = t >> 6;
  const float* xr = x_pt + (size_t)p*NC;
  float a = 0.f, b = 0.f;
#pragma unroll
  for (int e = 0; e < NC; ++e) {
    float w1 = ew1[o*20 + e], w2 = ew1[o*20 + 10 + e];
    float xv = xr[e];
    a = fmaf(xv, w1 - w2, a);
    b = fmaf(xv, w2, b);
  }
  Af[(size_t)p*64 + o] = a;
  Bf[(size_t)p*64 + o] = b;
}

// ---------------- K3: edgeconv layer2 via bf16 MFMA + max over k ----------------
__global__ __launch_bounds__(256, 2) void edgeconv_kernel(
    const float* __restrict__ Af, const float* __restrict__ Bf,
    const int* __restrict__ idx, const float* __restrict__ ew2,
    const float* __restrict__ eg1, const float* __restrict__ eb1,
    const float* __restrict__ em1, const float* __restrict__ ev1,
    const float* __restrict__ eg2, const float* __restrict__ eb2,
    const float* __restrict__ em2, const float* __restrict__ ev2,
    float* __restrict__ localf) {
  __shared__ __align__(16) ushort_t h1s[128*72];
  __shared__ __align__(16) ushort_t w2T[128*72];
  __shared__ float sc1[64], sh1[64], sc2[128], sh2[128];
  __shared__ int idxs[128];

  int tid = threadIdx.x;
  int p0  = blockIdx.x * NPB;
  int bt  = p0 >> 8;

  for (int i = tid; i < 8192; i += 256)
    w2T[(i >> 6)*72 + (i & 63)] = f2bf(ew2[i]);
  if (tid < 128) idxs[tid] = idx[(size_t)p0*16 + tid];
  if (tid < 64) {
    float s = eg1[tid] * (1.0f / sqrtf(ev1[tid] + 1e-5f));
    sc1[tid] = s; sh1[tid] = eb1[tid] - em1[tid]*s;
  }
  if (tid >= 64 && tid < 192) {
    int q = tid - 64;
    float s = eg2[q] * (1.0f / sqrtf(ev2[q] + 1e-5f));
    sc2[q] = s; sh2[q] = eb2[q] - em2[q]*s;
  }
  __syncthreads();

  {
    int o = tid & 63, g = tid >> 6;
    float s1 = sc1[o], h1v = sh1[o];
    const float* Bbase = Bf + (size_t)bt*NP*64 + o;
#pragma unroll
    for (int pi = 0; pi < 2; ++pi) {
      int pt = g*2 + pi;
      float af = Af[((size_t)(p0+pt))*64 + o];
      ushort_t* hrow = h1s + (pt*16)*72 + o;
      for (int k = 0; k < KNN; ++k) {
        int j = idxs[pt*16 + k];
        float hv = af + Bbase[(size_t)j*64];
        hrow[k*72] = f2bf(gelu_f(fmaf(hv, s1, h1v)));
      }
    }
  }
  __syncthreads();

  int w = tid >> 6, l = tid & 63;
  int m_lo = l & 15, kq = l >> 4;

  short8 afr[2][2];
#pragma unroll
  for (int pt = 0; pt < 2; ++pt)
#pragma unroll
    for (int ks = 0; ks < 2; ++ks)
      afr[pt][ks] = *(const short8*)&h1s[((2*w+pt)*16 + m_lo)*72 + ks*32 + kq*8];

  f32x4 acc[2][8];
#pragma unroll
  for (int pt = 0; pt < 2; ++pt)
#pragma unroll
    for (int ct = 0; ct < 8; ++ct) acc[pt][ct] = (f32x4){0.f,0.f,0.f,0.f};

#pragma unroll
  for (int ct = 0; ct < 8; ++ct) {
#pragma unroll
    for (int ks = 0; ks < 2; ++ks) {
      short8 bfr = *(const short8*)&w2T[(ct*16 + m_lo)*72 + ks*32 + kq*8];
      acc[0][ct] = __builtin_amdgcn_mfma_f32_16x16x32_bf16(afr[0][ks], bfr, acc[0][ct], 0, 0, 0);
      acc[1][ct] = __builtin_amdgcn_mfma_f32_16x16x32_bf16(afr[1][ks], bfr, acc[1][ct], 0, 0, 0);
    }
  }

#pragma unroll
  for (int pt = 0; pt < 2; ++pt) {
    int gp = p0 + 2*w + pt;
#pragma unroll
    for (int ct = 0; ct < 8; ++ct) {
      int q = ct*16 + m_lo;
      float sc = sc2[q], sh = sh2[q];
      f32x4 a = acc[pt][ct];
      float mn = INFINITY, mx = -INFINITY;
#pragma unroll
      for (int r = 0; r < 4; ++r) {
        float y = fmaf(a[r], sc, sh);
        mn = fminf(mn, y); mx = fmaxf(mx, y);
      }
      mn = fminf(mn, __shfl_xor(mn, 16));
      mn = fminf(mn, __shfl_xor(mn, 32));
      mx = fmaxf(mx, __shfl_xor(mx, 16));
      mx = fmaxf(mx, __shfl_xor(mx, 32));
      if (l < 16) {
        float res = fmaxf(gelu_f(mn), gelu_f(mx));
        localf[(size_t)gp*128 + q] = res;
      }
    }
  }
}

// ---------------- K3b: weight prep for p1p2 MFMA (runs after edgeconv) ----------------
// w1b: [128 o][168 e] bf16, e<138 from p1w[e][o] else 0
// w2b: [256 q][136 e] bf16, e<128 from p2w[e][q] else 0
__global__ __launch_bounds__(256) void prep_kernel(
    const float* __restrict__ p1w, const float* __restrict__ p2w,
    ushort_t* __restrict__ w1b, ushort_t* __restrict__ w2b) {
  int i = blockIdx.x*256 + threadIdx.x;
  if (i < 128*168) {
    int o = i / 168, e = i - o*168;
    float v = (e < 138) ? p1w[e*128 + o] : 0.f;
    w1b[i] = f2bf(v);
  } else {
    int j = i - 128*168;
    if (j < 256*136) {
      int q = j / 136, e = j - q*136;
      float v = (e < 128) ? p2w[e*256 + q] : 0.f;
      w2b[j] = f2bf(v);
    }
  }
}

// ---------------- K4: p1p2 via bf16 MFMA ----------------
// Grid NBT*4, 256 threads (4 waves), 64 points/block. Wave w owns m-tile w (16 points).
// sA [64][168]us: feat bf16 (GEMM1, K padded to 160) then h1 bf16 in cols 0..127 (GEMM2).
// wt: w1 tile [128][168]us (GEMM1) then w2 halves [128][136]us (GEMM2).
// D layout per r7-validated mapping: point=(l>>4)*4+reg, channel=ct*16+(l&15).
__global__ __launch_bounds__(256, 2) void p1p2_kernel(
    const float* __restrict__ localf, const float* __restrict__ x_pt,
    const ushort_t* __restrict__ w1b, const ushort_t* __restrict__ w2b,
    const float* __restrict__ p1b,
    const float* __restrict__ ln1g, const float* __restrict__ ln1b,
    const float* __restrict__ p2b,
    const float* __restrict__ ln2g, const float* __restrict__ ln2b,
    float* __restrict__ pmaxb, float* __restrict__ psumb) {
  __shared__ __align__(16) ushort_t sA[64*168];   // 21,504 B
  __shared__ __align__(16) ushort_t wt[128*168];  // 43,008 B
  __shared__ float pm4[4*256], ps4[4*256];        //  8,192 B
  int blk = blockIdx.x;
  int bt = blk >> 2, ch = blk & 3;
  int tid = threadIdx.x;
  size_t gbase = (size_t)bt*NP + ch*64;

  // ---- stage sA (feat -> bf16) + wt (w1b copy)
  for (int i = tid; i < 64*32; i += 256) {
    int pp = i >> 5, v = i & 31;
    float4 f4 = *(const float4*)(localf + (gbase+pp)*128 + v*4);
    ushort_t* dst = sA + pp*168 + v*4;
    dst[0]=f2bf(f4.x); dst[1]=f2bf(f4.y); dst[2]=f2bf(f4.z); dst[3]=f2bf(f4.w);
  }
  for (int i = tid; i < 64*40; i += 256) {
    int pp = i / 40, e = i - pp*40;
    ushort_t v = 0;
    if (e < 10) v = f2bf(x_pt[(gbase+pp)*NC + e]);
    sA[pp*168 + 128 + e] = v;
  }
  for (int i = tid; i < 2688; i += 256)
    ((uint4*)wt)[i] = ((const uint4*)w1b)[i];
  __syncthreads();                                            // B1

  int w = tid >> 6, l = tid & 63;
  int lo = l & 15, kq = l >> 4;

  // ---- GEMM1: M=16 (wave m-tile), N=128 (8 ct), K=160 (5 ks)
  short8 af1[5];
#pragma unroll
  for (int ks = 0; ks < 5; ++ks)
    af1[ks] = *(const short8*)&sA[(w*16 + lo)*168 + ks*32 + kq*8];
  f32x4 acc1[8];
#pragma unroll
  for (int ct = 0; ct < 8; ++ct) {
    float b = p1b[ct*16 + lo];
    acc1[ct] = (f32x4){b, b, b, b};
  }
#pragma unroll
  for (int ct = 0; ct < 8; ++ct) {
#pragma unroll
    for (int ks = 0; ks < 5; ++ks) {
      short8 bf = *(const short8*)&wt[(ct*16 + lo)*168 + ks*32 + kq*8];
      acc1[ct] = __builtin_amdgcn_mfma_f32_16x16x32_bf16(af1[ks], bf, acc1[ct], 0, 0, 0);
    }
  }
  __syncthreads();                                            // B2

  // ---- LN1 + gelu -> h1 bf16 into sA cols 0..127 ; stage w2 half 0
  {
    float g1v[8], b1v[8];
#pragma unroll
    for (int ct = 0; ct < 8; ++ct) { g1v[ct] = ln1g[ct*16+lo]; b1v[ct] = ln1b[ct*16+lo]; }
#pragma unroll
    for (int r = 0; r < 4; ++r) {
      float s = 0.f;
#pragma unroll
      for (int ct = 0; ct < 8; ++ct) s += acc1[ct][r];
      s += __shfl_xor(s,1); s += __shfl_xor(s,2); s += __shfl_xor(s,4); s += __shfl_xor(s,8);
      float mu = s * (1.0f/128.0f);
      float s2 = 0.f;
#pragma unroll
      for (int ct = 0; ct < 8; ++ct) { float d = acc1[ct][r]-mu; s2 += d*d; }
      s2 += __shfl_xor(s2,1); s2 += __shfl_xor(s2,2); s2 += __shfl_xor(s2,4); s2 += __shfl_xor(s2,8);
      float rs = 1.0f / sqrtf(s2*(1.0f/128.0f) + 1e-5f);
      int row = w*16 + kq*4 + r;
#pragma unroll
      for (int ct = 0; ct < 8; ++ct) {
        float h = gelu_f((acc1[ct][r]-mu)*rs*g1v[ct] + b1v[ct]);
        sA[row*168 + ct*16 + lo] = f2bf(h);
      }
    }
  }
  for (int i = tid; i < 2176; i += 256)
    ((uint4*)wt)[i] = ((const uint4*)w2b)[i];
  __syncthreads();                                            // B3

  // ---- GEMM2: K=128 (4 ks), N=256 in two halves
  short8 af2[4];
#pragma unroll
  for (int ks = 0; ks < 4; ++ks)
    af2[ks] = *(const short8*)&sA[(w*16 + lo)*168 + ks*32 + kq*8];
  f32x4 acc2[16];
#pragma unroll
  for (int ct = 0; ct < 8; ++ct) {
    float bA = p2b[ct*16 + lo], bB = p2b[128 + ct*16 + lo];
    acc2[ct]   = (f32x4){bA, bA, bA, bA};
    acc2[8+ct] = (f32x4){bB, bB, bB, bB};
  }
#pragma unroll
  for (int ct = 0; ct < 8; ++ct) {
#pragma unroll
    for (int ks = 0; ks < 4; ++ks) {
      short8 bf = *(const short8*)&wt[(ct*16 + lo)*136 + ks*32 + kq*8];
      acc2[ct] = __builtin_amdgcn_mfma_f32_16x16x32_bf16(af2[ks], bf, acc2[ct], 0, 0, 0);
    }
  }
  __syncthreads();                                            // B4
  for (int i = tid; i < 2176; i += 256)
    ((uint4*)wt)[i] = ((const uint4*)(w2b + 17408))[i];
  __syncthreads();                                            // B5
#pragma unroll
  for (int ct = 0; ct < 8; ++ct) {
#pragma unroll
    for (int ks = 0; ks < 4; ++ks) {
      short8 bf = *(const short8*)&wt[(ct*16 + lo)*136 + ks*32 + kq*8];
      acc2[8+ct] = __builtin_amdgcn_mfma_f32_16x16x32_bf16(af2[ks], bf, acc2[8+ct], 0, 0, 0);
    }
  }

  // ---- LN2 + gelu + pooling partials
  float vmax[16], vsum[16];
  {
    float g2v[16], b2v[16];
#pragma unroll
    for (int j = 0; j < 16; ++j) {
      int c = (j >= 8 ? 128 : 0) + (j & 7)*16 + lo;
      g2v[j] = ln2g[c]; b2v[j] = ln2b[c];
    }
#pragma unroll
    for (int j = 0; j < 16; ++j) { vmax[j] = -INFINITY; vsum[j] = 0.f; }
#pragma unroll
    for (int r = 0; r < 4; ++r) {
      float s = 0.f;
#pragma unroll
      for (int j = 0; j < 16; ++j) s += acc2[j][r];
      s += __shfl_xor(s,1); s += __shfl_xor(s,2); s += __shfl_xor(s,4); s += __shfl_xor(s,8);
      float mu = s * (1.0f/256.0f);
      float s2 = 0.f;
#pragma unroll
      for (int j = 0; j < 16; ++j) { float d = acc2[j][r]-mu; s2 += d*d; }
      s2 += __shfl_xor(s2,1); s2 += __shfl_xor(s2,2); s2 += __shfl_xor(s2,4); s2 += __shfl_xor(s2,8);
      float rs = 1.0f / sqrtf(s2*(1.0f/256.0f) + 1e-5f);
#pragma unroll
      for (int j = 0; j < 16; ++j) {
        float v = gelu_f((acc2[j][r]-mu)*rs*g2v[j] + b2v[j]);
        vmax[j] = fmaxf(vmax[j], v);
        vsum[j] += v;
      }
    }
  }
#pragma unroll
  for (int j = 0; j < 16; ++j) {
    float m = vmax[j], s = vsum[j];
    m = fmaxf(m, __shfl_xor(m, 16)); m = fmaxf(m, __shfl_xor(m, 32));
    s += __shfl_xor(s, 16);          s += __shfl_xor(s, 32);
    if (l < 16) {
      int c = (j >= 8 ? 128 : 0) + (j & 7)*16 + l;
      pm4[w*256 + c] = m;
      ps4[w*256 + c] = s;
    }
  }
  __syncthreads();                                            // B6
  {
    int c = tid;
    float mx = fmaxf(fmaxf(pm4[c], pm4[256+c]), fmaxf(pm4[512+c], pm4[768+c]));
    float sm = ps4[c] + ps4[256+c] + ps4[512+c] + ps4[768+c];
    pmaxb[(size_t)blk*256 + c] = mx;
    psumb[(size_t)blk*256 + c] = sm;
  }
}

// ---------------- K4b: combine partials + frame MLP ----------------
__global__ __launch_bounds__(256) void p1p2_reduce_kernel(
    const float* __restrict__ pmaxb, const float* __restrict__ psumb,
    const float* __restrict__ xfr, const float* __restrict__ f1w,
    const float* __restrict__ f1b, const float* __restrict__ f2w,
    const float* __restrict__ f2b, float* __restrict__ perbuf) {
  int bt = blockIdx.x, q = threadIdx.x;
  const float* mb = pmaxb + (size_t)bt*4*256 + q;
  const float* sb = psumb + (size_t)bt*4*256 + q;
  float mx = -INFINITY, sm = 0.f;
#pragma unroll
  for (int i = 0; i < 4; ++i) {
    mx = fmaxf(mx, mb[i*256]);
    sm += sb[i*256];
  }
  perbuf[(size_t)bt*576 + q] = mx;
  perbuf[(size_t)bt*576 + 256 + q] = sm * (1.0f/256.0f);

  if (q < 64) {
    float x0 = xfr[bt*4], x1 = xfr[bt*4+1], x2 = xfr[bt*4+2], x3 = xfr[bt*4+3];
    float acc = f2b[q];
#pragma unroll
    for (int e = 0; e < 32; ++e) {
      float hv = f1b[e];
      hv = fmaf(x0, f1w[e], hv);
      hv = fmaf(x1, f1w[32+e], hv);
      hv = fmaf(x2, f1w[64+e], hv);
      hv = fmaf(x3, f1w[96+e], hv);
      acc = fmaf(gelu_f(hv), f2w[e*64 + q], acc);
    }
    perbuf[(size_t)bt*576 + 512 + q] = acc;
  }
}

// ---------------- K6: 1x1 projection conv ----------------
__global__ __launch_bounds__(256) void proj_kernel(
    const float* __restrict__ per, const float* __restrict__ projw,
    const float* __restrict__ projb, float* __restrict__ hout) {
  __shared__ __align__(16) float sp[576];
  int bt = blockIdx.x, c = threadIdx.x;
  for (int i = c; i < 576; i += 256) sp[i] = per[(size_t)bt*576 + i];
  __syncthreads();
  float acc = projb[c];
  const float* wr = projw + (size_t)c*576;
  for (int i = 0; i < 144; ++i) {
    float4 wv = *(const float4*)(wr + i*4);
    float4 pv = *(const float4*)(sp + i*4);
    acc = fmaf(wv.x, pv.x, acc); acc = fmaf(wv.y, pv.y, acc);
    acc = fmaf(wv.z, pv.z, acc); acc = fmaf(wv.w, pv.w, acc);
  }
  hout[(size_t)bt*256 + c] = acc;
}

// ---------------- K7: conv3 + bn + gelu (+residual) ----------------
__global__ __launch_bounds__(256) void conv_bn_kernel(
    const float* __restrict__ hin, float* __restrict__ hout,
    const float* __restrict__ w, const float* __restrict__ bias,
    const float* __restrict__ g, const float* __restrict__ be,
    const float* __restrict__ m, const float* __restrict__ v,
    int residual) {
  __shared__ __align__(16) float win[768];
  int bt = blockIdx.x, b = bt >> 5, t = bt & 31;
  int c = threadIdx.x;
  for (int i = c; i < 768; i += 256) {
    int cin = i / 3, dt = i - cin*3;
    int tt = t + dt - 1;
    win[i] = (tt >= 0 && tt < 32) ? hin[((size_t)b*32 + tt)*256 + cin] : 0.0f;
  }
  __syncthreads();
  float acc = bias[c];
  const float* wr = w + (size_t)c*768;
  for (int i = 0; i < 192; ++i) {
    float4 wv = *(const float4*)(wr + i*4);
    float4 pv = *(const float4*)(win + i*4);
    acc = fmaf(wv.x, pv.x, acc); acc = fmaf(wv.y, pv.y, acc);
    acc = fmaf(wv.z, pv.z, acc); acc = fmaf(wv.w, pv.w, acc);
  }
  float rsv = 1.0f / sqrtf(v[c] + 1e-5f);
  float y = (acc - m[c]) * rsv * g[c] + be[c];
  y = gelu_f(y);
  if (residual) y += win[c*3 + 1];
  hout[(size_t)bt*256 + c] = y;
}

// ---------------- K8: max-pool over T + head ----------------
__global__ __launch_bounds__(256) void poolhead_kernel(
    const float* __restrict__ hs, const float* __restrict__ h1w,
    const float* __restrict__ h1b, const float* __restrict__ h2w,
    const float* __restrict__ h2b, float* __restrict__ out) {
  __shared__ float pooled[256];
  __shared__ float hh[128];
  int b = blockIdx.x, tid = threadIdx.x;
  float mx = -INFINITY;
  for (int t = 0; t < 32; ++t)
    mx = fmaxf(mx, hs[((size_t)b*32 + t)*256 + tid]);
  pooled[tid] = mx;
  __syncthreads();
  if (tid < 128) {
    float acc = h1b[tid];
    for (int e = 0; e < 256; ++e) acc = fmaf(pooled[e], h1w[e*128 + tid], acc);
    hh[tid] = gelu_f(acc);
  }
  __syncthreads();
  if (tid < 25) {
    float acc = h2b[tid];
    for (int e = 0; e < 128; ++e) acc = fmaf(hh[e], h2w[e*25 + tid], acc);
    out[b*25 + tid] = acc;
  }
}

// ---------------- launch ----------------
extern "C" void kernel_launch(void* const* d_in, const int* in_sizes, int n_in,
                              void* d_out, int out_size, void* d_ws, size_t ws_size,
                              hipStream_t stream) {
  const float* x_pt = (const float*)d_in[0];
  const float* x_fr = (const float*)d_in[1];
  const float* ew1  = (const float*)d_in[2];
  const float* eg1  = (const float*)d_in[3];
  const float* eb1  = (const float*)d_in[4];
  const float* em1  = (const float*)d_in[5];
  const float* ev1  = (const float*)d_in[6];
  const float* ew2  = (const float*)d_in[7];
  const float* eg2  = (const float*)d_in[8];
  const float* eb2  = (const float*)d_in[9];
  const float* em2  = (const float*)d_in[10];
  const float* ev2  = (const float*)d_in[11];
  const float* p1w  = (const float*)d_in[12];
  const float* p1b  = (const float*)d_in[13];
  const float* ln1g = (const float*)d_in[14];
  const float* ln1b = (const float*)d_in[15];
  const float* p2w  = (const float*)d_in[16];
  const float* p2b  = (const float*)d_in[17];
  const float* ln2g = (const float*)d_in[18];
  const float* ln2b = (const float*)d_in[19];
  const float* f1w  = (const float*)d_in[20];
  const float* f1b  = (const float*)d_in[21];
  const float* f2w  = (const float*)d_in[22];
  const float* f2b  = (const float*)d_in[23];
  const float* projw= (const float*)d_in[24];
  const float* projb= (const float*)d_in[25];
  const float* cw[4] = {(const float*)d_in[26],(const float*)d_in[32],(const float*)d_in[38],(const float*)d_in[44]};
  const float* cb[4] = {(const float*)d_in[27],(const float*)d_in[33],(const float*)d_in[39],(const float*)d_in[45]};
  const float* cg[4] = {(const float*)d_in[28],(const float*)d_in[34],(const float*)d_in[40],(const float*)d_in[46]};
  const float* cbe[4]= {(const float*)d_in[29],(const float*)d_in[35],(const float*)d_in[41],(const float*)d_in[47]};
  const float* cm[4] = {(const float*)d_in[30],(const float*)d_in[36],(const float*)d_in[42],(const float*)d_in[48]};
  const float* cv[4] = {(const float*)d_in[31],(const float*)d_in[37],(const float*)d_in[43],(const float*)d_in[49]};
  const float* h1w  = (const float*)d_in[50];
  const float* h1b  = (const float*)d_in[51];
  const float* h2w  = (const float*)d_in[52];
  const float* h2b  = (const float*)d_in[53];
  float* out = (float*)d_out;

  char* ws = (char*)d_ws;
  int*   idxw   = (int*)ws;                          // 4 MB (dead after edgeconv)
  float* perbuf = (float*)ws;                        // reused after edgeconv
  float* hs0    = (float*)(ws + 0x90000);
  float* hs1    = (float*)(ws + 0x90000 + 0x40000);
  float* hs2    = (float*)(ws + 0x90000 + 2*0x40000);
  float* hs3    = (float*)(ws + 0x90000 + 3*0x40000);
  float* hs4    = (float*)(ws + 0x90000 + 4*0x40000);
  float* Af     = (float*)(ws + ((size_t)4  << 20)); // dead after edgeconv
  float* Bfw    = (float*)(ws + ((size_t)20 << 20)); // dead after edgeconv
  float* localf = (float*)(ws + ((size_t)36 << 20));
  // post-edgeconv reuse of Af region:
  ushort_t* w1b = (ushort_t*)(ws + ((size_t)4 << 20));            // 43,008 B
  ushort_t* w2b = (ushort_t*)(ws + ((size_t)4 << 20) + 65536);    // 69,632 B
  float* pmaxb  = (float*)(ws + ((size_t)8  << 20));              // 1 MB
  float* psumb  = (float*)(ws + ((size_t)12 << 20));              // 1 MB

  knn_kernel<<<NBT*64, 256, 0, stream>>>(x_pt, idxw);
  featAB_kernel<<<(NBT*NP*64)/256, 256, 0, stream>>>(x_pt, ew1, Af, Bfw);
  edgeconv_kernel<<<(NBT*NP)/NPB, 256, 0, stream>>>(Af, Bfw, idxw, ew2,
      eg1, eb1, em1, ev1, eg2, eb2, em2, ev2, localf);
  prep_kernel<<<220, 256, 0, stream>>>(p1w, p2w, w1b, w2b);
  p1p2_kernel<<<NBT*4, 256, 0, stream>>>(localf, x_pt, w1b, w2b, p1b,
      ln1g, ln1b, p2b, ln2g, ln2b, pmaxb, psumb);
  p1p2_reduce_kernel<<<NBT, 256, 0, stream>>>(pmaxb, psumb, x_fr,
      f1w, f1b, f2w, f2b, perbuf);
  proj_kernel<<<NBT, 256, 0, stream>>>(perbuf, projw, projb, hs0);
  conv_bn_kernel<<<NBT, 256, 0, stream>>>(hs0, hs1, cw[0], cb[0], cg[0], cbe[0], cm[0], cv[0], 0);
  conv_bn_kernel<<<NBT, 256, 0, stream>>>(hs1, hs2, cw[1], cb[1], cg[1], cbe[1], cm[1], cv[1], 1);
  conv_bn_kernel<<<NBT, 256, 0, stream>>>(hs2, hs3, cw[2], cb[2], cg[2], cbe[2], cm[2], cv[2], 1);
  conv_bn_kernel<<<NBT, 256, 0, stream>>>(hs3, hs4, cw[3], cb[3], cg[3], cbe[3], cm[3], cv[3], 1);
  poolhead_kernel<<<8, 256, 0, stream>>>(hs4, h1w, h1b, h2w, h2b, out);
}

// Round 10
// 523.372 us; speedup vs baseline: 2.7512x; 1.1550x over previous
//
#include <hip/hip_runtime.h>
#include <math.h>

// ---------------- constants ----------------
#define NBT   256    // B*T
#define NP    256    // points per frame
#define NC    10     // point channels
#define KNN   16
#define NPB   8      // points per block in edgeconv

typedef unsigned short ushort_t;
typedef unsigned char uchar_t;
typedef __attribute__((ext_vector_type(8))) short short8;
typedef __attribute__((ext_vector_type(4))) float f32x4;

__device__ __forceinline__ float gelu_f(float x) {     // exact (tail kernels)
  return 0.5f * x * (1.0f + erff(x * 0.7071067811865476f));
}
// Branch-free erf (A&S 7.1.26, |err| <= 1.5e-7 abs) -> fast gelu for hot paths.
// Outputs land in bf16 or deep pre-LN activations; 3e-7 abs error is invisible
// next to bf16's 2^-9 rounding (absmax unchanged across r6-r8 at 0.015625).
__device__ __forceinline__ float gelu_fast(float x) {
  float u  = x * 0.7071067811865476f;
  float au = fabsf(u);
  float t  = __builtin_amdgcn_rcpf(fmaf(0.3275911f, au, 1.0f));
  float p  = fmaf(t, 1.061405429f, -1.453152027f);
  p = fmaf(t, p, 1.421413741f);
  p = fmaf(t, p, -0.284496736f);
  p = fmaf(t, p, 0.254829592f);
  p = p * t;
  float e  = __expf(-au * au);
  float er = fmaf(-p, e, 1.0f);               // erf(|u|)
  er = copysignf(er, u);
  return 0.5f * x * (1.0f + er);
}
__device__ __forceinline__ ushort_t f2bf(float f) {   // RNE fp32 -> bf16
  unsigned u = __float_as_uint(f);
  return (ushort_t)((u + 0x7FFFu + ((u >> 16) & 1u)) >> 16);
}

// ---------------- K1: knn (wave-per-point, branchless top-16, u8 output) ----------------
__global__ __launch_bounds__(256) void knn_kernel(const float* __restrict__ x_pt,
                                                  uchar_t* __restrict__ idx) {
  __shared__ float sx[NP], sy[NP], sz[NP], ssq[NP];
  int bt = blockIdx.x >> 6;
  int p0 = (blockIdx.x & 63) * 4;
  int tid = threadIdx.x;
  const float* xb = x_pt + (size_t)bt * NP * NC;
  {
    int q = tid;
    float x0 = xb[q*NC+0], x1 = xb[q*NC+1], x2 = xb[q*NC+2];
    sx[q] = x0; sy[q] = x1; sz[q] = x2;
    ssq[q] = x0*x0 + x1*x1 + x2*x2;
  }
  __syncthreads();

  int wv = tid >> 6, lane = tid & 63;
  int p = p0 + wv;
  float px = sx[p], py = sy[p], pz = sz[p], psq = ssq[p];

  unsigned k0, k1, k2, k3;
  {
    unsigned kk[4];
#pragma unroll
    for (int c = 0; c < 4; ++c) {
      int q = lane + c*64;
      float d = psq + ssq[q] - 2.0f*(px*sx[q] + py*sy[q] + pz*sz[q]);
      d = fmaxf(d, 0.0f);
      kk[c] = (__float_as_uint(d) & 0xFFFFFF00u) | (unsigned)q;
    }
    unsigned a0 = min(kk[0], kk[1]), a1 = max(kk[0], kk[1]);
    unsigned a2 = min(kk[2], kk[3]), a3 = max(kk[2], kk[3]);
    unsigned b0 = min(a0, a2), b2 = max(a0, a2);
    unsigned b1 = min(a1, a3), b3 = max(a1, a3);
    k0 = b0; k1 = min(b1, b2); k2 = max(b1, b2); k3 = b3;
  }

  unsigned cur = k0, mykeep = 0u;
#pragma unroll
  for (int r = 0; r < 16; ++r) {
    unsigned w = cur;
    w = min(w, (unsigned)__shfl_xor((int)w, 1));
    w = min(w, (unsigned)__shfl_xor((int)w, 2));
    w = min(w, (unsigned)__shfl_xor((int)w, 4));
    w = min(w, (unsigned)__shfl_xor((int)w, 8));
    w = min(w, (unsigned)__shfl_xor((int)w, 16));
    w = min(w, (unsigned)__shfl_xor((int)w, 32));
    bool win = (cur == w);
    cur = win ? k1 : cur;
    k1  = win ? k2 : k1;
    k2  = win ? k3 : k2;
    k3  = win ? 0xFFFFFFFFu : k3;
    if (lane == r) mykeep = w;
  }
  if (lane < 16)
    idx[((size_t)bt*NP + p)*KNN + lane] = (uchar_t)(mykeep & 0xFFu);
}

// ---------------- K2: factored layer-1 features ----------------
__global__ __launch_bounds__(256) void featAB_kernel(const float* __restrict__ x_pt,
                                                     const float* __restrict__ ew1,
                                                     float* __restrict__ Af,
                                                     float* __restrict__ Bf) {
  int t = blockIdx.x*256 + threadIdx.x;
  int o = t & 63, p = t >> 6;
  const float* xr = x_pt + (size_t)p*NC;
  float a = 0.f, b = 0.f;
#pragma unroll
  for (int e = 0; e < NC; ++e) {
    float w1 = ew1[o*20 + e], w2 = ew1[o*20 + 10 + e];
    float xv = xr[e];
    a = fmaf(xv, w1 - w2, a);
    b = fmaf(xv, w2, b);
  }
  Af[(size_t)p*64 + o] = a;
  Bf[(size_t)p*64 + o] = b;
}

// ---------------- K2b: weight prep (bf16 conversions, once) ----------------
// w1b: [128 o][168 e], e<138 from p1w[e][o] else 0
// w2b: [256 q][136 e], e<128 from p2w[e][q] else 0
// ew2b:[128 q][72  o], o<64  from ew2[q][o]  else 0
__global__ __launch_bounds__(256) void prep_kernel(
    const float* __restrict__ p1w, const float* __restrict__ p2w,
    const float* __restrict__ ew2,
    ushort_t* __restrict__ w1b, ushort_t* __restrict__ w2b,
    ushort_t* __restrict__ ew2b) {
  int i = blockIdx.x*256 + threadIdx.x;      // 0..65535 exactly
  if (i < 21504) {
    int o = i / 168, e = i - o*168;
    w1b[i] = f2bf((e < 138) ? p1w[e*128 + o] : 0.f);
  } else if (i < 56320) {
    int j = i - 21504;
    int q = j / 136, e = j - q*136;
    w2b[j] = f2bf((e < 128) ? p2w[e*256 + q] : 0.f);
  } else {
    int m = i - 56320;                       // 0..9215
    int q = m / 72, o = m - q*72;
    ew2b[m] = f2bf((o < 64) ? ew2[q*64 + o] : 0.f);
  }
}

// ---------------- K3: edgeconv layer2 via bf16 MFMA + max over k ----------------
__global__ __launch_bounds__(256, 2) void edgeconv_kernel(
    const float* __restrict__ Af, const float* __restrict__ Bf,
    const uchar_t* __restrict__ idx, const ushort_t* __restrict__ ew2b,
    const float* __restrict__ eg1, const float* __restrict__ eb1,
    const float* __restrict__ em1, const float* __restrict__ ev1,
    const float* __restrict__ eg2, const float* __restrict__ eb2,
    const float* __restrict__ em2, const float* __restrict__ ev2,
    float* __restrict__ localf) {
  __shared__ __align__(16) ushort_t h1s[128*72];
  __shared__ __align__(16) ushort_t w2T[128*72];
  __shared__ float sc1[64], sh1[64], sc2[128], sh2[128];
  __shared__ int idxs[128];

  int tid = threadIdx.x;
  // XCD swizzle (grid 8192 = 8*1024): each XCD gets 1024 consecutive work ids
  // -> a frame's 32 blocks share one L2 for the Bf gather.
  int bid = blockIdx.x;
  int wid = (bid & 7) * 1024 + (bid >> 3);
  int p0  = wid * NPB;
  int bt  = p0 >> 8;

  for (int i = tid; i < 1152; i += 256)          // 18,432 B vector copy
    ((uint4*)w2T)[i] = ((const uint4*)ew2b)[i];
  if (tid < 128) idxs[tid] = idx[(size_t)p0*16 + tid];
  if (tid < 64) {
    float s = eg1[tid] * (1.0f / sqrtf(ev1[tid] + 1e-5f));
    sc1[tid] = s; sh1[tid] = eb1[tid] - em1[tid]*s;
  }
  if (tid >= 64 && tid < 192) {
    int q = tid - 64;
    float s = eg2[q] * (1.0f / sqrtf(ev2[q] + 1e-5f));
    sc2[q] = s; sh2[q] = eb2[q] - em2[q]*s;
  }
  __syncthreads();

  // h1 = bf16(gelu(bn1(A[p] + B[idx])))
  {
    int o = tid & 63, g = tid >> 6;
    float s1 = sc1[o], h1v = sh1[o];
    const float* Bbase = Bf + (size_t)bt*NP*64 + o;
#pragma unroll
    for (int pi = 0; pi < 2; ++pi) {
      int pt = g*2 + pi;
      float af = Af[((size_t)(p0+pt))*64 + o];
      ushort_t* hrow = h1s + (pt*16)*72 + o;
      for (int k = 0; k < KNN; ++k) {
        int j = idxs[pt*16 + k];
        float hv = af + Bbase[(size_t)j*64];
        hrow[k*72] = f2bf(gelu_fast(fmaf(hv, s1, h1v)));
      }
    }
  }
  __syncthreads();

  int w = tid >> 6, l = tid & 63;
  int m_lo = l & 15, kq = l >> 4;

  short8 afr[2][2];
#pragma unroll
  for (int pt = 0; pt < 2; ++pt)
#pragma unroll
    for (int ks = 0; ks < 2; ++ks)
      afr[pt][ks] = *(const short8*)&h1s[((2*w+pt)*16 + m_lo)*72 + ks*32 + kq*8];

  f32x4 acc[2][8];
#pragma unroll
  for (int pt = 0; pt < 2; ++pt)
#pragma unroll
    for (int ct = 0; ct < 8; ++ct) acc[pt][ct] = (f32x4){0.f,0.f,0.f,0.f};

#pragma unroll
  for (int ct = 0; ct < 8; ++ct) {
#pragma unroll
    for (int ks = 0; ks < 2; ++ks) {
      short8 bfr = *(const short8*)&w2T[(ct*16 + m_lo)*72 + ks*32 + kq*8];
      acc[0][ct] = __builtin_amdgcn_mfma_f32_16x16x32_bf16(afr[0][ks], bfr, acc[0][ct], 0, 0, 0);
      acc[1][ct] = __builtin_amdgcn_mfma_f32_16x16x32_bf16(afr[1][ks], bfr, acc[1][ct], 0, 0, 0);
    }
  }

  // epilogue: bn2 -> min/max over k -> SPLIT gelu (kq-even: mn, kq-odd: mx)
#pragma unroll
  for (int pt = 0; pt < 2; ++pt) {
    int gp = p0 + 2*w + pt;
#pragma unroll
    for (int ct = 0; ct < 8; ++ct) {
      int q = ct*16 + m_lo;
      float sc = sc2[q], sh = sh2[q];
      f32x4 a = acc[pt][ct];
      float mn = INFINITY, mx = -INFINITY;
#pragma unroll
      for (int r = 0; r < 4; ++r) {
        float y = fmaf(a[r], sc, sh);
        mn = fminf(mn, y); mx = fmaxf(mx, y);
      }
      mn = fminf(mn, __shfl_xor(mn, 16));
      mn = fminf(mn, __shfl_xor(mn, 32));
      mx = fmaxf(mx, __shfl_xor(mx, 16));
      mx = fmaxf(mx, __shfl_xor(mx, 32));
      float g = gelu_fast((kq & 1) ? mx : mn);
      g = fmaxf(g, __shfl_xor(g, 16));
      if (l < 16)
        localf[(size_t)gp*128 + q] = g;
    }
  }
}

// ---------------- K4: p1p2 via bf16 MFMA ----------------
__global__ __launch_bounds__(256, 2) void p1p2_kernel(
    const float* __restrict__ localf, const float* __restrict__ x_pt,
    const ushort_t* __restrict__ w1b, const ushort_t* __restrict__ w2b,
    const float* __restrict__ p1b,
    const float* __restrict__ ln1g, const float* __restrict__ ln1b,
    const float* __restrict__ p2b,
    const float* __restrict__ ln2g, const float* __restrict__ ln2b,
    float* __restrict__ pmaxb, float* __restrict__ psumb) {
  __shared__ __align__(16) ushort_t sA[64*168];
  __shared__ __align__(16) ushort_t wt[128*168];
  __shared__ float pm4[4*256], ps4[4*256];
  int blk = blockIdx.x;
  int bt = blk >> 2, ch = blk & 3;
  int tid = threadIdx.x;
  size_t gbase = (size_t)bt*NP + ch*64;

  for (int i = tid; i < 64*32; i += 256) {
    int pp = i >> 5, v = i & 31;
    float4 f4 = *(const float4*)(localf + (gbase+pp)*128 + v*4);
    ushort_t* dst = sA + pp*168 + v*4;
    dst[0]=f2bf(f4.x); dst[1]=f2bf(f4.y); dst[2]=f2bf(f4.z); dst[3]=f2bf(f4.w);
  }
  for (int i = tid; i < 64*40; i += 256) {
    int pp = i / 40, e = i - pp*40;
    ushort_t v = 0;
    if (e < 10) v = f2bf(x_pt[(gbase+pp)*NC + e]);
    sA[pp*168 + 128 + e] = v;
  }
  for (int i = tid; i < 2688; i += 256)
    ((uint4*)wt)[i] = ((const uint4*)w1b)[i];
  __syncthreads();                                            // B1

  int w = tid >> 6, l = tid & 63;
  int lo = l & 15, kq = l >> 4;

  short8 af1[5];
#pragma unroll
  for (int ks = 0; ks < 5; ++ks)
    af1[ks] = *(const short8*)&sA[(w*16 + lo)*168 + ks*32 + kq*8];
  f32x4 acc1[8];
#pragma unroll
  for (int ct = 0; ct < 8; ++ct) {
    float b = p1b[ct*16 + lo];
    acc1[ct] = (f32x4){b, b, b, b};
  }
#pragma unroll
  for (int ct = 0; ct < 8; ++ct) {
#pragma unroll
    for (int ks = 0; ks < 5; ++ks) {
      short8 bf = *(const short8*)&wt[(ct*16 + lo)*168 + ks*32 + kq*8];
      acc1[ct] = __builtin_amdgcn_mfma_f32_16x16x32_bf16(af1[ks], bf, acc1[ct], 0, 0, 0);
    }
  }
  __syncthreads();                                            // B2

  {
    float g1v[8], b1v[8];
#pragma unroll
    for (int ct = 0; ct < 8; ++ct) { g1v[ct] = ln1g[ct*16+lo]; b1v[ct] = ln1b[ct*16+lo]; }
#pragma unroll
    for (int r = 0; r < 4; ++r) {
      float s = 0.f;
#pragma unroll
      for (int ct = 0; ct < 8; ++ct) s += acc1[ct][r];
      s += __shfl_xor(s,1); s += __shfl_xor(s,2); s += __shfl_xor(s,4); s += __shfl_xor(s,8);
      float mu = s * (1.0f/128.0f);
      float s2 = 0.f;
#pragma unroll
      for (int ct = 0; ct < 8; ++ct) { float d = acc1[ct][r]-mu; s2 += d*d; }
      s2 += __shfl_xor(s2,1); s2 += __shfl_xor(s2,2); s2 += __shfl_xor(s2,4); s2 += __shfl_xor(s2,8);
      float rs = 1.0f / sqrtf(s2*(1.0f/128.0f) + 1e-5f);
      int row = w*16 + kq*4 + r;
#pragma unroll
      for (int ct = 0; ct < 8; ++ct) {
        float h = gelu_fast((acc1[ct][r]-mu)*rs*g1v[ct] + b1v[ct]);
        sA[row*168 + ct*16 + lo] = f2bf(h);
      }
    }
  }
  for (int i = tid; i < 2176; i += 256)
    ((uint4*)wt)[i] = ((const uint4*)w2b)[i];
  __syncthreads();                                            // B3

  short8 af2[4];
#pragma unroll
  for (int ks = 0; ks < 4; ++ks)
    af2[ks] = *(const short8*)&sA[(w*16 + lo)*168 + ks*32 + kq*8];
  f32x4 acc2[16];
#pragma unroll
  for (int ct = 0; ct < 8; ++ct) {
    float bA = p2b[ct*16 + lo], bB = p2b[128 + ct*16 + lo];
    acc2[ct]   = (f32x4){bA, bA, bA, bA};
    acc2[8+ct] = (f32x4){bB, bB, bB, bB};
  }
#pragma unroll
  for (int ct = 0; ct < 8; ++ct) {
#pragma unroll
    for (int ks = 0; ks < 4; ++ks) {
      short8 bf = *(const short8*)&wt[(ct*16 + lo)*136 + ks*32 + kq*8];
      acc2[ct] = __builtin_amdgcn_mfma_f32_16x16x32_bf16(af2[ks], bf, acc2[ct], 0, 0, 0);
    }
  }
  __syncthreads();                                            // B4
  for (int i = tid; i < 2176; i += 256)
    ((uint4*)wt)[i] = ((const uint4*)(w2b + 17408))[i];
  __syncthreads();                                            // B5
#pragma unroll
  for (int ct = 0; ct < 8; ++ct) {
#pragma unroll
    for (int ks = 0; ks < 4; ++ks) {
      short8 bf = *(const short8*)&wt[(ct*16 + lo)*136 + ks*32 + kq*8];
      acc2[8+ct] = __builtin_amdgcn_mfma_f32_16x16x32_bf16(af2[ks], bf, acc2[8+ct], 0, 0, 0);
    }
  }

  float vmax[16], vsum[16];
  {
    float g2v[16], b2v[16];
#pragma unroll
    for (int j = 0; j < 16; ++j) {
      int c = (j >= 8 ? 128 : 0) + (j & 7)*16 + lo;
      g2v[j] = ln2g[c]; b2v[j] = ln2b[c];
    }
#pragma unroll
    for (int j = 0; j < 16; ++j) { vmax[j] = -INFINITY; vsum[j] = 0.f; }
#pragma unroll
    for (int r = 0; r < 4; ++r) {
      float s = 0.f;
#pragma unroll
      for (int j = 0; j < 16; ++j) s += acc2[j][r];
      s += __shfl_xor(s,1); s += __shfl_xor(s,2); s += __shfl_xor(s,4); s += __shfl_xor(s,8);
      float mu = s * (1.0f/256.0f);
      float s2 = 0.f;
#pragma unroll
      for (int j = 0; j < 16; ++j) { float d = acc2[j][r]-mu; s2 += d*d; }
      s2 += __shfl_xor(s2,1); s2 += __shfl_xor(s2,2); s2 += __shfl_xor(s2,4); s2 += __shfl_xor(s2,8);
      float rs = 1.0f / sqrtf(s2*(1.0f/256.0f) + 1e-5f);
#pragma unroll
      for (int j = 0; j < 16; ++j) {
        float v = gelu_fast((acc2[j][r]-mu)*rs*g2v[j] + b2v[j]);
        vmax[j] = fmaxf(vmax[j], v);
        vsum[j] += v;
      }
    }
  }
#pragma unroll
  for (int j = 0; j < 16; ++j) {
    float m = vmax[j], s = vsum[j];
    m = fmaxf(m, __shfl_xor(m, 16)); m = fmaxf(m, __shfl_xor(m, 32));
    s += __shfl_xor(s, 16);          s += __shfl_xor(s, 32);
    if (l < 16) {
      int c = (j >= 8 ? 128 : 0) + (j & 7)*16 + l;
      pm4[w*256 + c] = m;
      ps4[w*256 + c] = s;
    }
  }
  __syncthreads();                                            // B6
  {
    int c = tid;
    float mx = fmaxf(fmaxf(pm4[c], pm4[256+c]), fmaxf(pm4[512+c], pm4[768+c]));
    float sm = ps4[c] + ps4[256+c] + ps4[512+c] + ps4[768+c];
    pmaxb[(size_t)blk*256 + c] = mx;
    psumb[(size_t)blk*256 + c] = sm;
  }
}

// ---------------- K4b: combine partials + frame MLP ----------------
__global__ __launch_bounds__(256) void p1p2_reduce_kernel(
    const float* __restrict__ pmaxb, const float* __restrict__ psumb,
    const float* __restrict__ xfr, const float* __restrict__ f1w,
    const float* __restrict__ f1b, const float* __restrict__ f2w,
    const float* __restrict__ f2b, float* __restrict__ perbuf) {
  int bt = blockIdx.x, q = threadIdx.x;
  const float* mb = pmaxb + (size_t)bt*4*256 + q;
  const float* sb = psumb + (size_t)bt*4*256 + q;
  float mx = -INFINITY, sm = 0.f;
#pragma unroll
  for (int i = 0; i < 4; ++i) {
    mx = fmaxf(mx, mb[i*256]);
    sm += sb[i*256];
  }
  perbuf[(size_t)bt*576 + q] = mx;
  perbuf[(size_t)bt*576 + 256 + q] = sm * (1.0f/256.0f);

  if (q < 64) {
    float x0 = xfr[bt*4], x1 = xfr[bt*4+1], x2 = xfr[bt*4+2], x3 = xfr[bt*4+3];
    float acc = f2b[q];
#pragma unroll
    for (int e = 0; e < 32; ++e) {
      float hv = f1b[e];
      hv = fmaf(x0, f1w[e], hv);
      hv = fmaf(x1, f1w[32+e], hv);
      hv = fmaf(x2, f1w[64+e], hv);
      hv = fmaf(x3, f1w[96+e], hv);
      acc = fmaf(gelu_f(hv), f2w[e*64 + q], acc);
    }
    perbuf[(size_t)bt*576 + 512 + q] = acc;
  }
}

// ---------------- K6: 1x1 projection conv ----------------
__global__ __launch_bounds__(256) void proj_kernel(
    const float* __restrict__ per, const float* __restrict__ projw,
    const float* __restrict__ projb, float* __restrict__ hout) {
  __shared__ __align__(16) float sp[576];
  int bt = blockIdx.x, c = threadIdx.x;
  for (int i = c; i < 576; i += 256) sp[i] = per[(size_t)bt*576 + i];
  __syncthreads();
  float acc = projb[c];
  const float* wr = projw + (size_t)c*576;
  for (int i = 0; i < 144; ++i) {
    float4 wv = *(const float4*)(wr + i*4);
    float4 pv = *(const float4*)(sp + i*4);
    acc = fmaf(wv.x, pv.x, acc); acc = fmaf(wv.y, pv.y, acc);
    acc = fmaf(wv.z, pv.z, acc); acc = fmaf(wv.w, pv.w, acc);
  }
  hout[(size_t)bt*256 + c] = acc;
}

// ---------------- K7: conv3 + bn + gelu (+residual) ----------------
__global__ __launch_bounds__(256) void conv_bn_kernel(
    const float* __restrict__ hin, float* __restrict__ hout,
    const float* __restrict__ w, const float* __restrict__ bias,
    const float* __restrict__ g, const float* __restrict__ be,
    const float* __restrict__ m, const float* __restrict__ v,
    int residual) {
  __shared__ __align__(16) float win[768];
  int bt = blockIdx.x, b = bt >> 5, t = bt & 31;
  int c = threadIdx.x;
  for (int i = c; i < 768; i += 256) {
    int cin = i / 3, dt = i - cin*3;
    int tt = t + dt - 1;
    win[i] = (tt >= 0 && tt < 32) ? hin[((size_t)b*32 + tt)*256 + cin] : 0.0f;
  }
  __syncthreads();
  float acc = bias[c];
  const float* wr = w + (size_t)c*768;
  for (int i = 0; i < 192; ++i) {
    float4 wv = *(const float4*)(wr + i*4);
    float4 pv = *(const float4*)(win + i*4);
    acc = fmaf(wv.x, pv.x, acc); acc = fmaf(wv.y, pv.y, acc);
    acc = fmaf(wv.z, pv.z, acc); acc = fmaf(wv.w, pv.w, acc);
  }
  float rsv = 1.0f / sqrtf(v[c] + 1e-5f);
  float y = (acc - m[c]) * rsv * g[c] + be[c];
  y = gelu_f(y);
  if (residual) y += win[c*3 + 1];
  hout[(size_t)bt*256 + c] = y;
}

// ---------------- K8: max-pool over T + head ----------------
__global__ __launch_bounds__(256) void poolhead_kernel(
    const float* __restrict__ hs, const float* __restrict__ h1w,
    const float* __restrict__ h1b, const float* __restrict__ h2w,
    const float* __restrict__ h2b, float* __restrict__ out) {
  __shared__ float pooled[256];
  __shared__ float hh[128];
  int b = blockIdx.x, tid = threadIdx.x;
  float mx = -INFINITY;
  for (int t = 0; t < 32; ++t)
    mx = fmaxf(mx, hs[((size_t)b*32 + t)*256 + tid]);
  pooled[tid] = mx;
  __syncthreads();
  if (tid < 128) {
    float acc = h1b[tid];
    for (int e = 0; e < 256; ++e) acc = fmaf(pooled[e], h1w[e*128 + tid], acc);
    hh[tid] = gelu_f(acc);
  }
  __syncthreads();
  if (tid < 25) {
    float acc = h2b[tid];
    for (int e = 0; e < 128; ++e) acc = fmaf(hh[e], h2w[e*25 + tid], acc);
    out[b*25 + tid] = acc;
  }
}

// ---------------- launch ----------------
extern "C" void kernel_launch(void* const* d_in, const int* in_sizes, int n_in,
                              void* d_out, int out_size, void* d_ws, size_t ws_size,
                              hipStream_t stream) {
  const float* x_pt = (const float*)d_in[0];
  const float* x_fr = (const float*)d_in[1];
  const float* ew1  = (const float*)d_in[2];
  const float* eg1  = (const float*)d_in[3];
  const float* eb1  = (const float*)d_in[4];
  const float* em1  = (const float*)d_in[5];
  const float* ev1  = (const float*)d_in[6];
  const float* ew2  = (const float*)d_in[7];
  const float* eg2  = (const float*)d_in[8];
  const float* eb2  = (const float*)d_in[9];
  const float* em2  = (const float*)d_in[10];
  const float* ev2  = (const float*)d_in[11];
  const float* p1w  = (const float*)d_in[12];
  const float* p1b  = (const float*)d_in[13];
  const float* ln1g = (const float*)d_in[14];
  const float* ln1b = (const float*)d_in[15];
  const float* p2w  = (const float*)d_in[16];
  const float* p2b  = (const float*)d_in[17];
  const float* ln2g = (const float*)d_in[18];
  const float* ln2b = (const float*)d_in[19];
  const float* f1w  = (const float*)d_in[20];
  const float* f1b  = (const float*)d_in[21];
  const float* f2w  = (const float*)d_in[22];
  const float* f2b  = (const float*)d_in[23];
  const float* projw= (const float*)d_in[24];
  const float* projb= (const float*)d_in[25];
  const float* cw[4] = {(const float*)d_in[26],(const float*)d_in[32],(const float*)d_in[38],(const float*)d_in[44]};
  const float* cb[4] = {(const float*)d_in[27],(const float*)d_in[33],(const float*)d_in[39],(const float*)d_in[45]};
  const float* cg[4] = {(const float*)d_in[28],(const float*)d_in[34],(const float*)d_in[40],(const float*)d_in[46]};
  const float* cbe[4]= {(const float*)d_in[29],(const float*)d_in[35],(const float*)d_in[41],(const float*)d_in[47]};
  const float* cm[4] = {(const float*)d_in[30],(const float*)d_in[36],(const float*)d_in[42],(const float*)d_in[48]};
  const float* cv[4] = {(const float*)d_in[31],(const float*)d_in[37],(const float*)d_in[43],(const float*)d_in[49]};
  const float* h1w  = (const float*)d_in[50];
  const float* h1b  = (const float*)d_in[51];
  const float* h2w  = (const float*)d_in[52];
  const float* h2b  = (const float*)d_in[53];
  float* out = (float*)d_out;

  char* ws = (char*)d_ws;
  // layout: [0,1M) idx u8 (dead after edgeconv; perbuf/hs overlap after)
  //         [2M,2.3M) prep bf16 weights  [4,20M) Af  [20,36M) Bf  [36,68M) localf
  uchar_t* idxw  = (uchar_t*)ws;                               // 1 MB
  float* perbuf  = (float*)ws;
  float* hs0     = (float*)(ws + 0x90000);
  float* hs1     = (float*)(ws + 0x90000 + 0x40000);
  float* hs2     = (float*)(ws + 0x90000 + 2*0x40000);
  float* hs3     = (float*)(ws + 0x90000 + 3*0x40000);
  float* hs4     = (float*)(ws + 0x90000 + 4*0x40000);
  ushort_t* ew2b = (ushort_t*)(ws + 0x200000);                 // 18,432 B
  ushort_t* w1b  = (ushort_t*)(ws + 0x200000 + 0x8000);        // 43,008 B
  ushort_t* w2b  = (ushort_t*)(ws + 0x200000 + 0x14000);       // 69,632 B
  float* Af      = (float*)(ws + ((size_t)4  << 20));
  float* Bfw     = (float*)(ws + ((size_t)20 << 20));
  float* localf  = (float*)(ws + ((size_t)36 << 20));
  float* pmaxb   = (float*)(ws + ((size_t)8  << 20));          // dead-Af reuse
  float* psumb   = (float*)(ws + ((size_t)12 << 20));

  knn_kernel<<<NBT*64, 256, 0, stream>>>(x_pt, idxw);
  featAB_kernel<<<(NBT*NP*64)/256, 256, 0, stream>>>(x_pt, ew1, Af, Bfw);
  prep_kernel<<<256, 256, 0, stream>>>(p1w, p2w, ew2, w1b, w2b, ew2b);
  edgeconv_kernel<<<(NBT*NP)/NPB, 256, 0, stream>>>(Af, Bfw, idxw, ew2b,
      eg1, eb1, em1, ev1, eg2, eb2, em2, ev2, localf);
  p1p2_kernel<<<NBT*4, 256, 0, stream>>>(localf, x_pt, w1b, w2b, p1b,
      ln1g, ln1b, p2b, ln2g, ln2b, pmaxb, psumb);
  p1p2_reduce_kernel<<<NBT, 256, 0, stream>>>(pmaxb, psumb, x_fr,
      f1w, f1b, f2w, f2b, perbuf);
  proj_kernel<<<NBT, 256, 0, stream>>>(perbuf, projw, projb, hs0);
  conv_bn_kernel<<<NBT, 256, 0, stream>>>(hs0, hs1, cw[0], cb[0], cg[0], cbe[0], cm[0], cv[0], 0);
  conv_bn_kernel<<<NBT, 256, 0, stream>>>(hs1, hs2, cw[1], cb[1], cg[1], cbe[1], cm[1], cv[1], 1);
  conv_bn_kernel<<<NBT, 256, 0, stream>>>(hs2, hs3, cw[2], cb[2], cg[2], cbe[2], cm[2], cv[2], 1);
  conv_bn_kernel<<<NBT, 256, 0, stream>>>(hs3, hs4, cw[3], cb[3], cg[3], cbe[3], cm[3], cv[3], 1);
  poolhead_kernel<<<8, 256, 0, stream>>>(hs4, h1w, h1b, h2w, h2b, out);
}

// Round 11
// 518.325 us; speedup vs baseline: 2.7779x; 1.0097x over previous
//
#include <hip/hip_runtime.h>
#include <math.h>

// ---------------- constants ----------------
#define NBT   256    // B*T
#define NP    256    // points per frame
#define NC    10     // point channels
#define KNN   16
#define NPB   8      // points per block in edgeconv

typedef unsigned short ushort_t;
typedef unsigned char uchar_t;
typedef __attribute__((ext_vector_type(8))) short short8;
typedef __attribute__((ext_vector_type(4))) float f32x4;

__device__ __forceinline__ float gelu_f(float x) {     // exact (cold paths)
  return 0.5f * x * (1.0f + erff(x * 0.7071067811865476f));
}
// Branch-free erf (A&S 7.1.26, |err| <= 1.5e-7 abs) -> fast gelu for hot paths.
__device__ __forceinline__ float gelu_fast(float x) {
  float u  = x * 0.7071067811865476f;
  float au = fabsf(u);
  float t  = __builtin_amdgcn_rcpf(fmaf(0.3275911f, au, 1.0f));
  float p  = fmaf(t, 1.061405429f, -1.453152027f);
  p = fmaf(t, p, 1.421413741f);
  p = fmaf(t, p, -0.284496736f);
  p = fmaf(t, p, 0.254829592f);
  p = p * t;
  float e  = __expf(-au * au);
  float er = fmaf(-p, e, 1.0f);               // erf(|u|)
  er = copysignf(er, u);
  return 0.5f * x * (1.0f + er);
}
__device__ __forceinline__ ushort_t f2bf(float f) {   // RNE fp32 -> bf16
  unsigned u = __float_as_uint(f);
  return (ushort_t)((u + 0x7FFFu + ((u >> 16) & 1u)) >> 16);
}

// ---------------- K1: knn ----------------
__global__ __launch_bounds__(256) void knn_kernel(const float* __restrict__ x_pt,
                                                  uchar_t* __restrict__ idx) {
  __shared__ float sx[NP], sy[NP], sz[NP], ssq[NP];
  int bt = blockIdx.x >> 6;
  int p0 = (blockIdx.x & 63) * 4;
  int tid = threadIdx.x;
  const float* xb = x_pt + (size_t)bt * NP * NC;
  {
    int q = tid;
    float x0 = xb[q*NC+0], x1 = xb[q*NC+1], x2 = xb[q*NC+2];
    sx[q] = x0; sy[q] = x1; sz[q] = x2;
    ssq[q] = x0*x0 + x1*x1 + x2*x2;
  }
  __syncthreads();

  int wv = tid >> 6, lane = tid & 63;
  int p = p0 + wv;
  float px = sx[p], py = sy[p], pz = sz[p], psq = ssq[p];

  unsigned k0, k1, k2, k3;
  {
    unsigned kk[4];
#pragma unroll
    for (int c = 0; c < 4; ++c) {
      int q = lane + c*64;
      float d = psq + ssq[q] - 2.0f*(px*sx[q] + py*sy[q] + pz*sz[q]);
      d = fmaxf(d, 0.0f);
      kk[c] = (__float_as_uint(d) & 0xFFFFFF00u) | (unsigned)q;
    }
    unsigned a0 = min(kk[0], kk[1]), a1 = max(kk[0], kk[1]);
    unsigned a2 = min(kk[2], kk[3]), a3 = max(kk[2], kk[3]);
    unsigned b0 = min(a0, a2), b2 = max(a0, a2);
    unsigned b1 = min(a1, a3), b3 = max(a1, a3);
    k0 = b0; k1 = min(b1, b2); k2 = max(b1, b2); k3 = b3;
  }

  unsigned cur = k0, mykeep = 0u;
#pragma unroll
  for (int r = 0; r < 16; ++r) {
    unsigned w = cur;
    w = min(w, (unsigned)__shfl_xor((int)w, 1));
    w = min(w, (unsigned)__shfl_xor((int)w, 2));
    w = min(w, (unsigned)__shfl_xor((int)w, 4));
    w = min(w, (unsigned)__shfl_xor((int)w, 8));
    w = min(w, (unsigned)__shfl_xor((int)w, 16));
    w = min(w, (unsigned)__shfl_xor((int)w, 32));
    bool win = (cur == w);
    cur = win ? k1 : cur;
    k1  = win ? k2 : k1;
    k2  = win ? k3 : k2;
    k3  = win ? 0xFFFFFFFFu : k3;
    if (lane == r) mykeep = w;
  }
  if (lane < 16)
    idx[((size_t)bt*NP + p)*KNN + lane] = (uchar_t)(mykeep & 0xFFu);
}

// ---------------- K2: factored layer-1 features ----------------
__global__ __launch_bounds__(256) void featAB_kernel(const float* __restrict__ x_pt,
                                                     const float* __restrict__ ew1,
                                                     float* __restrict__ Af,
                                                     float* __restrict__ Bf) {
  int t = blockIdx.x*256 + threadIdx.x;
  int o = t & 63, p = t >> 6;
  const float* xr = x_pt + (size_t)p*NC;
  float a = 0.f, b = 0.f;
#pragma unroll
  for (int e = 0; e < NC; ++e) {
    float w1 = ew1[o*20 + e], w2 = ew1[o*20 + 10 + e];
    float xv = xr[e];
    a = fmaf(xv, w1 - w2, a);
    b = fmaf(xv, w2, b);
  }
  Af[(size_t)p*64 + o] = a;
  Bf[(size_t)p*64 + o] = b;
}

// ---------------- K2b: weight prep #1 (p1/p2/ew2 bf16) ----------------
__global__ __launch_bounds__(256) void prep_kernel(
    const float* __restrict__ p1w, const float* __restrict__ p2w,
    const float* __restrict__ ew2,
    ushort_t* __restrict__ w1b, ushort_t* __restrict__ w2b,
    ushort_t* __restrict__ ew2b) {
  int i = blockIdx.x*256 + threadIdx.x;      // 0..65535 exactly
  if (i < 21504) {
    int o = i / 168, e = i - o*168;
    w1b[i] = f2bf((e < 138) ? p1w[e*128 + o] : 0.f);
  } else if (i < 56320) {
    int j = i - 21504;
    int q = j / 136, e = j - q*136;
    w2b[j] = f2bf((e < 128) ? p2w[e*256 + q] : 0.f);
  } else {
    int m = i - 56320;                       // 0..9215
    int q = m / 72, o = m - q*72;
    ew2b[m] = f2bf((o < 64) ? ew2[q*64 + o] : 0.f);
  }
}

// ---------------- K2c: weight prep #2 (tail: proj + conv dt-major bf16 + folded bn) ----------------
// pjb [256][576]: pjb[c][e] = projw[c][e]
// cwb [4][256][768]: cwb[l][c][dt*256+cin] = cw_l[c][cin*3+dt]
// SCt/SHt [4][256]: y = conv*SC + SH  (bias+bn folded)
__global__ __launch_bounds__(256) void prep2_kernel(
    const float* __restrict__ projw,
    const float* __restrict__ cw0, const float* __restrict__ cw1,
    const float* __restrict__ cw2, const float* __restrict__ cw3,
    const float* __restrict__ cb0, const float* __restrict__ cb1,
    const float* __restrict__ cb2, const float* __restrict__ cb3,
    const float* __restrict__ cg0, const float* __restrict__ cg1,
    const float* __restrict__ cg2, const float* __restrict__ cg3,
    const float* __restrict__ be0, const float* __restrict__ be1,
    const float* __restrict__ be2, const float* __restrict__ be3,
    const float* __restrict__ cm0, const float* __restrict__ cm1,
    const float* __restrict__ cm2, const float* __restrict__ cm3,
    const float* __restrict__ cv0, const float* __restrict__ cv1,
    const float* __restrict__ cv2, const float* __restrict__ cv3,
    ushort_t* __restrict__ pjb, ushort_t* __restrict__ cwb,
    float* __restrict__ SCt, float* __restrict__ SHt) {
  const float* cwp[4] = {cw0, cw1, cw2, cw3};
  const float* cbp[4] = {cb0, cb1, cb2, cb3};
  const float* cgp[4] = {cg0, cg1, cg2, cg3};
  const float* bep[4] = {be0, be1, be2, be3};
  const float* cmp[4] = {cm0, cm1, cm2, cm3};
  const float* cvp[4] = {cv0, cv1, cv2, cv3};
  int i = blockIdx.x*256 + threadIdx.x;
  if (i < 147456) {                       // pjb
    pjb[i] = f2bf(projw[i]);              // [c][e][1] row-major == [c][e]
  } else if (i < 147456 + 786432) {       // cwb
    int j = i - 147456;
    int lay = j / 196608, rem = j - lay*196608;
    int c = rem / 768, kp = rem - c*768;
    int dt = kp >> 8, cin = kp & 255;
    cwb[j] = f2bf(cwp[lay][c*768 + cin*3 + dt]);
  } else if (i < 147456 + 786432 + 1024) {
    int j = i - 147456 - 786432;
    int lay = j >> 8, c = j & 255;
    float rsv = 1.0f / sqrtf(cvp[lay][c] + 1e-5f);
    float sc = cgp[lay][c] * rsv;
    SCt[j] = sc;
    SHt[j] = (cbp[lay][c] - cmp[lay][c]) * sc + bep[lay][c];
  }
}

// ---------------- K3: edgeconv layer2 via bf16 MFMA + max over k ----------------
__global__ __launch_bounds__(256, 2) void edgeconv_kernel(
    const float* __restrict__ Af, const float* __restrict__ Bf,
    const uchar_t* __restrict__ idx, const ushort_t* __restrict__ ew2b,
    const float* __restrict__ eg1, const float* __restrict__ eb1,
    const float* __restrict__ em1, const float* __restrict__ ev1,
    const float* __restrict__ eg2, const float* __restrict__ eb2,
    const float* __restrict__ em2, const float* __restrict__ ev2,
    ushort_t* __restrict__ localfb) {
  __shared__ __align__(16) ushort_t h1s[128*72];
  __shared__ __align__(16) ushort_t w2T[128*72];
  __shared__ float sc1[64], sh1[64], sc2[128], sh2[128];
  __shared__ int idxs[128];

  int tid = threadIdx.x;
  int bid = blockIdx.x;
  int wid = (bid & 7) * 1024 + (bid >> 3);
  int p0  = wid * NPB;
  int bt  = p0 >> 8;

  for (int i = tid; i < 1152; i += 256)
    ((uint4*)w2T)[i] = ((const uint4*)ew2b)[i];
  if (tid < 128) idxs[tid] = idx[(size_t)p0*16 + tid];
  if (tid < 64) {
    float s = eg1[tid] * (1.0f / sqrtf(ev1[tid] + 1e-5f));
    sc1[tid] = s; sh1[tid] = eb1[tid] - em1[tid]*s;
  }
  if (tid >= 64 && tid < 192) {
    int q = tid - 64;
    float s = eg2[q] * (1.0f / sqrtf(ev2[q] + 1e-5f));
    sc2[q] = s; sh2[q] = eb2[q] - em2[q]*s;
  }
  __syncthreads();

  {
    int o = tid & 63, g = tid >> 6;
    float s1 = sc1[o], h1v = sh1[o];
    const float* Bbase = Bf + (size_t)bt*NP*64 + o;
#pragma unroll
    for (int pi = 0; pi < 2; ++pi) {
      int pt = g*2 + pi;
      float af = Af[((size_t)(p0+pt))*64 + o];
      ushort_t* hrow = h1s + (pt*16)*72 + o;
#pragma unroll
      for (int k = 0; k < KNN; ++k) {
        int j = idxs[pt*16 + k];
        float hv = af + Bbase[(size_t)j*64];
        hrow[k*72] = f2bf(gelu_fast(fmaf(hv, s1, h1v)));
      }
    }
  }
  __syncthreads();

  int w = tid >> 6, l = tid & 63;
  int m_lo = l & 15, kq = l >> 4;

  short8 afr[2][2];
#pragma unroll
  for (int pt = 0; pt < 2; ++pt)
#pragma unroll
    for (int ks = 0; ks < 2; ++ks)
      afr[pt][ks] = *(const short8*)&h1s[((2*w+pt)*16 + m_lo)*72 + ks*32 + kq*8];

  f32x4 acc[2][8];
#pragma unroll
  for (int pt = 0; pt < 2; ++pt)
#pragma unroll
    for (int ct = 0; ct < 8; ++ct) acc[pt][ct] = (f32x4){0.f,0.f,0.f,0.f};

#pragma unroll
  for (int ct = 0; ct < 8; ++ct) {
#pragma unroll
    for (int ks = 0; ks < 2; ++ks) {
      short8 bfr = *(const short8*)&w2T[(ct*16 + m_lo)*72 + ks*32 + kq*8];
      acc[0][ct] = __builtin_amdgcn_mfma_f32_16x16x32_bf16(afr[0][ks], bfr, acc[0][ct], 0, 0, 0);
      acc[1][ct] = __builtin_amdgcn_mfma_f32_16x16x32_bf16(afr[1][ks], bfr, acc[1][ct], 0, 0, 0);
    }
  }

#pragma unroll
  for (int pt = 0; pt < 2; ++pt) {
    int gp = p0 + 2*w + pt;
#pragma unroll
    for (int ct = 0; ct < 8; ++ct) {
      int q = ct*16 + m_lo;
      float sc = sc2[q], sh = sh2[q];
      f32x4 a = acc[pt][ct];
      float mn = INFINITY, mx = -INFINITY;
#pragma unroll
      for (int r = 0; r < 4; ++r) {
        float y = fmaf(a[r], sc, sh);
        mn = fminf(mn, y); mx = fmaxf(mx, y);
      }
      mn = fminf(mn, __shfl_xor(mn, 16));
      mn = fminf(mn, __shfl_xor(mn, 32));
      mx = fmaxf(mx, __shfl_xor(mx, 16));
      mx = fmaxf(mx, __shfl_xor(mx, 32));
      float g = gelu_fast((kq & 1) ? mx : mn);
      g = fmaxf(g, __shfl_xor(g, 16));
      if (l < 16)
        localfb[(size_t)gp*128 + q] = f2bf(g);
    }
  }
}

// ---------------- K4: p1p2 via bf16 MFMA ----------------
__global__ __launch_bounds__(256, 2) void p1p2_kernel(
    const ushort_t* __restrict__ localfb, const float* __restrict__ x_pt,
    const ushort_t* __restrict__ w1b, const ushort_t* __restrict__ w2b,
    const float* __restrict__ p1b,
    const float* __restrict__ ln1g, const float* __restrict__ ln1b,
    const float* __restrict__ p2b,
    const float* __restrict__ ln2g, const float* __restrict__ ln2b,
    float* __restrict__ pmaxb, float* __restrict__ psumb) {
  __shared__ __align__(16) ushort_t sA[64*168];
  __shared__ __align__(16) ushort_t wt[128*168];
  __shared__ float pm4[4*256], ps4[4*256];
  int blk = blockIdx.x;
  int bt = blk >> 2, ch = blk & 3;
  int tid = threadIdx.x;
  size_t gbase = (size_t)bt*NP + ch*64;

  // stage localfb (bf16, straight uint4 copy) + x_pt (bf16)
  for (int i = tid; i < 1024; i += 256) {       // 64 rows x 16 uint4
    int pp = i >> 4, v = i & 15;
    *(uint4*)(sA + pp*168 + v*8) =
        *(const uint4*)(localfb + (gbase+pp)*128 + v*8);
  }
  for (int i = tid; i < 64*40; i += 256) {
    int pp = i / 40, e = i - pp*40;
    ushort_t v = 0;
    if (e < 10) v = f2bf(x_pt[(gbase+pp)*NC + e]);
    sA[pp*168 + 128 + e] = v;
  }
  for (int i = tid; i < 2688; i += 256)
    ((uint4*)wt)[i] = ((const uint4*)w1b)[i];
  __syncthreads();                                            // B1

  int w = tid >> 6, l = tid & 63;
  int lo = l & 15, kq = l >> 4;

  short8 af1[5];
#pragma unroll
  for (int ks = 0; ks < 5; ++ks)
    af1[ks] = *(const short8*)&sA[(w*16 + lo)*168 + ks*32 + kq*8];
  f32x4 acc1[8];
#pragma unroll
  for (int ct = 0; ct < 8; ++ct) {
    float b = p1b[ct*16 + lo];
    acc1[ct] = (f32x4){b, b, b, b};
  }
#pragma unroll
  for (int ct = 0; ct < 8; ++ct) {
#pragma unroll
    for (int ks = 0; ks < 5; ++ks) {
      short8 bf = *(const short8*)&wt[(ct*16 + lo)*168 + ks*32 + kq*8];
      acc1[ct] = __builtin_amdgcn_mfma_f32_16x16x32_bf16(af1[ks], bf, acc1[ct], 0, 0, 0);
    }
  }
  __syncthreads();                                            // B2

  {
    float g1v[8], b1v[8];
#pragma unroll
    for (int ct = 0; ct < 8; ++ct) { g1v[ct] = ln1g[ct*16+lo]; b1v[ct] = ln1b[ct*16+lo]; }
#pragma unroll
    for (int r = 0; r < 4; ++r) {
      float s = 0.f;
#pragma unroll
      for (int ct = 0; ct < 8; ++ct) s += acc1[ct][r];
      s += __shfl_xor(s,1); s += __shfl_xor(s,2); s += __shfl_xor(s,4); s += __shfl_xor(s,8);
      float mu = s * (1.0f/128.0f);
      float s2 = 0.f;
#pragma unroll
      for (int ct = 0; ct < 8; ++ct) { float d = acc1[ct][r]-mu; s2 += d*d; }
      s2 += __shfl_xor(s2,1); s2 += __shfl_xor(s2,2); s2 += __shfl_xor(s2,4); s2 += __shfl_xor(s2,8);
      float rs = 1.0f / sqrtf(s2*(1.0f/128.0f) + 1e-5f);
      int row = w*16 + kq*4 + r;
#pragma unroll
      for (int ct = 0; ct < 8; ++ct) {
        float h = gelu_fast((acc1[ct][r]-mu)*rs*g1v[ct] + b1v[ct]);
        sA[row*168 + ct*16 + lo] = f2bf(h);
      }
    }
  }
  for (int i = tid; i < 2176; i += 256)
    ((uint4*)wt)[i] = ((const uint4*)w2b)[i];
  __syncthreads();                                            // B3

  short8 af2[4];
#pragma unroll
  for (int ks = 0; ks < 4; ++ks)
    af2[ks] = *(const short8*)&sA[(w*16 + lo)*168 + ks*32 + kq*8];
  f32x4 acc2[16];
#pragma unroll
  for (int ct = 0; ct < 8; ++ct) {
    float bA = p2b[ct*16 + lo], bB = p2b[128 + ct*16 + lo];
    acc2[ct]   = (f32x4){bA, bA, bA, bA};
    acc2[8+ct] = (f32x4){bB, bB, bB, bB};
  }
#pragma unroll
  for (int ct = 0; ct < 8; ++ct) {
#pragma unroll
    for (int ks = 0; ks < 4; ++ks) {
      short8 bf = *(const short8*)&wt[(ct*16 + lo)*136 + ks*32 + kq*8];
      acc2[ct] = __builtin_amdgcn_mfma_f32_16x16x32_bf16(af2[ks], bf, acc2[ct], 0, 0, 0);
    }
  }
  __syncthreads();                                            // B4
  for (int i = tid; i < 2176; i += 256)
    ((uint4*)wt)[i] = ((const uint4*)(w2b + 17408))[i];
  __syncthreads();                                            // B5
#pragma unroll
  for (int ct = 0; ct < 8; ++ct) {
#pragma unroll
    for (int ks = 0; ks < 4; ++ks) {
      short8 bf = *(const short8*)&wt[(ct*16 + lo)*136 + ks*32 + kq*8];
      acc2[8+ct] = __builtin_amdgcn_mfma_f32_16x16x32_bf16(af2[ks], bf, acc2[8+ct], 0, 0, 0);
    }
  }

  float vmax[16], vsum[16];
  {
    float g2v[16], b2v[16];
#pragma unroll
    for (int j = 0; j < 16; ++j) {
      int c = (j >= 8 ? 128 : 0) + (j & 7)*16 + lo;
      g2v[j] = ln2g[c]; b2v[j] = ln2b[c];
    }
#pragma unroll
    for (int j = 0; j < 16; ++j) { vmax[j] = -INFINITY; vsum[j] = 0.f; }
#pragma unroll
    for (int r = 0; r < 4; ++r) {
      float s = 0.f;
#pragma unroll
      for (int j = 0; j < 16; ++j) s += acc2[j][r];
      s += __shfl_xor(s,1); s += __shfl_xor(s,2); s += __shfl_xor(s,4); s += __shfl_xor(s,8);
      float mu = s * (1.0f/256.0f);
      float s2 = 0.f;
#pragma unroll
      for (int j = 0; j < 16; ++j) { float d = acc2[j][r]-mu; s2 += d*d; }
      s2 += __shfl_xor(s2,1); s2 += __shfl_xor(s2,2); s2 += __shfl_xor(s2,4); s2 += __shfl_xor(s2,8);
      float rs = 1.0f / sqrtf(s2*(1.0f/256.0f) + 1e-5f);
#pragma unroll
      for (int j = 0; j < 16; ++j) {
        float v = gelu_fast((acc2[j][r]-mu)*rs*g2v[j] + b2v[j]);
        vmax[j] = fmaxf(vmax[j], v);
        vsum[j] += v;
      }
    }
  }
#pragma unroll
  for (int j = 0; j < 16; ++j) {
    float m = vmax[j], s = vsum[j];
    m = fmaxf(m, __shfl_xor(m, 16)); m = fmaxf(m, __shfl_xor(m, 32));
    s += __shfl_xor(s, 16);          s += __shfl_xor(s, 32);
    if (l < 16) {
      int c = (j >= 8 ? 128 : 0) + (j & 7)*16 + l;
      pm4[w*256 + c] = m;
      ps4[w*256 + c] = s;
    }
  }
  __syncthreads();                                            // B6
  {
    int c = tid;
    float mx = fmaxf(fmaxf(pm4[c], pm4[256+c]), fmaxf(pm4[512+c], pm4[768+c]));
    float sm = ps4[c] + ps4[256+c] + ps4[512+c] + ps4[768+c];
    pmaxb[(size_t)blk*256 + c] = mx;
    psumb[(size_t)blk*256 + c] = sm;
  }
}

// ---------------- K4b: combine partials + frame MLP -> perbuf ----------------
__global__ __launch_bounds__(256) void p1p2_reduce_kernel(
    const float* __restrict__ pmaxb, const float* __restrict__ psumb,
    const float* __restrict__ xfr, const float* __restrict__ f1w,
    const float* __restrict__ f1b, const float* __restrict__ f2w,
    const float* __restrict__ f2b, float* __restrict__ perbuf) {
  int bt = blockIdx.x, q = threadIdx.x;
  const float* mb = pmaxb + (size_t)bt*4*256 + q;
  const float* sb = psumb + (size_t)bt*4*256 + q;
  float mx = -INFINITY, sm = 0.f;
#pragma unroll
  for (int i = 0; i < 4; ++i) {
    mx = fmaxf(mx, mb[i*256]);
    sm += sb[i*256];
  }
  perbuf[(size_t)bt*576 + q] = mx;
  perbuf[(size_t)bt*576 + 256 + q] = sm * (1.0f/256.0f);

  if (q < 64) {
    float x0 = xfr[bt*4], x1 = xfr[bt*4+1], x2 = xfr[bt*4+2], x3 = xfr[bt*4+3];
    float acc = f2b[q];
#pragma unroll
    for (int e = 0; e < 32; ++e) {
      float hv = f1b[e];
      hv = fmaf(x0, f1w[e], hv);
      hv = fmaf(x1, f1w[32+e], hv);
      hv = fmaf(x2, f1w[64+e], hv);
      hv = fmaf(x3, f1w[96+e], hv);
      acc = fmaf(gelu_f(hv), f2w[e*64 + q], acc);
    }
    perbuf[(size_t)bt*576 + 512 + q] = acc;
  }
}

// ---------------- K5: megafused tail: proj -> c1..c4 -> pool -> head ----------------
// grid 8 (one block per b), 512 threads (8 waves = 2 m-tiles x 4 n-quarters).
// master [32][260] fp32; hsb [34][264] bf16 (halo rows 0,33 zero).
// conv K reordered dt-major: A[t][dt*256+cin] = hsb[t+dt][cin]; B = cwb (prep2).
__global__ __launch_bounds__(512, 1) void tail_kernel(
    const float* __restrict__ perbuf,
    const ushort_t* __restrict__ pjb, const ushort_t* __restrict__ cwb,
    const float* __restrict__ projb,
    const float* __restrict__ SCt, const float* __restrict__ SHt,
    const float* __restrict__ h1w, const float* __restrict__ h1b,
    const float* __restrict__ h2w, const float* __restrict__ h2b,
    float* __restrict__ out) {
  __shared__ __align__(16) ushort_t perA[32*584];   // 37,376 B
  __shared__ __align__(16) float master[32*260];    // 33,280 B
  __shared__ __align__(16) ushort_t hsb[34*264];    // 17,952 B
  __shared__ float pooled[256], hh[128];
  int b = blockIdx.x, tid = threadIdx.x;
  int w = tid >> 6, l = tid & 63;
  int lo = l & 15, kq = l >> 4;
  int mt = w & 1, nq = w >> 1;

  // stage per rows (bf16): 32 x 576
  for (int i = tid; i < 4608; i += 512) {     // 32*144 float4s
    int t = i / 144, v = i - t*144;
    float4 f4 = *(const float4*)(perbuf + ((size_t)b*32 + t)*576 + v*4);
    ushort_t* dst = perA + t*584 + v*4;
    dst[0]=f2bf(f4.x); dst[1]=f2bf(f4.y); dst[2]=f2bf(f4.z); dst[3]=f2bf(f4.w);
  }
  // zero halo rows of hsb once
  for (int i = tid; i < 264; i += 512) { hsb[i] = 0; hsb[33*264 + i] = 0; }
  __syncthreads();

  // ---- proj: M=32, N=256, K=576 (18 ks)
  {
    f32x4 acc[4];
#pragma unroll
    for (int j = 0; j < 4; ++j) {
      float bb = projb[(nq*4+j)*16 + lo];
      acc[j] = (f32x4){bb, bb, bb, bb};
    }
    for (int ks = 0; ks < 18; ++ks) {
      short8 af = *(const short8*)&perA[(mt*16 + lo)*584 + ks*32 + kq*8];
#pragma unroll
      for (int j = 0; j < 4; ++j) {
        int ct = nq*4 + j;
        short8 bf = *(const short8*)&pjb[(ct*16 + lo)*576 + ks*32 + kq*8];
        acc[j] = __builtin_amdgcn_mfma_f32_16x16x32_bf16(af, bf, acc[j], 0, 0, 0);
      }
    }
#pragma unroll
    for (int j = 0; j < 4; ++j) {
      int col = (nq*4+j)*16 + lo;
#pragma unroll
      for (int r = 0; r < 4; ++r)
        master[(mt*16 + kq*4 + r)*260 + col] = acc[j][r];
    }
  }
  __syncthreads();

  // ---- 4 conv layers
  for (int lay = 0; lay < 4; ++lay) {
    // bf16 copy of master into hsb rows 1..32
    for (int i = tid; i < 8192; i += 512) {
      int t = i >> 8, c = i & 255;
      hsb[(t+1)*264 + c] = f2bf(master[t*260 + c]);
    }
    __syncthreads();

    f32x4 acc[4];
#pragma unroll
    for (int j = 0; j < 4; ++j) acc[j] = (f32x4){0.f,0.f,0.f,0.f};
    const ushort_t* wb = cwb + (size_t)lay*196608;
    for (int ks = 0; ks < 24; ++ks) {
      int dt = ks >> 3, cin0 = (ks & 7)*32 + kq*8;
      short8 af = *(const short8*)&hsb[(mt*16 + lo + dt)*264 + cin0];
#pragma unroll
      for (int j = 0; j < 4; ++j) {
        int ct = nq*4 + j;
        short8 bf = *(const short8*)&wb[(ct*16 + lo)*768 + ks*32 + kq*8];
        acc[j] = __builtin_amdgcn_mfma_f32_16x16x32_bf16(af, bf, acc[j], 0, 0, 0);
      }
    }
    __syncthreads();   // all hsb reads done before master rewrite
#pragma unroll
    for (int j = 0; j < 4; ++j) {
      int col = (nq*4+j)*16 + lo;
      float sc = SCt[lay*256 + col], sh = SHt[lay*256 + col];
#pragma unroll
      for (int r = 0; r < 4; ++r) {
        int row = mt*16 + kq*4 + r;
        float y = gelu_fast(fmaf(acc[j][r], sc, sh));
        if (lay > 0) y += master[row*260 + col];
        master[row*260 + col] = y;
      }
    }
    __syncthreads();
  }

  // ---- pool over t + head
  if (tid < 256) {
    float mx = -INFINITY;
#pragma unroll 8
    for (int t = 0; t < 32; ++t) mx = fmaxf(mx, master[t*260 + tid]);
    pooled[tid] = mx;
  }
  __syncthreads();
  if (tid < 128) {
    float acc = h1b[tid];
    for (int e = 0; e < 256; ++e) acc = fmaf(pooled[e], h1w[e*128 + tid], acc);
    hh[tid] = gelu_f(acc);
  }
  __syncthreads();
  if (tid < 25) {
    float acc = h2b[tid];
    for (int e = 0; e < 128; ++e) acc = fmaf(hh[e], h2w[e*25 + tid], acc);
    out[b*25 + tid] = acc;
  }
}

// ---------------- launch ----------------
extern "C" void kernel_launch(void* const* d_in, const int* in_sizes, int n_in,
                              void* d_out, int out_size, void* d_ws, size_t ws_size,
                              hipStream_t stream) {
  const float* x_pt = (const float*)d_in[0];
  const float* x_fr = (const float*)d_in[1];
  const float* ew1  = (const float*)d_in[2];
  const float* eg1  = (const float*)d_in[3];
  const float* eb1  = (const float*)d_in[4];
  const float* em1  = (const float*)d_in[5];
  const float* ev1  = (const float*)d_in[6];
  const float* ew2  = (const float*)d_in[7];
  const float* eg2  = (const float*)d_in[8];
  const float* eb2  = (const float*)d_in[9];
  const float* em2  = (const float*)d_in[10];
  const float* ev2  = (const float*)d_in[11];
  const float* p1w  = (const float*)d_in[12];
  const float* p1b  = (const float*)d_in[13];
  const float* ln1g = (const float*)d_in[14];
  const float* ln1b = (const float*)d_in[15];
  const float* p2w  = (const float*)d_in[16];
  const float* p2b  = (const float*)d_in[17];
  const float* ln2g = (const float*)d_in[18];
  const float* ln2b = (const float*)d_in[19];
  const float* f1w  = (const float*)d_in[20];
  const float* f1b  = (const float*)d_in[21];
  const float* f2w  = (const float*)d_in[22];
  const float* f2b  = (const float*)d_in[23];
  const float* projw= (const float*)d_in[24];
  const float* projb= (const float*)d_in[25];
  const float* cw[4] = {(const float*)d_in[26],(const float*)d_in[32],(const float*)d_in[38],(const float*)d_in[44]};
  const float* cb[4] = {(const float*)d_in[27],(const float*)d_in[33],(const float*)d_in[39],(const float*)d_in[45]};
  const float* cg[4] = {(const float*)d_in[28],(const float*)d_in[34],(const float*)d_in[40],(const float*)d_in[46]};
  const float* cbe[4]= {(const float*)d_in[29],(const float*)d_in[35],(const float*)d_in[41],(const float*)d_in[47]};
  const float* cm[4] = {(const float*)d_in[30],(const float*)d_in[36],(const float*)d_in[42],(const float*)d_in[48]};
  const float* cv[4] = {(const float*)d_in[31],(const float*)d_in[37],(const float*)d_in[43],(const float*)d_in[49]};
  const float* h1w  = (const float*)d_in[50];
  const float* h1b  = (const float*)d_in[51];
  const float* h2w  = (const float*)d_in[52];
  const float* h2b  = (const float*)d_in[53];
  float* out = (float*)d_out;

  char* ws = (char*)d_ws;
  // layout: [0,1M) idx u8 (dead after edgeconv) / perbuf after
  //   [2M,4M) prep bf16 weights (p1/p2/ew2 + tail pjb/cwb/SC/SH)
  //   [4M,8M) pmaxb/psumb  [8M,12M) spare  [20M,36M) Bf + Af  [36M,52M) localfb
  uchar_t* idxw  = (uchar_t*)ws;                               // 1 MB
  float* perbuf  = (float*)ws;                                 // after edgeconv
  ushort_t* ew2b = (ushort_t*)(ws + 0x200000);                 // 18,432 B
  ushort_t* w1b  = (ushort_t*)(ws + 0x200000 + 0x8000);        // 43,008 B
  ushort_t* w2b  = (ushort_t*)(ws + 0x200000 + 0x14000);       // 69,632 B
  ushort_t* pjb  = (ushort_t*)(ws + 0x200000 + 0x28000);       // 294,912 B
  ushort_t* cwb  = (ushort_t*)(ws + 0x200000 + 0x70000);       // 1,572,864 B
  float* SCt     = (float*)(ws + 0x200000 + 0x1F0000);         // 4,096 B
  float* SHt     = (float*)(ws + 0x200000 + 0x1F1000);         // 4,096 B
  float* pmaxb   = (float*)(ws + ((size_t)4  << 20));          // 1 MB
  float* psumb   = (float*)(ws + ((size_t)6  << 20));          // 1 MB
  float* Af      = (float*)(ws + ((size_t)12 << 20));
  float* Bfw     = (float*)(ws + ((size_t)28 << 20));
  ushort_t* localfb = (ushort_t*)(ws + ((size_t)44 << 20));    // 16 MB

  knn_kernel<<<NBT*64, 256, 0, stream>>>(x_pt, idxw);
  featAB_kernel<<<(NBT*NP*64)/256, 256, 0, stream>>>(x_pt, ew1, Af, Bfw);
  prep_kernel<<<256, 256, 0, stream>>>(p1w, p2w, ew2, w1b, w2b, ew2b);
  prep2_kernel<<<3656, 256, 0, stream>>>(projw,
      cw[0], cw[1], cw[2], cw[3], cb[0], cb[1], cb[2], cb[3],
      cg[0], cg[1], cg[2], cg[3], cbe[0], cbe[1], cbe[2], cbe[3],
      cm[0], cm[1], cm[2], cm[3], cv[0], cv[1], cv[2], cv[3],
      pjb, cwb, SCt, SHt);
  edgeconv_kernel<<<(NBT*NP)/NPB, 256, 0, stream>>>(Af, Bfw, idxw, ew2b,
      eg1, eb1, em1, ev1, eg2, eb2, em2, ev2, localfb);
  p1p2_kernel<<<NBT*4, 256, 0, stream>>>(localfb, x_pt, w1b, w2b, p1b,
      ln1g, ln1b, p2b, ln2g, ln2b, pmaxb, psumb);
  p1p2_reduce_kernel<<<NBT, 256, 0, stream>>>(pmaxb, psumb, x_fr,
      f1w, f1b, f2w, f2b, perbuf);
  tail_kernel<<<8, 512, 0, stream>>>(perbuf, pjb, cwb, projb, SCt, SHt,
      h1w, h1b, h2w, h2b, out);
}

// Round 12
// 464.950 us; speedup vs baseline: 3.0968x; 1.1148x over previous
//
#include <hip/hip_runtime.h>
#include <math.h>

// ---------------- constants ----------------
#define NBT   256    // B*T
#define NP    256    // points per frame
#define NC    10     // point channels
#define KNN   16
#define NPB   8      // points per block in edgeconv

typedef unsigned short ushort_t;
typedef unsigned char uchar_t;
typedef __attribute__((ext_vector_type(8))) short short8;
typedef __attribute__((ext_vector_type(4))) float f32x4;

__device__ __forceinline__ float gelu_f(float x) {     // exact (cold paths)
  return 0.5f * x * (1.0f + erff(x * 0.7071067811865476f));
}
// Branch-free erf (A&S 7.1.26, |err| <= 1.5e-7 abs) -> fast gelu for hot paths.
__device__ __forceinline__ float gelu_fast(float x) {
  float u  = x * 0.7071067811865476f;
  float au = fabsf(u);
  float t  = __builtin_amdgcn_rcpf(fmaf(0.3275911f, au, 1.0f));
  float p  = fmaf(t, 1.061405429f, -1.453152027f);
  p = fmaf(t, p, 1.421413741f);
  p = fmaf(t, p, -0.284496736f);
  p = fmaf(t, p, 0.254829592f);
  p = p * t;
  float e  = __expf(-au * au);
  float er = fmaf(-p, e, 1.0f);               // erf(|u|)
  er = copysignf(er, u);
  return 0.5f * x * (1.0f + er);
}
__device__ __forceinline__ ushort_t f2bf(float f) {   // RNE fp32 -> bf16
  unsigned u = __float_as_uint(f);
  return (ushort_t)((u + 0x7FFFu + ((u >> 16) & 1u)) >> 16);
}

// ---------------- K1: knn ----------------
__global__ __launch_bounds__(256) void knn_kernel(const float* __restrict__ x_pt,
                                                  uchar_t* __restrict__ idx) {
  __shared__ float sx[NP], sy[NP], sz[NP], ssq[NP];
  int bt = blockIdx.x >> 6;
  int p0 = (blockIdx.x & 63) * 4;
  int tid = threadIdx.x;
  const float* xb = x_pt + (size_t)bt * NP * NC;
  {
    int q = tid;
    float x0 = xb[q*NC+0], x1 = xb[q*NC+1], x2 = xb[q*NC+2];
    sx[q] = x0; sy[q] = x1; sz[q] = x2;
    ssq[q] = x0*x0 + x1*x1 + x2*x2;
  }
  __syncthreads();

  int wv = tid >> 6, lane = tid & 63;
  int p = p0 + wv;
  float px = sx[p], py = sy[p], pz = sz[p], psq = ssq[p];

  unsigned k0, k1, k2, k3;
  {
    unsigned kk[4];
#pragma unroll
    for (int c = 0; c < 4; ++c) {
      int q = lane + c*64;
      float d = psq + ssq[q] - 2.0f*(px*sx[q] + py*sy[q] + pz*sz[q]);
      d = fmaxf(d, 0.0f);
      kk[c] = (__float_as_uint(d) & 0xFFFFFF00u) | (unsigned)q;
    }
    unsigned a0 = min(kk[0], kk[1]), a1 = max(kk[0], kk[1]);
    unsigned a2 = min(kk[2], kk[3]), a3 = max(kk[2], kk[3]);
    unsigned b0 = min(a0, a2), b2 = max(a0, a2);
    unsigned b1 = min(a1, a3), b3 = max(a1, a3);
    k0 = b0; k1 = min(b1, b2); k2 = max(b1, b2); k3 = b3;
  }

  unsigned cur = k0, mykeep = 0u;
#pragma unroll
  for (int r = 0; r < 16; ++r) {
    unsigned w = cur;
    w = min(w, (unsigned)__shfl_xor((int)w, 1));
    w = min(w, (unsigned)__shfl_xor((int)w, 2));
    w = min(w, (unsigned)__shfl_xor((int)w, 4));
    w = min(w, (unsigned)__shfl_xor((int)w, 8));
    w = min(w, (unsigned)__shfl_xor((int)w, 16));
    w = min(w, (unsigned)__shfl_xor((int)w, 32));
    bool win = (cur == w);
    cur = win ? k1 : cur;
    k1  = win ? k2 : k1;
    k2  = win ? k3 : k2;
    k3  = win ? 0xFFFFFFFFu : k3;
    if (lane == r) mykeep = w;
  }
  if (lane < 16)
    idx[((size_t)bt*NP + p)*KNN + lane] = (uchar_t)(mykeep & 0xFFu);
}

// ---------------- K2: factored layer-1 features ----------------
__global__ __launch_bounds__(256) void featAB_kernel(const float* __restrict__ x_pt,
                                                     const float* __restrict__ ew1,
                                                     float* __restrict__ Af,
                                                     float* __restrict__ Bf) {
  int t = blockIdx.x*256 + threadIdx.x;
  int o = t & 63, p = t >> 6;
  const float* xr = x_pt + (size_t)p*NC;
  float a = 0.f, b = 0.f;
#pragma unroll
  for (int e = 0; e < NC; ++e) {
    float w1 = ew1[o*20 + e], w2 = ew1[o*20 + 10 + e];
    float xv = xr[e];
    a = fmaf(xv, w1 - w2, a);
    b = fmaf(xv, w2, b);
  }
  Af[(size_t)p*64 + o] = a;
  Bf[(size_t)p*64 + o] = b;
}

// ---------------- K2b: weight prep #1 (p1/p2/ew2 bf16) ----------------
__global__ __launch_bounds__(256) void prep_kernel(
    const float* __restrict__ p1w, const float* __restrict__ p2w,
    const float* __restrict__ ew2,
    ushort_t* __restrict__ w1b, ushort_t* __restrict__ w2b,
    ushort_t* __restrict__ ew2b) {
  int i = blockIdx.x*256 + threadIdx.x;      // 0..65535 exactly
  if (i < 21504) {
    int o = i / 168, e = i - o*168;
    w1b[i] = f2bf((e < 138) ? p1w[e*128 + o] : 0.f);
  } else if (i < 56320) {
    int j = i - 21504;
    int q = j / 136, e = j - q*136;
    w2b[j] = f2bf((e < 128) ? p2w[e*256 + q] : 0.f);
  } else {
    int m = i - 56320;                       // 0..9215
    int q = m / 72, o = m - q*72;
    ew2b[m] = f2bf((o < 64) ? ew2[q*64 + o] : 0.f);
  }
}

// ---------------- K2c: weight prep #2 (tail weights) ----------------
__global__ __launch_bounds__(256) void prep2_kernel(
    const float* __restrict__ projw,
    const float* __restrict__ cw0, const float* __restrict__ cw1,
    const float* __restrict__ cw2, const float* __restrict__ cw3,
    const float* __restrict__ cb0, const float* __restrict__ cb1,
    const float* __restrict__ cb2, const float* __restrict__ cb3,
    const float* __restrict__ cg0, const float* __restrict__ cg1,
    const float* __restrict__ cg2, const float* __restrict__ cg3,
    const float* __restrict__ be0, const float* __restrict__ be1,
    const float* __restrict__ be2, const float* __restrict__ be3,
    const float* __restrict__ cm0, const float* __restrict__ cm1,
    const float* __restrict__ cm2, const float* __restrict__ cm3,
    const float* __restrict__ cv0, const float* __restrict__ cv1,
    const float* __restrict__ cv2, const float* __restrict__ cv3,
    ushort_t* __restrict__ pjb, ushort_t* __restrict__ cwb,
    float* __restrict__ SCt, float* __restrict__ SHt) {
  const float* cwp[4] = {cw0, cw1, cw2, cw3};
  const float* cbp[4] = {cb0, cb1, cb2, cb3};
  const float* cgp[4] = {cg0, cg1, cg2, cg3};
  const float* bep[4] = {be0, be1, be2, be3};
  const float* cmp[4] = {cm0, cm1, cm2, cm3};
  const float* cvp[4] = {cv0, cv1, cv2, cv3};
  int i = blockIdx.x*256 + threadIdx.x;
  if (i < 147456) {                       // pjb [c][e]
    pjb[i] = f2bf(projw[i]);
  } else if (i < 147456 + 786432) {       // cwb [l][c][dt*256+cin]
    int j = i - 147456;
    int lay = j / 196608, rem = j - lay*196608;
    int c = rem / 768, kp = rem - c*768;
    int dt = kp >> 8, cin = kp & 255;
    cwb[j] = f2bf(cwp[lay][c*768 + cin*3 + dt]);
  } else if (i < 147456 + 786432 + 1024) {
    int j = i - 147456 - 786432;
    int lay = j >> 8, c = j & 255;
    float rsv = 1.0f / sqrtf(cvp[lay][c] + 1e-5f);
    float sc = cgp[lay][c] * rsv;
    SCt[j] = sc;
    SHt[j] = (cbp[lay][c] - cmp[lay][c]) * sc + bep[lay][c];
  }
}

// ---------------- K3: edgeconv layer2 via bf16 MFMA + max over k ----------------
__global__ __launch_bounds__(256, 2) void edgeconv_kernel(
    const float* __restrict__ Af, const float* __restrict__ Bf,
    const uchar_t* __restrict__ idx, const ushort_t* __restrict__ ew2b,
    const float* __restrict__ eg1, const float* __restrict__ eb1,
    const float* __restrict__ em1, const float* __restrict__ ev1,
    const float* __restrict__ eg2, const float* __restrict__ eb2,
    const float* __restrict__ em2, const float* __restrict__ ev2,
    ushort_t* __restrict__ localfb) {
  __shared__ __align__(16) ushort_t h1s[128*72];
  __shared__ __align__(16) ushort_t w2T[128*72];
  __shared__ float sc1[64], sh1[64], sc2[128], sh2[128];
  __shared__ int idxs[128];

  int tid = threadIdx.x;
  int bid = blockIdx.x;
  int wid = (bid & 7) * 1024 + (bid >> 3);
  int p0  = wid * NPB;
  int bt  = p0 >> 8;

  for (int i = tid; i < 1152; i += 256)
    ((uint4*)w2T)[i] = ((const uint4*)ew2b)[i];
  if (tid < 128) idxs[tid] = idx[(size_t)p0*16 + tid];
  if (tid < 64) {
    float s = eg1[tid] * (1.0f / sqrtf(ev1[tid] + 1e-5f));
    sc1[tid] = s; sh1[tid] = eb1[tid] - em1[tid]*s;
  }
  if (tid >= 64 && tid < 192) {
    int q = tid - 64;
    float s = eg2[q] * (1.0f / sqrtf(ev2[q] + 1e-5f));
    sc2[q] = s; sh2[q] = eb2[q] - em2[q]*s;
  }
  __syncthreads();

  {
    int o = tid & 63, g = tid >> 6;
    float s1 = sc1[o], h1v = sh1[o];
    const float* Bbase = Bf + (size_t)bt*NP*64 + o;
#pragma unroll
    for (int pi = 0; pi < 2; ++pi) {
      int pt = g*2 + pi;
      float af = Af[((size_t)(p0+pt))*64 + o];
      ushort_t* hrow = h1s + (pt*16)*72 + o;
#pragma unroll
      for (int k = 0; k < KNN; ++k) {
        int j = idxs[pt*16 + k];
        float hv = af + Bbase[(size_t)j*64];
        hrow[k*72] = f2bf(gelu_fast(fmaf(hv, s1, h1v)));
      }
    }
  }
  __syncthreads();

  int w = tid >> 6, l = tid & 63;
  int m_lo = l & 15, kq = l >> 4;

  short8 afr[2][2];
#pragma unroll
  for (int pt = 0; pt < 2; ++pt)
#pragma unroll
    for (int ks = 0; ks < 2; ++ks)
      afr[pt][ks] = *(const short8*)&h1s[((2*w+pt)*16 + m_lo)*72 + ks*32 + kq*8];

  f32x4 acc[2][8];
#pragma unroll
  for (int pt = 0; pt < 2; ++pt)
#pragma unroll
    for (int ct = 0; ct < 8; ++ct) acc[pt][ct] = (f32x4){0.f,0.f,0.f,0.f};

#pragma unroll
  for (int ct = 0; ct < 8; ++ct) {
#pragma unroll
    for (int ks = 0; ks < 2; ++ks) {
      short8 bfr = *(const short8*)&w2T[(ct*16 + m_lo)*72 + ks*32 + kq*8];
      acc[0][ct] = __builtin_amdgcn_mfma_f32_16x16x32_bf16(afr[0][ks], bfr, acc[0][ct], 0, 0, 0);
      acc[1][ct] = __builtin_amdgcn_mfma_f32_16x16x32_bf16(afr[1][ks], bfr, acc[1][ct], 0, 0, 0);
    }
  }

#pragma unroll
  for (int pt = 0; pt < 2; ++pt) {
    int gp = p0 + 2*w + pt;
#pragma unroll
    for (int ct = 0; ct < 8; ++ct) {
      int q = ct*16 + m_lo;
      float sc = sc2[q], sh = sh2[q];
      f32x4 a = acc[pt][ct];
      float mn = INFINITY, mx = -INFINITY;
#pragma unroll
      for (int r = 0; r < 4; ++r) {
        float y = fmaf(a[r], sc, sh);
        mn = fminf(mn, y); mx = fmaxf(mx, y);
      }
      mn = fminf(mn, __shfl_xor(mn, 16));
      mn = fminf(mn, __shfl_xor(mn, 32));
      mx = fmaxf(mx, __shfl_xor(mx, 16));
      mx = fmaxf(mx, __shfl_xor(mx, 32));
      float g = gelu_fast((kq & 1) ? mx : mn);
      g = fmaxf(g, __shfl_xor(g, 16));
      if (l < 16)
        localfb[(size_t)gp*128 + q] = f2bf(g);
    }
  }
}

// ---------------- K4: p1p2 via bf16 MFMA ----------------
__global__ __launch_bounds__(256, 2) void p1p2_kernel(
    const ushort_t* __restrict__ localfb, const float* __restrict__ x_pt,
    const ushort_t* __restrict__ w1b, const ushort_t* __restrict__ w2b,
    const float* __restrict__ p1b,
    const float* __restrict__ ln1g, const float* __restrict__ ln1b,
    const float* __restrict__ p2b,
    const float* __restrict__ ln2g, const float* __restrict__ ln2b,
    float* __restrict__ pmaxb, float* __restrict__ psumb) {
  __shared__ __align__(16) ushort_t sA[64*168];
  __shared__ __align__(16) ushort_t wt[128*168];
  __shared__ float pm4[4*256], ps4[4*256];
  int blk = blockIdx.x;
  int bt = blk >> 2, ch = blk & 3;
  int tid = threadIdx.x;
  size_t gbase = (size_t)bt*NP + ch*64;

  for (int i = tid; i < 1024; i += 256) {       // 64 rows x 16 uint4
    int pp = i >> 4, v = i & 15;
    *(uint4*)(sA + pp*168 + v*8) =
        *(const uint4*)(localfb + (gbase+pp)*128 + v*8);
  }
  for (int i = tid; i < 64*40; i += 256) {
    int pp = i / 40, e = i - pp*40;
    ushort_t v = 0;
    if (e < 10) v = f2bf(x_pt[(gbase+pp)*NC + e]);
    sA[pp*168 + 128 + e] = v;
  }
  for (int i = tid; i < 2688; i += 256)
    ((uint4*)wt)[i] = ((const uint4*)w1b)[i];
  __syncthreads();                                            // B1

  int w = tid >> 6, l = tid & 63;
  int lo = l & 15, kq = l >> 4;

  short8 af1[5];
#pragma unroll
  for (int ks = 0; ks < 5; ++ks)
    af1[ks] = *(const short8*)&sA[(w*16 + lo)*168 + ks*32 + kq*8];
  f32x4 acc1[8];
#pragma unroll
  for (int ct = 0; ct < 8; ++ct) {
    float b = p1b[ct*16 + lo];
    acc1[ct] = (f32x4){b, b, b, b};
  }
#pragma unroll
  for (int ct = 0; ct < 8; ++ct) {
#pragma unroll
    for (int ks = 0; ks < 5; ++ks) {
      short8 bf = *(const short8*)&wt[(ct*16 + lo)*168 + ks*32 + kq*8];
      acc1[ct] = __builtin_amdgcn_mfma_f32_16x16x32_bf16(af1[ks], bf, acc1[ct], 0, 0, 0);
    }
  }
  __syncthreads();                                            // B2

  {
    float g1v[8], b1v[8];
#pragma unroll
    for (int ct = 0; ct < 8; ++ct) { g1v[ct] = ln1g[ct*16+lo]; b1v[ct] = ln1b[ct*16+lo]; }
#pragma unroll
    for (int r = 0; r < 4; ++r) {
      float s = 0.f;
#pragma unroll
      for (int ct = 0; ct < 8; ++ct) s += acc1[ct][r];
      s += __shfl_xor(s,1); s += __shfl_xor(s,2); s += __shfl_xor(s,4); s += __shfl_xor(s,8);
      float mu = s * (1.0f/128.0f);
      float s2 = 0.f;
#pragma unroll
      for (int ct = 0; ct < 8; ++ct) { float d = acc1[ct][r]-mu; s2 += d*d; }
      s2 += __shfl_xor(s2,1); s2 += __shfl_xor(s2,2); s2 += __shfl_xor(s2,4); s2 += __shfl_xor(s2,8);
      float rs = 1.0f / sqrtf(s2*(1.0f/128.0f) + 1e-5f);
      int row = w*16 + kq*4 + r;
#pragma unroll
      for (int ct = 0; ct < 8; ++ct) {
        float h = gelu_fast((acc1[ct][r]-mu)*rs*g1v[ct] + b1v[ct]);
        sA[row*168 + ct*16 + lo] = f2bf(h);
      }
    }
  }
  for (int i = tid; i < 2176; i += 256)
    ((uint4*)wt)[i] = ((const uint4*)w2b)[i];
  __syncthreads();                                            // B3

  short8 af2[4];
#pragma unroll
  for (int ks = 0; ks < 4; ++ks)
    af2[ks] = *(const short8*)&sA[(w*16 + lo)*168 + ks*32 + kq*8];
  f32x4 acc2[16];
#pragma unroll
  for (int ct = 0; ct < 8; ++ct) {
    float bA = p2b[ct*16 + lo], bB = p2b[128 + ct*16 + lo];
    acc2[ct]   = (f32x4){bA, bA, bA, bA};
    acc2[8+ct] = (f32x4){bB, bB, bB, bB};
  }
#pragma unroll
  for (int ct = 0; ct < 8; ++ct) {
#pragma unroll
    for (int ks = 0; ks < 4; ++ks) {
      short8 bf = *(const short8*)&wt[(ct*16 + lo)*136 + ks*32 + kq*8];
      acc2[ct] = __builtin_amdgcn_mfma_f32_16x16x32_bf16(af2[ks], bf, acc2[ct], 0, 0, 0);
    }
  }
  __syncthreads();                                            // B4
  for (int i = tid; i < 2176; i += 256)
    ((uint4*)wt)[i] = ((const uint4*)(w2b + 17408))[i];
  __syncthreads();                                            // B5
#pragma unroll
  for (int ct = 0; ct < 8; ++ct) {
#pragma unroll
    for (int ks = 0; ks < 4; ++ks) {
      short8 bf = *(const short8*)&wt[(ct*16 + lo)*136 + ks*32 + kq*8];
      acc2[8+ct] = __builtin_amdgcn_mfma_f32_16x16x32_bf16(af2[ks], bf, acc2[8+ct], 0, 0, 0);
    }
  }

  float vmax[16], vsum[16];
  {
    float g2v[16], b2v[16];
#pragma unroll
    for (int j = 0; j < 16; ++j) {
      int c = (j >= 8 ? 128 : 0) + (j & 7)*16 + lo;
      g2v[j] = ln2g[c]; b2v[j] = ln2b[c];
    }
#pragma unroll
    for (int j = 0; j < 16; ++j) { vmax[j] = -INFINITY; vsum[j] = 0.f; }
#pragma unroll
    for (int r = 0; r < 4; ++r) {
      float s = 0.f;
#pragma unroll
      for (int j = 0; j < 16; ++j) s += acc2[j][r];
      s += __shfl_xor(s,1); s += __shfl_xor(s,2); s += __shfl_xor(s,4); s += __shfl_xor(s,8);
      float mu = s * (1.0f/256.0f);
      float s2 = 0.f;
#pragma unroll
      for (int j = 0; j < 16; ++j) { float d = acc2[j][r]-mu; s2 += d*d; }
      s2 += __shfl_xor(s2,1); s2 += __shfl_xor(s2,2); s2 += __shfl_xor(s2,4); s2 += __shfl_xor(s2,8);
      float rs = 1.0f / sqrtf(s2*(1.0f/256.0f) + 1e-5f);
#pragma unroll
      for (int j = 0; j < 16; ++j) {
        float v = gelu_fast((acc2[j][r]-mu)*rs*g2v[j] + b2v[j]);
        vmax[j] = fmaxf(vmax[j], v);
        vsum[j] += v;
      }
    }
  }
#pragma unroll
  for (int j = 0; j < 16; ++j) {
    float m = vmax[j], s = vsum[j];
    m = fmaxf(m, __shfl_xor(m, 16)); m = fmaxf(m, __shfl_xor(m, 32));
    s += __shfl_xor(s, 16);          s += __shfl_xor(s, 32);
    if (l < 16) {
      int c = (j >= 8 ? 128 : 0) + (j & 7)*16 + l;
      pm4[w*256 + c] = m;
      ps4[w*256 + c] = s;
    }
  }
  __syncthreads();                                            // B6
  {
    int c = tid;
    float mx = fmaxf(fmaxf(pm4[c], pm4[256+c]), fmaxf(pm4[512+c], pm4[768+c]));
    float sm = ps4[c] + ps4[256+c] + ps4[512+c] + ps4[768+c];
    pmaxb[(size_t)blk*256 + c] = mx;
    psumb[(size_t)blk*256 + c] = sm;
  }
}

// ---------------- K4b: combine partials + frame MLP -> perbuf ----------------
__global__ __launch_bounds__(256) void p1p2_reduce_kernel(
    const float* __restrict__ pmaxb, const float* __restrict__ psumb,
    const float* __restrict__ xfr, const float* __restrict__ f1w,
    const float* __restrict__ f1b, const float* __restrict__ f2w,
    const float* __restrict__ f2b, float* __restrict__ perbuf) {
  int bt = blockIdx.x, q = threadIdx.x;
  const float* mb = pmaxb + (size_t)bt*4*256 + q;
  const float* sb = psumb + (size_t)bt*4*256 + q;
  float mx = -INFINITY, sm = 0.f;
#pragma unroll
  for (int i = 0; i < 4; ++i) {
    mx = fmaxf(mx, mb[i*256]);
    sm += sb[i*256];
  }
  perbuf[(size_t)bt*576 + q] = mx;
  perbuf[(size_t)bt*576 + 256 + q] = sm * (1.0f/256.0f);

  if (q < 64) {
    float x0 = xfr[bt*4], x1 = xfr[bt*4+1], x2 = xfr[bt*4+2], x3 = xfr[bt*4+3];
    float acc = f2b[q];
#pragma unroll
    for (int e = 0; e < 32; ++e) {
      float hv = f1b[e];
      hv = fmaf(x0, f1w[e], hv);
      hv = fmaf(x1, f1w[32+e], hv);
      hv = fmaf(x2, f1w[64+e], hv);
      hv = fmaf(x3, f1w[96+e], hv);
      acc = fmaf(gelu_f(hv), f2w[e*64 + q], acc);
    }
    perbuf[(size_t)bt*576 + 512 + q] = acc;
  }
}

// ---------------- K5: tail conv chain, t-chunk parallel with halo recompute ----------------
// grid 32 (b = blk>>2, chunk = blk&3). Window = 16 t-rows: global t = w0+i,
// w0 = chunk*8-4. Rows with invalid global t are re-zeroed at every layer input
// (exact conv zero-pad semantics). Window edge rows are computed wrong (missing
// halo) but corruption advances 1 row/layer; center rows 4..11 stay exact.
// 512 threads = 8 waves; wave w owns cols [w*32, w*32+32) (ct = 2w, 2w+1), M=16.
__global__ __launch_bounds__(512, 1) void tail2_kernel(
    const float* __restrict__ perbuf,
    const ushort_t* __restrict__ pjb, const ushort_t* __restrict__ cwb,
    const float* __restrict__ projb,
    const float* __restrict__ SCt, const float* __restrict__ SHt,
    float* __restrict__ hs4) {
  __shared__ __align__(16) ushort_t perA[16*584];   // 18,688 B
  __shared__ __align__(16) float master[16*260];    // 16,640 B
  __shared__ __align__(16) ushort_t hsb[18*264];    //  9,504 B
  int blk = blockIdx.x;
  int b = blk >> 2, chunk = blk & 3;
  int w0 = chunk*8 - 4;
  int tid = threadIdx.x;
  int w = tid >> 6, l = tid & 63;
  int lo = l & 15, kq = l >> 4;

  // stage perA bf16 (zeros for invalid t)
  for (int i = tid; i < 16*144; i += 512) {
    int t = i / 144, v = i - t*144;
    int gt = w0 + t;
    ushort_t* dst = perA + t*584 + v*4;
    if (gt >= 0 && gt < 32) {
      float4 f4 = *(const float4*)(perbuf + ((size_t)b*32 + gt)*576 + v*4);
      dst[0]=f2bf(f4.x); dst[1]=f2bf(f4.y); dst[2]=f2bf(f4.z); dst[3]=f2bf(f4.w);
    } else {
      dst[0]=0; dst[1]=0; dst[2]=0; dst[3]=0;
    }
  }
  for (int i = tid; i < 264; i += 512) { hsb[i] = 0; hsb[17*264 + i] = 0; }
  __syncthreads();

  // ---- proj: M=16, N=32/wave, K=576 (18 ks)
  {
    f32x4 acc[2];
#pragma unroll
    for (int j = 0; j < 2; ++j) {
      float bb = projb[(2*w+j)*16 + lo];
      acc[j] = (f32x4){bb, bb, bb, bb};
    }
    for (int ks = 0; ks < 18; ++ks) {
      short8 af = *(const short8*)&perA[lo*584 + ks*32 + kq*8];
#pragma unroll
      for (int j = 0; j < 2; ++j) {
        short8 bf = *(const short8*)&pjb[((2*w+j)*16 + lo)*576 + ks*32 + kq*8];
        acc[j] = __builtin_amdgcn_mfma_f32_16x16x32_bf16(af, bf, acc[j], 0, 0, 0);
      }
    }
#pragma unroll
    for (int j = 0; j < 2; ++j) {
      int col = (2*w+j)*16 + lo;
#pragma unroll
      for (int r = 0; r < 4; ++r) {
        int row = kq*4 + r;
        int gt = w0 + row;
        master[row*260 + col] = (gt >= 0 && gt < 32) ? acc[j][r] : 0.f;
      }
    }
  }
  __syncthreads();

  // ---- 4 conv layers (no global sync needed: halo recompute)
  for (int lay = 0; lay < 4; ++lay) {
    for (int i = tid; i < 4096; i += 512) {
      int t = i >> 8, c = i & 255;
      int gt = w0 + t;
      hsb[(t+1)*264 + c] = (gt >= 0 && gt < 32) ? f2bf(master[t*260 + c])
                                                : (ushort_t)0;
    }
    __syncthreads();

    f32x4 acc[2];
#pragma unroll
    for (int j = 0; j < 2; ++j) acc[j] = (f32x4){0.f,0.f,0.f,0.f};
    const ushort_t* wb = cwb + (size_t)lay*196608;
    for (int ks = 0; ks < 24; ++ks) {
      int dt = ks >> 3, cin0 = (ks & 7)*32 + kq*8;
      short8 af = *(const short8*)&hsb[(lo + dt)*264 + cin0];
#pragma unroll
      for (int j = 0; j < 2; ++j) {
        short8 bf = *(const short8*)&wb[((2*w+j)*16 + lo)*768 + ks*32 + kq*8];
        acc[j] = __builtin_amdgcn_mfma_f32_16x16x32_bf16(af, bf, acc[j], 0, 0, 0);
      }
    }
    __syncthreads();   // hsb reads done before master rewrite
#pragma unroll
    for (int j = 0; j < 2; ++j) {
      int col = (2*w+j)*16 + lo;
      float sc = SCt[lay*256 + col], sh = SHt[lay*256 + col];
#pragma unroll
      for (int r = 0; r < 4; ++r) {
        int row = kq*4 + r;
        float y = gelu_fast(fmaf(acc[j][r], sc, sh));
        if (lay > 0) y += master[row*260 + col];
        master[row*260 + col] = y;
      }
    }
    __syncthreads();
  }

  // ---- write center rows 4..11 (global t = chunk*8 .. +7)
  for (int i = tid; i < 2048; i += 512) {
    int t = i >> 8, c = i & 255;
    hs4[((size_t)b*32 + chunk*8 + t)*256 + c] = master[(t+4)*260 + c];
  }
}

// ---------------- K6: max-pool over T + head ----------------
__global__ __launch_bounds__(256) void poolhead_kernel(
    const float* __restrict__ hs, const float* __restrict__ h1w,
    const float* __restrict__ h1b, const float* __restrict__ h2w,
    const float* __restrict__ h2b, float* __restrict__ out) {
  __shared__ float pooled[256];
  __shared__ float hh[128];
  int b = blockIdx.x, tid = threadIdx.x;
  float mx = -INFINITY;
  for (int t = 0; t < 32; ++t)
    mx = fmaxf(mx, hs[((size_t)b*32 + t)*256 + tid]);
  pooled[tid] = mx;
  __syncthreads();
  // hh: 2 threads per output (e-split halves the serial chain)
  if (tid < 256) {
    int o = tid >> 1, half = tid & 1;
    float acc = half ? 0.f : h1b[o];
    for (int e = half*128; e < half*128 + 128; ++e)
      acc = fmaf(pooled[e], h1w[e*128 + o], acc);
    acc += __shfl_xor(acc, 1);
    if (half == 0 && o < 128) hh[o] = gelu_f(acc);
  }
  __syncthreads();
  if (tid < 25) {
    float acc = h2b[tid];
    for (int e = 0; e < 128; ++e) acc = fmaf(hh[e], h2w[e*25 + tid], acc);
    out[b*25 + tid] = acc;
  }
}

// ---------------- launch ----------------
extern "C" void kernel_launch(void* const* d_in, const int* in_sizes, int n_in,
                              void* d_out, int out_size, void* d_ws, size_t ws_size,
                              hipStream_t stream) {
  const float* x_pt = (const float*)d_in[0];
  const float* x_fr = (const float*)d_in[1];
  const float* ew1  = (const float*)d_in[2];
  const float* eg1  = (const float*)d_in[3];
  const float* eb1  = (const float*)d_in[4];
  const float* em1  = (const float*)d_in[5];
  const float* ev1  = (const float*)d_in[6];
  const float* ew2  = (const float*)d_in[7];
  const float* eg2  = (const float*)d_in[8];
  const float* eb2  = (const float*)d_in[9];
  const float* em2  = (const float*)d_in[10];
  const float* ev2  = (const float*)d_in[11];
  const float* p1w  = (const float*)d_in[12];
  const float* p1b  = (const float*)d_in[13];
  const float* ln1g = (const float*)d_in[14];
  const float* ln1b = (const float*)d_in[15];
  const float* p2w  = (const float*)d_in[16];
  const float* p2b  = (const float*)d_in[17];
  const float* ln2g = (const float*)d_in[18];
  const float* ln2b = (const float*)d_in[19];
  const float* f1w  = (const float*)d_in[20];
  const float* f1b  = (const float*)d_in[21];
  const float* f2w  = (const float*)d_in[22];
  const float* f2b  = (const float*)d_in[23];
  const float* projw= (const float*)d_in[24];
  const float* projb= (const float*)d_in[25];
  const float* cw[4] = {(const float*)d_in[26],(const float*)d_in[32],(const float*)d_in[38],(const float*)d_in[44]};
  const float* cb[4] = {(const float*)d_in[27],(const float*)d_in[33],(const float*)d_in[39],(const float*)d_in[45]};
  const float* cg[4] = {(const float*)d_in[28],(const float*)d_in[34],(const float*)d_in[40],(const float*)d_in[46]};
  const float* cbe[4]= {(const float*)d_in[29],(const float*)d_in[35],(const float*)d_in[41],(const float*)d_in[47]};
  const float* cm[4] = {(const float*)d_in[30],(const float*)d_in[36],(const float*)d_in[42],(const float*)d_in[48]};
  const float* cv[4] = {(const float*)d_in[31],(const float*)d_in[37],(const float*)d_in[43],(const float*)d_in[49]};
  const float* h1w  = (const float*)d_in[50];
  const float* h1b  = (const float*)d_in[51];
  const float* h2w  = (const float*)d_in[52];
  const float* h2b  = (const float*)d_in[53];
  float* out = (float*)d_out;

  char* ws = (char*)d_ws;
  uchar_t* idxw  = (uchar_t*)ws;                               // 1 MB
  float* perbuf  = (float*)ws;                                 // after edgeconv
  float* hs4     = (float*)(ws + 0x90000);                     // 256 KB
  ushort_t* ew2b = (ushort_t*)(ws + 0x200000);                 // 18,432 B
  ushort_t* w1b  = (ushort_t*)(ws + 0x200000 + 0x8000);        // 43,008 B
  ushort_t* w2b  = (ushort_t*)(ws + 0x200000 + 0x14000);       // 69,632 B
  ushort_t* pjb  = (ushort_t*)(ws + 0x200000 + 0x28000);       // 294,912 B
  ushort_t* cwb  = (ushort_t*)(ws + 0x200000 + 0x70000);       // 1,572,864 B
  float* SCt     = (float*)(ws + 0x200000 + 0x1F0000);         // 4,096 B
  float* SHt     = (float*)(ws + 0x200000 + 0x1F1000);         // 4,096 B
  float* pmaxb   = (float*)(ws + ((size_t)4  << 20));          // 1 MB
  float* psumb   = (float*)(ws + ((size_t)6  << 20));          // 1 MB
  float* Af      = (float*)(ws + ((size_t)12 << 20));
  float* Bfw     = (float*)(ws + ((size_t)28 << 20));
  ushort_t* localfb = (ushort_t*)(ws + ((size_t)44 << 20));    // 16 MB

  knn_kernel<<<NBT*64, 256, 0, stream>>>(x_pt, idxw);
  featAB_kernel<<<(NBT*NP*64)/256, 256, 0, stream>>>(x_pt, ew1, Af, Bfw);
  prep_kernel<<<256, 256, 0, stream>>>(p1w, p2w, ew2, w1b, w2b, ew2b);
  prep2_kernel<<<3656, 256, 0, stream>>>(projw,
      cw[0], cw[1], cw[2], cw[3], cb[0], cb[1], cb[2], cb[3],
      cg[0], cg[1], cg[2], cg[3], cbe[0], cbe[1], cbe[2], cbe[3],
      cm[0], cm[1], cm[2], cm[3], cv[0], cv[1], cv[2], cv[3],
      pjb, cwb, SCt, SHt);
  edgeconv_kernel<<<(NBT*NP)/NPB, 256, 0, stream>>>(Af, Bfw, idxw, ew2b,
      eg1, eb1, em1, ev1, eg2, eb2, em2, ev2, localfb);
  p1p2_kernel<<<NBT*4, 256, 0, stream>>>(localfb, x_pt, w1b, w2b, p1b,
      ln1g, ln1b, p2b, ln2g, ln2b, pmaxb, psumb);
  p1p2_reduce_kernel<<<NBT, 256, 0, stream>>>(pmaxb, psumb, x_fr,
      f1w, f1b, f2w, f2b, perbuf);
  tail2_kernel<<<32, 512, 0, stream>>>(perbuf, pjb, cwb, projb, SCt, SHt, hs4);
  poolhead_kernel<<<8, 256, 0, stream>>>(hs4, h1w, h1b, h2w, h2b, out);
}

// Round 13
// 450.623 us; speedup vs baseline: 3.1953x; 1.0318x over previous
//
#include <hip/hip_runtime.h>
#include <math.h>

// ---------------- constants ----------------
#define NBT   256    // B*T
#define NP    256    // points per frame
#define NC    10     // point channels
#define KNN   16
#define NPB   8      // points per block in edgeconv

typedef unsigned short ushort_t;
typedef unsigned char uchar_t;
typedef __attribute__((ext_vector_type(8))) short short8;
typedef __attribute__((ext_vector_type(4))) float f32x4;

__device__ __forceinline__ float gelu_f(float x) {     // exact (cold paths)
  return 0.5f * x * (1.0f + erff(x * 0.7071067811865476f));
}
// tanh-form gelu via sigmoid: gelu(x) ~= x * sigmoid(2*sqrt(2/pi)*(x+0.044715x^3))
//  = x * rcp(1 + exp(x*(A1 + A2*x^2))), A1=-2*0.7978845608, A2=-2*0.0356774081.
// Max |err| vs exact-erf gelu ~3e-4 (standard tanh-gelu) -- 13x below the bf16
// rounding already applied downstream. 8 VALU slots + exp + rcp (~28 cyc vs 46
// for the A&S-erf version). x->-inf => exp->inf => 0; x->+inf => exp->0 => x.
__device__ __forceinline__ float gelu_sig(float x) {
  float s = x * x;
  float z = x * fmaf(s, -0.0713548162f, -1.5957691216f);
  float e = __expf(z);
  float r = __builtin_amdgcn_rcpf(1.0f + e);
  return x * r;
}
__device__ __forceinline__ ushort_t f2bf(float f) {   // RNE fp32 -> bf16
  unsigned u = __float_as_uint(f);
  return (ushort_t)((u + 0x7FFFu + ((u >> 16) & 1u)) >> 16);
}

// ---------------- K1: knn ----------------
__global__ __launch_bounds__(256) void knn_kernel(const float* __restrict__ x_pt,
                                                  uchar_t* __restrict__ idx) {
  __shared__ float sx[NP], sy[NP], sz[NP], ssq[NP];
  int bt = blockIdx.x >> 6;
  int p0 = (blockIdx.x & 63) * 4;
  int tid = threadIdx.x;
  const float* xb = x_pt + (size_t)bt * NP * NC;
  {
    int q = tid;
    float x0 = xb[q*NC+0], x1 = xb[q*NC+1], x2 = xb[q*NC+2];
    sx[q] = x0; sy[q] = x1; sz[q] = x2;
    ssq[q] = x0*x0 + x1*x1 + x2*x2;
  }
  __syncthreads();

  int wv = tid >> 6, lane = tid & 63;
  int p = p0 + wv;
  float px = sx[p], py = sy[p], pz = sz[p], psq = ssq[p];

  unsigned k0, k1, k2, k3;
  {
    unsigned kk[4];
#pragma unroll
    for (int c = 0; c < 4; ++c) {
      int q = lane + c*64;
      float d = psq + ssq[q] - 2.0f*(px*sx[q] + py*sy[q] + pz*sz[q]);
      d = fmaxf(d, 0.0f);
      kk[c] = (__float_as_uint(d) & 0xFFFFFF00u) | (unsigned)q;
    }
    unsigned a0 = min(kk[0], kk[1]), a1 = max(kk[0], kk[1]);
    unsigned a2 = min(kk[2], kk[3]), a3 = max(kk[2], kk[3]);
    unsigned b0 = min(a0, a2), b2 = max(a0, a2);
    unsigned b1 = min(a1, a3), b3 = max(a1, a3);
    k0 = b0; k1 = min(b1, b2); k2 = max(b1, b2); k3 = b3;
  }

  unsigned cur = k0, mykeep = 0u;
#pragma unroll
  for (int r = 0; r < 16; ++r) {
    unsigned w = cur;
    w = min(w, (unsigned)__shfl_xor((int)w, 1));
    w = min(w, (unsigned)__shfl_xor((int)w, 2));
    w = min(w, (unsigned)__shfl_xor((int)w, 4));
    w = min(w, (unsigned)__shfl_xor((int)w, 8));
    w = min(w, (unsigned)__shfl_xor((int)w, 16));
    w = min(w, (unsigned)__shfl_xor((int)w, 32));
    bool win = (cur == w);
    cur = win ? k1 : cur;
    k1  = win ? k2 : k1;
    k2  = win ? k3 : k2;
    k3  = win ? 0xFFFFFFFFu : k3;
    if (lane == r) mykeep = w;
  }
  if (lane < 16)
    idx[((size_t)bt*NP + p)*KNN + lane] = (uchar_t)(mykeep & 0xFFu);
}

// ---------------- K2: factored layer-1 features ----------------
__global__ __launch_bounds__(256) void featAB_kernel(const float* __restrict__ x_pt,
                                                     const float* __restrict__ ew1,
                                                     float* __restrict__ Af,
                                                     float* __restrict__ Bf) {
  int t = blockIdx.x*256 + threadIdx.x;
  int o = t & 63, p = t >> 6;
  const float* xr = x_pt + (size_t)p*NC;
  float a = 0.f, b = 0.f;
#pragma unroll
  for (int e = 0; e < NC; ++e) {
    float w1 = ew1[o*20 + e], w2 = ew1[o*20 + 10 + e];
    float xv = xr[e];
    a = fmaf(xv, w1 - w2, a);
    b = fmaf(xv, w2, b);
  }
  Af[(size_t)p*64 + o] = a;
  Bf[(size_t)p*64 + o] = b;
}

// ---------------- K2b: weight prep #1 (p1/p2/ew2 bf16) ----------------
__global__ __launch_bounds__(256) void prep_kernel(
    const float* __restrict__ p1w, const float* __restrict__ p2w,
    const float* __restrict__ ew2,
    ushort_t* __restrict__ w1b, ushort_t* __restrict__ w2b,
    ushort_t* __restrict__ ew2b) {
  int i = blockIdx.x*256 + threadIdx.x;      // 0..65535 exactly
  if (i < 21504) {
    int o = i / 168, e = i - o*168;
    w1b[i] = f2bf((e < 138) ? p1w[e*128 + o] : 0.f);
  } else if (i < 56320) {
    int j = i - 21504;
    int q = j / 136, e = j - q*136;
    w2b[j] = f2bf((e < 128) ? p2w[e*256 + q] : 0.f);
  } else {
    int m = i - 56320;                       // 0..9215
    int q = m / 72, o = m - q*72;
    ew2b[m] = f2bf((o < 64) ? ew2[q*64 + o] : 0.f);
  }
}

// ---------------- K2c: weight prep #2 (tail weights) ----------------
__global__ __launch_bounds__(256) void prep2_kernel(
    const float* __restrict__ projw,
    const float* __restrict__ cw0, const float* __restrict__ cw1,
    const float* __restrict__ cw2, const float* __restrict__ cw3,
    const float* __restrict__ cb0, const float* __restrict__ cb1,
    const float* __restrict__ cb2, const float* __restrict__ cb3,
    const float* __restrict__ cg0, const float* __restrict__ cg1,
    const float* __restrict__ cg2, const float* __restrict__ cg3,
    const float* __restrict__ be0, const float* __restrict__ be1,
    const float* __restrict__ be2, const float* __restrict__ be3,
    const float* __restrict__ cm0, const float* __restrict__ cm1,
    const float* __restrict__ cm2, const float* __restrict__ cm3,
    const float* __restrict__ cv0, const float* __restrict__ cv1,
    const float* __restrict__ cv2, const float* __restrict__ cv3,
    ushort_t* __restrict__ pjb, ushort_t* __restrict__ cwb,
    float* __restrict__ SCt, float* __restrict__ SHt) {
  const float* cwp[4] = {cw0, cw1, cw2, cw3};
  const float* cbp[4] = {cb0, cb1, cb2, cb3};
  const float* cgp[4] = {cg0, cg1, cg2, cg3};
  const float* bep[4] = {be0, be1, be2, be3};
  const float* cmp[4] = {cm0, cm1, cm2, cm3};
  const float* cvp[4] = {cv0, cv1, cv2, cv3};
  int i = blockIdx.x*256 + threadIdx.x;
  if (i < 147456) {                       // pjb [c][e]
    pjb[i] = f2bf(projw[i]);
  } else if (i < 147456 + 786432) {       // cwb [l][c][dt*256+cin]
    int j = i - 147456;
    int lay = j / 196608, rem = j - lay*196608;
    int c = rem / 768, kp = rem - c*768;
    int dt = kp >> 8, cin = kp & 255;
    cwb[j] = f2bf(cwp[lay][c*768 + cin*3 + dt]);
  } else if (i < 147456 + 786432 + 1024) {
    int j = i - 147456 - 786432;
    int lay = j >> 8, c = j & 255;
    float rsv = 1.0f / sqrtf(cvp[lay][c] + 1e-5f);
    float sc = cgp[lay][c] * rsv;
    SCt[j] = sc;
    SHt[j] = (cbp[lay][c] - cmp[lay][c]) * sc + bep[lay][c];
  }
}

// ---------------- K3: edgeconv layer2 via bf16 MFMA + max over k ----------------
__global__ __launch_bounds__(256, 2) void edgeconv_kernel(
    const float* __restrict__ Af, const float* __restrict__ Bf,
    const uchar_t* __restrict__ idx, const ushort_t* __restrict__ ew2b,
    const float* __restrict__ eg1, const float* __restrict__ eb1,
    const float* __restrict__ em1, const float* __restrict__ ev1,
    const float* __restrict__ eg2, const float* __restrict__ eb2,
    const float* __restrict__ em2, const float* __restrict__ ev2,
    ushort_t* __restrict__ localfb) {
  __shared__ __align__(16) ushort_t h1s[128*72];
  __shared__ __align__(16) ushort_t w2T[128*72];
  __shared__ float sc1[64], sh1[64], sc2[128], sh2[128];
  __shared__ int idxs[128];

  int tid = threadIdx.x;
  int bid = blockIdx.x;
  int wid = (bid & 7) * 1024 + (bid >> 3);
  int p0  = wid * NPB;
  int bt  = p0 >> 8;

  for (int i = tid; i < 1152; i += 256)
    ((uint4*)w2T)[i] = ((const uint4*)ew2b)[i];
  if (tid < 128) idxs[tid] = idx[(size_t)p0*16 + tid];
  if (tid < 64) {
    float s = eg1[tid] * (1.0f / sqrtf(ev1[tid] + 1e-5f));
    sc1[tid] = s; sh1[tid] = eb1[tid] - em1[tid]*s;
  }
  if (tid >= 64 && tid < 192) {
    int q = tid - 64;
    float s = eg2[q] * (1.0f / sqrtf(ev2[q] + 1e-5f));
    sc2[q] = s; sh2[q] = eb2[q] - em2[q]*s;
  }
  __syncthreads();

  {
    int o = tid & 63, g = tid >> 6;
    float s1 = sc1[o], h1v = sh1[o];
    const float* Bbase = Bf + (size_t)bt*NP*64 + o;
#pragma unroll
    for (int pi = 0; pi < 2; ++pi) {
      int pt = g*2 + pi;
      float af = Af[((size_t)(p0+pt))*64 + o];
      ushort_t* hrow = h1s + (pt*16)*72 + o;
#pragma unroll
      for (int k = 0; k < KNN; ++k) {
        int j = idxs[pt*16 + k];
        float hv = af + Bbase[(size_t)j*64];
        hrow[k*72] = f2bf(gelu_sig(fmaf(hv, s1, h1v)));
      }
    }
  }
  __syncthreads();

  int w = tid >> 6, l = tid & 63;
  int m_lo = l & 15, kq = l >> 4;

  short8 afr[2][2];
#pragma unroll
  for (int pt = 0; pt < 2; ++pt)
#pragma unroll
    for (int ks = 0; ks < 2; ++ks)
      afr[pt][ks] = *(const short8*)&h1s[((2*w+pt)*16 + m_lo)*72 + ks*32 + kq*8];

  f32x4 acc[2][8];
#pragma unroll
  for (int pt = 0; pt < 2; ++pt)
#pragma unroll
    for (int ct = 0; ct < 8; ++ct) acc[pt][ct] = (f32x4){0.f,0.f,0.f,0.f};

#pragma unroll
  for (int ct = 0; ct < 8; ++ct) {
#pragma unroll
    for (int ks = 0; ks < 2; ++ks) {
      short8 bfr = *(const short8*)&w2T[(ct*16 + m_lo)*72 + ks*32 + kq*8];
      acc[0][ct] = __builtin_amdgcn_mfma_f32_16x16x32_bf16(afr[0][ks], bfr, acc[0][ct], 0, 0, 0);
      acc[1][ct] = __builtin_amdgcn_mfma_f32_16x16x32_bf16(afr[1][ks], bfr, acc[1][ct], 0, 0, 0);
    }
  }

#pragma unroll
  for (int pt = 0; pt < 2; ++pt) {
    int gp = p0 + 2*w + pt;
#pragma unroll
    for (int ct = 0; ct < 8; ++ct) {
      int q = ct*16 + m_lo;
      float sc = sc2[q], sh = sh2[q];
      f32x4 a = acc[pt][ct];
      float mn = INFINITY, mx = -INFINITY;
#pragma unroll
      for (int r = 0; r < 4; ++r) {
        float y = fmaf(a[r], sc, sh);
        mn = fminf(mn, y); mx = fmaxf(mx, y);
      }
      mn = fminf(mn, __shfl_xor(mn, 16));
      mn = fminf(mn, __shfl_xor(mn, 32));
      mx = fmaxf(mx, __shfl_xor(mx, 16));
      mx = fmaxf(mx, __shfl_xor(mx, 32));
      float g = gelu_sig((kq & 1) ? mx : mn);
      g = fmaxf(g, __shfl_xor(g, 16));
      if (l < 16)
        localfb[(size_t)gp*128 + q] = f2bf(g);
    }
  }
}

// ---------------- K4: p1p2 via bf16 MFMA ----------------
__global__ __launch_bounds__(256, 2) void p1p2_kernel(
    const ushort_t* __restrict__ localfb, const float* __restrict__ x_pt,
    const ushort_t* __restrict__ w1b, const ushort_t* __restrict__ w2b,
    const float* __restrict__ p1b,
    const float* __restrict__ ln1g, const float* __restrict__ ln1b,
    const float* __restrict__ p2b,
    const float* __restrict__ ln2g, const float* __restrict__ ln2b,
    float* __restrict__ pmaxb, float* __restrict__ psumb) {
  __shared__ __align__(16) ushort_t sA[64*168];
  __shared__ __align__(16) ushort_t wt[128*168];
  __shared__ float pm4[4*256], ps4[4*256];
  int blk = blockIdx.x;
  int bt = blk >> 2, ch = blk & 3;
  int tid = threadIdx.x;
  size_t gbase = (size_t)bt*NP + ch*64;

  for (int i = tid; i < 1024; i += 256) {       // 64 rows x 16 uint4
    int pp = i >> 4, v = i & 15;
    *(uint4*)(sA + pp*168 + v*8) =
        *(const uint4*)(localfb + (gbase+pp)*128 + v*8);
  }
  for (int i = tid; i < 64*40; i += 256) {
    int pp = i / 40, e = i - pp*40;
    ushort_t v = 0;
    if (e < 10) v = f2bf(x_pt[(gbase+pp)*NC + e]);
    sA[pp*168 + 128 + e] = v;
  }
  for (int i = tid; i < 2688; i += 256)
    ((uint4*)wt)[i] = ((const uint4*)w1b)[i];
  __syncthreads();                                            // B1

  int w = tid >> 6, l = tid & 63;
  int lo = l & 15, kq = l >> 4;

  short8 af1[5];
#pragma unroll
  for (int ks = 0; ks < 5; ++ks)
    af1[ks] = *(const short8*)&sA[(w*16 + lo)*168 + ks*32 + kq*8];
  f32x4 acc1[8];
#pragma unroll
  for (int ct = 0; ct < 8; ++ct) {
    float b = p1b[ct*16 + lo];
    acc1[ct] = (f32x4){b, b, b, b};
  }
#pragma unroll
  for (int ct = 0; ct < 8; ++ct) {
#pragma unroll
    for (int ks = 0; ks < 5; ++ks) {
      short8 bf = *(const short8*)&wt[(ct*16 + lo)*168 + ks*32 + kq*8];
      acc1[ct] = __builtin_amdgcn_mfma_f32_16x16x32_bf16(af1[ks], bf, acc1[ct], 0, 0, 0);
    }
  }
  __syncthreads();                                            // B2

  {
    float g1v[8], b1v[8];
#pragma unroll
    for (int ct = 0; ct < 8; ++ct) { g1v[ct] = ln1g[ct*16+lo]; b1v[ct] = ln1b[ct*16+lo]; }
#pragma unroll
    for (int r = 0; r < 4; ++r) {
      float s = 0.f;
#pragma unroll
      for (int ct = 0; ct < 8; ++ct) s += acc1[ct][r];
      s += __shfl_xor(s,1); s += __shfl_xor(s,2); s += __shfl_xor(s,4); s += __shfl_xor(s,8);
      float mu = s * (1.0f/128.0f);
      float s2 = 0.f;
#pragma unroll
      for (int ct = 0; ct < 8; ++ct) { float d = acc1[ct][r]-mu; s2 += d*d; }
      s2 += __shfl_xor(s2,1); s2 += __shfl_xor(s2,2); s2 += __shfl_xor(s2,4); s2 += __shfl_xor(s2,8);
      float rs = 1.0f / sqrtf(s2*(1.0f/128.0f) + 1e-5f);
      int row = w*16 + kq*4 + r;
#pragma unroll
      for (int ct = 0; ct < 8; ++ct) {
        float h = gelu_sig((acc1[ct][r]-mu)*rs*g1v[ct] + b1v[ct]);
        sA[row*168 + ct*16 + lo] = f2bf(h);
      }
    }
  }
  for (int i = tid; i < 2176; i += 256)
    ((uint4*)wt)[i] = ((const uint4*)w2b)[i];
  __syncthreads();                                            // B3

  short8 af2[4];
#pragma unroll
  for (int ks = 0; ks < 4; ++ks)
    af2[ks] = *(const short8*)&sA[(w*16 + lo)*168 + ks*32 + kq*8];
  f32x4 acc2[16];
#pragma unroll
  for (int ct = 0; ct < 8; ++ct) {
    float bA = p2b[ct*16 + lo], bB = p2b[128 + ct*16 + lo];
    acc2[ct]   = (f32x4){bA, bA, bA, bA};
    acc2[8+ct] = (f32x4){bB, bB, bB, bB};
  }
#pragma unroll
  for (int ct = 0; ct < 8; ++ct) {
#pragma unroll
    for (int ks = 0; ks < 4; ++ks) {
      short8 bf = *(const short8*)&wt[(ct*16 + lo)*136 + ks*32 + kq*8];
      acc2[ct] = __builtin_amdgcn_mfma_f32_16x16x32_bf16(af2[ks], bf, acc2[ct], 0, 0, 0);
    }
  }
  __syncthreads();                                            // B4
  for (int i = tid; i < 2176; i += 256)
    ((uint4*)wt)[i] = ((const uint4*)(w2b + 17408))[i];
  __syncthreads();                                            // B5
#pragma unroll
  for (int ct = 0; ct < 8; ++ct) {
#pragma unroll
    for (int ks = 0; ks < 4; ++ks) {
      short8 bf = *(const short8*)&wt[(ct*16 + lo)*136 + ks*32 + kq*8];
      acc2[8+ct] = __builtin_amdgcn_mfma_f32_16x16x32_bf16(af2[ks], bf, acc2[8+ct], 0, 0, 0);
    }
  }

  float vmax[16], vsum[16];
  {
    float g2v[16], b2v[16];
#pragma unroll
    for (int j = 0; j < 16; ++j) {
      int c = (j >= 8 ? 128 : 0) + (j & 7)*16 + lo;
      g2v[j] = ln2g[c]; b2v[j] = ln2b[c];
    }
#pragma unroll
    for (int j = 0; j < 16; ++j) { vmax[j] = -INFINITY; vsum[j] = 0.f; }
#pragma unroll
    for (int r = 0; r < 4; ++r) {
      float s = 0.f;
#pragma unroll
      for (int j = 0; j < 16; ++j) s += acc2[j][r];
      s += __shfl_xor(s,1); s += __shfl_xor(s,2); s += __shfl_xor(s,4); s += __shfl_xor(s,8);
      float mu = s * (1.0f/256.0f);
      float s2 = 0.f;
#pragma unroll
      for (int j = 0; j < 16; ++j) { float d = acc2[j][r]-mu; s2 += d*d; }
      s2 += __shfl_xor(s2,1); s2 += __shfl_xor(s2,2); s2 += __shfl_xor(s2,4); s2 += __shfl_xor(s2,8);
      float rs = 1.0f / sqrtf(s2*(1.0f/256.0f) + 1e-5f);
#pragma unroll
      for (int j = 0; j < 16; ++j) {
        float v = gelu_sig((acc2[j][r]-mu)*rs*g2v[j] + b2v[j]);
        vmax[j] = fmaxf(vmax[j], v);
        vsum[j] += v;
      }
    }
  }
#pragma unroll
  for (int j = 0; j < 16; ++j) {
    float m = vmax[j], s = vsum[j];
    m = fmaxf(m, __shfl_xor(m, 16)); m = fmaxf(m, __shfl_xor(m, 32));
    s += __shfl_xor(s, 16);          s += __shfl_xor(s, 32);
    if (l < 16) {
      int c = (j >= 8 ? 128 : 0) + (j & 7)*16 + l;
      pm4[w*256 + c] = m;
      ps4[w*256 + c] = s;
    }
  }
  __syncthreads();                                            // B6
  {
    int c = tid;
    float mx = fmaxf(fmaxf(pm4[c], pm4[256+c]), fmaxf(pm4[512+c], pm4[768+c]));
    float sm = ps4[c] + ps4[256+c] + ps4[512+c] + ps4[768+c];
    pmaxb[(size_t)blk*256 + c] = mx;
    psumb[(size_t)blk*256 + c] = sm;
  }
}

// ---------------- K4b: combine partials + frame MLP -> perbuf ----------------
__global__ __launch_bounds__(256) void p1p2_reduce_kernel(
    const float* __restrict__ pmaxb, const float* __restrict__ psumb,
    const float* __restrict__ xfr, const float* __restrict__ f1w,
    const float* __restrict__ f1b, const float* __restrict__ f2w,
    const float* __restrict__ f2b, float* __restrict__ perbuf) {
  int bt = blockIdx.x, q = threadIdx.x;
  const float* mb = pmaxb + (size_t)bt*4*256 + q;
  const float* sb = psumb + (size_t)bt*4*256 + q;
  float mx = -INFINITY, sm = 0.f;
#pragma unroll
  for (int i = 0; i < 4; ++i) {
    mx = fmaxf(mx, mb[i*256]);
    sm += sb[i*256];
  }
  perbuf[(size_t)bt*576 + q] = mx;
  perbuf[(size_t)bt*576 + 256 + q] = sm * (1.0f/256.0f);

  if (q < 64) {
    float x0 = xfr[bt*4], x1 = xfr[bt*4+1], x2 = xfr[bt*4+2], x3 = xfr[bt*4+3];
    float acc = f2b[q];
#pragma unroll
    for (int e = 0; e < 32; ++e) {
      float hv = f1b[e];
      hv = fmaf(x0, f1w[e], hv);
      hv = fmaf(x1, f1w[32+e], hv);
      hv = fmaf(x2, f1w[64+e], hv);
      hv = fmaf(x3, f1w[96+e], hv);
      acc = fmaf(gelu_f(hv), f2w[e*64 + q], acc);
    }
    perbuf[(size_t)bt*576 + 512 + q] = acc;
  }
}

// ---------------- K5: tail conv chain, t-chunk parallel with halo recompute ----------------
__global__ __launch_bounds__(512, 1) void tail2_kernel(
    const float* __restrict__ perbuf,
    const ushort_t* __restrict__ pjb, const ushort_t* __restrict__ cwb,
    const float* __restrict__ projb,
    const float* __restrict__ SCt, const float* __restrict__ SHt,
    float* __restrict__ hs4) {
  __shared__ __align__(16) ushort_t perA[16*584];   // 18,688 B
  __shared__ __align__(16) float master[16*260];    // 16,640 B
  __shared__ __align__(16) ushort_t hsb[18*264];    //  9,504 B
  int blk = blockIdx.x;
  int b = blk >> 2, chunk = blk & 3;
  int w0 = chunk*8 - 4;
  int tid = threadIdx.x;
  int w = tid >> 6, l = tid & 63;
  int lo = l & 15, kq = l >> 4;

  for (int i = tid; i < 16*144; i += 512) {
    int t = i / 144, v = i - t*144;
    int gt = w0 + t;
    ushort_t* dst = perA + t*584 + v*4;
    if (gt >= 0 && gt < 32) {
      float4 f4 = *(const float4*)(perbuf + ((size_t)b*32 + gt)*576 + v*4);
      dst[0]=f2bf(f4.x); dst[1]=f2bf(f4.y); dst[2]=f2bf(f4.z); dst[3]=f2bf(f4.w);
    } else {
      dst[0]=0; dst[1]=0; dst[2]=0; dst[3]=0;
    }
  }
  for (int i = tid; i < 264; i += 512) { hsb[i] = 0; hsb[17*264 + i] = 0; }
  __syncthreads();

  {
    f32x4 acc[2];
#pragma unroll
    for (int j = 0; j < 2; ++j) {
      float bb = projb[(2*w+j)*16 + lo];
      acc[j] = (f32x4){bb, bb, bb, bb};
    }
    for (int ks = 0; ks < 18; ++ks) {
      short8 af = *(const short8*)&perA[lo*584 + ks*32 + kq*8];
#pragma unroll
      for (int j = 0; j < 2; ++j) {
        short8 bf = *(const short8*)&pjb[((2*w+j)*16 + lo)*576 + ks*32 + kq*8];
        acc[j] = __builtin_amdgcn_mfma_f32_16x16x32_bf16(af, bf, acc[j], 0, 0, 0);
      }
    }
#pragma unroll
    for (int j = 0; j < 2; ++j) {
      int col = (2*w+j)*16 + lo;
#pragma unroll
      for (int r = 0; r < 4; ++r) {
        int row = kq*4 + r;
        int gt = w0 + row;
        master[row*260 + col] = (gt >= 0 && gt < 32) ? acc[j][r] : 0.f;
      }
    }
  }
  __syncthreads();

  for (int lay = 0; lay < 4; ++lay) {
    for (int i = tid; i < 4096; i += 512) {
      int t = i >> 8, c = i & 255;
      int gt = w0 + t;
      hsb[(t+1)*264 + c] = (gt >= 0 && gt < 32) ? f2bf(master[t*260 + c])
                                                : (ushort_t)0;
    }
    __syncthreads();

    f32x4 acc[2];
#pragma unroll
    for (int j = 0; j < 2; ++j) acc[j] = (f32x4){0.f,0.f,0.f,0.f};
    const ushort_t* wb = cwb + (size_t)lay*196608;
    for (int ks = 0; ks < 24; ++ks) {
      int dt = ks >> 3, cin0 = (ks & 7)*32 + kq*8;
      short8 af = *(const short8*)&hsb[(lo + dt)*264 + cin0];
#pragma unroll
      for (int j = 0; j < 2; ++j) {
        short8 bf = *(const short8*)&wb[((2*w+j)*16 + lo)*768 + ks*32 + kq*8];
        acc[j] = __builtin_amdgcn_mfma_f32_16x16x32_bf16(af, bf, acc[j], 0, 0, 0);
      }
    }
    __syncthreads();
#pragma unroll
    for (int j = 0; j < 2; ++j) {
      int col = (2*w+j)*16 + lo;
      float sc = SCt[lay*256 + col], sh = SHt[lay*256 + col];
#pragma unroll
      for (int r = 0; r < 4; ++r) {
        int row = kq*4 + r;
        float y = gelu_sig(fmaf(acc[j][r], sc, sh));
        if (lay > 0) y += master[row*260 + col];
        master[row*260 + col] = y;
      }
    }
    __syncthreads();
  }

  for (int i = tid; i < 2048; i += 512) {
    int t = i >> 8, c = i & 255;
    hs4[((size_t)b*32 + chunk*8 + t)*256 + c] = master[(t+4)*260 + c];
  }
}

// ---------------- K6: max-pool over T + head ----------------
__global__ __launch_bounds__(256) void poolhead_kernel(
    const float* __restrict__ hs, const float* __restrict__ h1w,
    const float* __restrict__ h1b, const float* __restrict__ h2w,
    const float* __restrict__ h2b, float* __restrict__ out) {
  __shared__ float pooled[256];
  __shared__ float hh[128];
  int b = blockIdx.x, tid = threadIdx.x;
  float mx = -INFINITY;
  for (int t = 0; t < 32; ++t)
    mx = fmaxf(mx, hs[((size_t)b*32 + t)*256 + tid]);
  pooled[tid] = mx;
  __syncthreads();
  if (tid < 256) {
    int o = tid >> 1, half = tid & 1;
    float acc = half ? 0.f : h1b[o];
    for (int e = half*128; e < half*128 + 128; ++e)
      acc = fmaf(pooled[e], h1w[e*128 + o], acc);
    acc += __shfl_xor(acc, 1);
    if (half == 0 && o < 128) hh[o] = gelu_f(acc);
  }
  __syncthreads();
  if (tid < 25) {
    float acc = h2b[tid];
    for (int e = 0; e < 128; ++e) acc = fmaf(hh[e], h2w[e*25 + tid], acc);
    out[b*25 + tid] = acc;
  }
}

// ---------------- launch ----------------
extern "C" void kernel_launch(void* const* d_in, const int* in_sizes, int n_in,
                              void* d_out, int out_size, void* d_ws, size_t ws_size,
                              hipStream_t stream) {
  const float* x_pt = (const float*)d_in[0];
  const float* x_fr = (const float*)d_in[1];
  const float* ew1  = (const float*)d_in[2];
  const float* eg1  = (const float*)d_in[3];
  const float* eb1  = (const float*)d_in[4];
  const float* em1  = (const float*)d_in[5];
  const float* ev1  = (const float*)d_in[6];
  const float* ew2  = (const float*)d_in[7];
  const float* eg2  = (const float*)d_in[8];
  const float* eb2  = (const float*)d_in[9];
  const float* em2  = (const float*)d_in[10];
  const float* ev2  = (const float*)d_in[11];
  const float* p1w  = (const float*)d_in[12];
  const float* p1b  = (const float*)d_in[13];
  const float* ln1g = (const float*)d_in[14];
  const float* ln1b = (const float*)d_in[15];
  const float* p2w  = (const float*)d_in[16];
  const float* p2b  = (const float*)d_in[17];
  const float* ln2g = (const float*)d_in[18];
  const float* ln2b = (const float*)d_in[19];
  const float* f1w  = (const float*)d_in[20];
  const float* f1b  = (const float*)d_in[21];
  const float* f2w  = (const float*)d_in[22];
  const float* f2b  = (const float*)d_in[23];
  const float* projw= (const float*)d_in[24];
  const float* projb= (const float*)d_in[25];
  const float* cw[4] = {(const float*)d_in[26],(const float*)d_in[32],(const float*)d_in[38],(const float*)d_in[44]};
  const float* cb[4] = {(const float*)d_in[27],(const float*)d_in[33],(const float*)d_in[39],(const float*)d_in[45]};
  const float* cg[4] = {(const float*)d_in[28],(const float*)d_in[34],(const float*)d_in[40],(const float*)d_in[46]};
  const float* cbe[4]= {(const float*)d_in[29],(const float*)d_in[35],(const float*)d_in[41],(const float*)d_in[47]};
  const float* cm[4] = {(const float*)d_in[30],(const float*)d_in[36],(const float*)d_in[42],(const float*)d_in[48]};
  const float* cv[4] = {(const float*)d_in[31],(const float*)d_in[37],(const float*)d_in[43],(const float*)d_in[49]};
  const float* h1w  = (const float*)d_in[50];
  const float* h1b  = (const float*)d_in[51];
  const float* h2w  = (const float*)d_in[52];
  const float* h2b  = (const float*)d_in[53];
  float* out = (float*)d_out;

  char* ws = (char*)d_ws;
  uchar_t* idxw  = (uchar_t*)ws;                               // 1 MB
  float* perbuf  = (float*)ws;                                 // after edgeconv
  float* hs4     = (float*)(ws + 0x90000);                     // 256 KB
  ushort_t* ew2b = (ushort_t*)(ws + 0x200000);                 // 18,432 B
  ushort_t* w1b  = (ushort_t*)(ws + 0x200000 + 0x8000);        // 43,008 B
  ushort_t* w2b  = (ushort_t*)(ws + 0x200000 + 0x14000);       // 69,632 B
  ushort_t* pjb  = (ushort_t*)(ws + 0x200000 + 0x28000);       // 294,912 B
  ushort_t* cwb  = (ushort_t*)(ws + 0x200000 + 0x70000);       // 1,572,864 B
  float* SCt     = (float*)(ws + 0x200000 + 0x1F0000);         // 4,096 B
  float* SHt     = (float*)(ws + 0x200000 + 0x1F1000);         // 4,096 B
  float* pmaxb   = (float*)(ws + ((size_t)4  << 20));          // 1 MB
  float* psumb   = (float*)(ws + ((size_t)6  << 20));          // 1 MB
  float* Af      = (float*)(ws + ((size_t)12 << 20));
  float* Bfw     = (float*)(ws + ((size_t)28 << 20));
  ushort_t* localfb = (ushort_t*)(ws + ((size_t)44 << 20));    // 16 MB

  knn_kernel<<<NBT*64, 256, 0, stream>>>(x_pt, idxw);
  featAB_kernel<<<(NBT*NP*64)/256, 256, 0, stream>>>(x_pt, ew1, Af, Bfw);
  prep_kernel<<<256, 256, 0, stream>>>(p1w, p2w, ew2, w1b, w2b, ew2b);
  prep2_kernel<<<3656, 256, 0, stream>>>(projw,
      cw[0], cw[1], cw[2], cw[3], cb[0], cb[1], cb[2], cb[3],
      cg[0], cg[1], cg[2], cg[3], cbe[0], cbe[1], cbe[2], cbe[3],
      cm[0], cm[1], cm[2], cm[3], cv[0], cv[1], cv[2], cv[3],
      pjb, cwb, SCt, SHt);
  edgeconv_kernel<<<(NBT*NP)/NPB, 256, 0, stream>>>(Af, Bfw, idxw, ew2b,
      eg1, eb1, em1, ev1, eg2, eb2, em2, ev2, localfb);
  p1p2_kernel<<<NBT*4, 256, 0, stream>>>(localfb, x_pt, w1b, w2b, p1b,
      ln1g, ln1b, p2b, ln2g, ln2b, pmaxb, psumb);
  p1p2_reduce_kernel<<<NBT, 256, 0, stream>>>(pmaxb, psumb, x_fr,
      f1w, f1b, f2w, f2b, perbuf);
  tail2_kernel<<<32, 512, 0, stream>>>(perbuf, pjb, cwb, projb, SCt, SHt, hs4);
  poolhead_kernel<<<8, 256, 0, stream>>>(hs4, h1w, h1b, h2w, h2b, out);
}